// Round 21
// baseline (609.133 us; speedup 1.0000x reference)
//
#include <hip/hip_runtime.h>
#include <hip/hip_bf16.h>
#include <cstdint>
#include <cstddef>

typedef unsigned short ushortT;
typedef unsigned int uintT;

using bf16x8 = __attribute__((ext_vector_type(8))) short;
using f32x4  = __attribute__((ext_vector_type(4))) float;

static constexpr int NN  = 8192;    // total nodes
static constexpr int EE  = 131072;  // edges
static constexpr float SLOPE  = 0.2f;
static constexpr float LN_EPS = 1e-5f;

#define DEVI __device__ __forceinline__

DEVI float red32(float v) {
  #pragma unroll
  for (int m = 16; m >= 1; m >>= 1) v += __shfl_xor(v, m, 64);
  return v;
}
DEVI float red64(float v) {
  #pragma unroll
  for (int m = 32; m >= 1; m >>= 1) v += __shfl_xor(v, m, 64);
  return v;
}
DEVI float max32(float v) {
  #pragma unroll
  for (int m = 16; m >= 1; m >>= 1) v = fmaxf(v, __shfl_xor(v, m, 64));
  return v;
}
DEVI float blo(uintT u) { union { uintT i; float f; } c; c.i = u << 16; return c.f; }
DEVI float bhi(uintT u) { union { uintT i; float f; } c; c.i = u & 0xffff0000u; return c.f; }
DEVI float b2f(ushortT u) { union { uintT i; float f; } c; c.i = ((uintT)u) << 16; return c.f; }
DEVI ushortT f2bu(float f) {
  __hip_bfloat16 h = __float2bfloat16(f);
  return *reinterpret_cast<ushortT*>(&h);
}
DEVI void storeC(float* p, float v) { *p = v; }
DEVI void storeC(ushortT* p, float v) { *p = f2bu(v); }

// ---------------------------------------------------------------------------
// FC: gh[n] = feat_t[n] @ Wfc_t + bfc_t ; out[n,0:256] = l2n(gh[n])
// ---------------------------------------------------------------------------
__global__ __launch_bounds__(256) void fc_kernel(
    const float* __restrict__ f0, const float* __restrict__ f1,
    const float* __restrict__ f2, const float* __restrict__ f3,
    const float* __restrict__ w0, const float* __restrict__ w1,
    const float* __restrict__ w2, const float* __restrict__ w3,
    const float* __restrict__ b0, const float* __restrict__ b1,
    const float* __restrict__ b2, const float* __restrict__ b3,
    float* __restrict__ gh, float* __restrict__ out)
{
  const int nb = blockIdx.x * 32;
  const int t  = threadIdx.x;
  int base, D;
  const float *F, *W, *Bv;
  if (nb < 4096)      { base = 0;    D = 128; F = f0; W = w0; Bv = b0; }
  else if (nb < 6144) { base = 4096; D = 64;  F = f1; W = w1; Bv = b1; }
  else if (nb < 7168) { base = 6144; D = 32;  F = f2; W = w2; Bv = b2; }
  else                { base = 7168; D = 16;  F = f3; W = w3; Bv = b3; }

  __shared__ float Fs[32 * 128];
  __shared__ float red[32][4];
  __shared__ float nrm[32];

  const int total = 32 * D;
  for (int i = t; i < total; i += 256) Fs[i] = F[(size_t)(nb - base) * D + i];
  __syncthreads();

  float acc[32];
  #pragma unroll
  for (int r = 0; r < 32; ++r) acc[r] = Bv[t];
  for (int d = 0; d < D; ++d) {
    float w = W[(size_t)d * 256 + t];
    #pragma unroll
    for (int r = 0; r < 32; ++r) acc[r] = fmaf(Fs[r * D + d], w, acc[r]);
  }

  const int lane = t & 63, wid = t >> 6;
  #pragma unroll
  for (int r = 0; r < 32; ++r) {
    float v = acc[r] * acc[r];
    for (int o = 32; o > 0; o >>= 1) v += __shfl_down(v, o, 64);
    if (lane == 0) red[r][wid] = v;
  }
  __syncthreads();
  if (t < 32) {
    float s = red[t][0] + red[t][1] + red[t][2] + red[t][3];
    nrm[t] = 1.0f / fmaxf(sqrtf(s), 1e-12f);
  }
  __syncthreads();
  #pragma unroll
  for (int r = 0; r < 32; ++r) {
    gh[(size_t)(nb + r) * 256 + t]  = acc[r];
    out[(size_t)(nb + r) * 768 + t] = acc[r] * nrm[r];
  }
}

// ---------------------------------------------------------------------------
// degree / CSR build
// ---------------------------------------------------------------------------
__global__ __launch_bounds__(256) void zero_counts(int* outc, int* inc) {
  int g = blockIdx.x * 256 + threadIdx.x;
  if (g < NN) outc[g] = 0; else inc[g - NN] = 0;
}
__global__ __launch_bounds__(256) void count_deg(const int* __restrict__ src,
                                                 const int* __restrict__ dst,
                                                 int* outc, int* inc) {
  int g = blockIdx.x * 256 + threadIdx.x;
  atomicAdd(&outc[src[g]], 1);
  atomicAdd(&inc[dst[g]], 1);
}
// scan + norm + cur in one
__global__ __launch_bounds__(1024) void scan_kernel(
    const int* __restrict__ inc, const int* __restrict__ outc,
    int* __restrict__ offs, int* __restrict__ cur,
    float* __restrict__ n_out, float* __restrict__ n_in)
{
  __shared__ int sums[1024];
  const int t = threadIdx.x;
  int x[8];
  const int base = t * 8;
  int s = 0;
  #pragma unroll
  for (int i = 0; i < 8; ++i) { int v = inc[base + i] + 1; x[i] = s; s += v; }
  sums[t] = s;
  __syncthreads();
  for (int off = 1; off < 1024; off <<= 1) {
    int a = (t >= off) ? sums[t - off] : 0;
    __syncthreads();
    sums[t] += a;
    __syncthreads();
  }
  const int pre = (t > 0) ? sums[t - 1] : 0;
  #pragma unroll
  for (int i = 0; i < 8; ++i) {
    const int o = pre + x[i];
    offs[base + i] = o;
    cur[base + i]  = o;
    n_in[base + i]  = rsqrtf((float)inc[base + i] + 1.0f);
    n_out[base + i] = rsqrtf((float)outc[base + i] + 1.0f);
  }
  if (t == 1023) offs[NN] = sums[1023];
}
__global__ __launch_bounds__(256) void fill_csr(const int* __restrict__ src,
                                                const int* __restrict__ dst,
                                                int* cur, int* __restrict__ csr) {
  int g = blockIdx.x * 256 + threadIdx.x;   // EE + NN total
  int s, d;
  if (g < EE) { s = src[g]; d = dst[g]; }
  else        { s = g - EE; d = g - EE; }   // self-loops
  int pos = atomicAdd(&cur[d], 1);
  csr[pos] = s;
}
__global__ __launch_bounds__(256) void init_R(const float* __restrict__ type_emb,
                                              const int* __restrict__ nt,
                                              float* __restrict__ R) {
  int g = blockIdx.x * 256 + threadIdx.x;   // NN*4
  int n = g >> 2, c = g & 3;
  R[g] = type_emb[nt[n] * 4 + c];
}

// ---------------------------------------------------------------------------
// MFMA GEMM (single B): C = (rowscale? diag(rs):I) A @ W ; optional RED
// ---------------------------------------------------------------------------
template<bool ROWSCALE, bool STORE, bool RED, typename CT>
__global__ __launch_bounds__(256) void mfma_gemm_kernel(
    const float* __restrict__ A, const float* __restrict__ W,
    const float* __restrict__ rowscale,
    CT* __restrict__ C, const float* __restrict__ avec,
    float* __restrict__ SSo)
{
  const int m0 = blockIdx.x * 64;
  const int n0 = blockIdx.y * 64;
  const int t = threadIdx.x;
  const int w = t >> 6, l = t & 63;
  const int wr = w >> 1, wc = w & 1;
  const int l15 = l & 15, l16 = l >> 4;

  __shared__ alignas(16) ushortT As[64][72];   // [m][k]
  __shared__ alignas(16) ushortT Bs[64][72];   // [n][k]

  f32x4 acc[2][2];
  #pragma unroll
  for (int mh = 0; mh < 2; ++mh)
    #pragma unroll
    for (int nh = 0; nh < 2; ++nh)
      #pragma unroll
      for (int r = 0; r < 4; ++r) acc[mh][nh][r] = 0.f;

  for (int k0 = 0; k0 < 256; k0 += 64) {
    #pragma unroll
    for (int rep = 0; rep < 16; ++rep) {
      int flat = rep * 256 + t;
      int r = flat >> 6, k = flat & 63;
      float v = A[(size_t)(m0 + r) * 256 + k0 + k];
      if constexpr (ROWSCALE) v *= rowscale[m0 + r];
      As[r][k] = f2bu(v);
    }
    #pragma unroll
    for (int rep = 0; rep < 16; ++rep) {
      int flat = rep * 256 + t;
      int k = flat >> 6, n = flat & 63;
      Bs[n][k] = f2bu(W[(size_t)(k0 + k) * 256 + n0 + n]);
    }
    __syncthreads();
    #pragma unroll
    for (int ks = 0; ks < 2; ++ks) {
      const int kb = ks * 32 + l16 * 8;
      bf16x8 afr[2], bfr[2];
      #pragma unroll
      for (int mh = 0; mh < 2; ++mh)
        afr[mh] = *reinterpret_cast<const bf16x8*>(&As[wr * 32 + mh * 16 + l15][kb]);
      #pragma unroll
      for (int nh = 0; nh < 2; ++nh)
        bfr[nh] = *reinterpret_cast<const bf16x8*>(&Bs[wc * 32 + nh * 16 + l15][kb]);
      #pragma unroll
      for (int mh = 0; mh < 2; ++mh)
        #pragma unroll
        for (int nh = 0; nh < 2; ++nh)
          acc[mh][nh] = __builtin_amdgcn_mfma_f32_16x16x32_bf16(
              afr[mh], bfr[nh], acc[mh][nh], 0, 0, 0);
    }
    __syncthreads();
  }
  if constexpr (STORE) {
    #pragma unroll
    for (int mh = 0; mh < 2; ++mh)
      #pragma unroll
      for (int nh = 0; nh < 2; ++nh)
        #pragma unroll
        for (int r = 0; r < 4; ++r) {
          const int row = m0 + wr * 32 + mh * 16 + l16 * 4 + r;
          const int col = n0 + wc * 32 + nh * 16 + l15;
          storeC(&C[(size_t)row * 256 + col], acc[mh][nh][r]);
        }
  }
  if constexpr (RED) {
    const float av0 = avec[l15], av1 = avec[16 + l15];
    #pragma unroll
    for (int mh = 0; mh < 2; ++mh)
      #pragma unroll
      for (int r = 0; r < 4; ++r) {
        float s = 0.f;
        {
          float x = acc[mh][0][r];
          s = fmaf(x > 0.f ? x : SLOPE * x, av0, s);
          x = acc[mh][1][r];
          s = fmaf(x > 0.f ? x : SLOPE * x, av1, s);
        }
        #pragma unroll
        for (int m = 8; m >= 1; m >>= 1) s += __shfl_xor(s, m, 64);
        if (l15 == 0) {
          const int row = m0 + wr * 32 + mh * 16 + l16 * 4 + r;
          SSo[(size_t)row * 8 + blockIdx.y * 2 + wc] = s;
        }
      }
  }
}

// ---------------------------------------------------------------------------
// Fused Wl/Wr GEMM: A staged once; SLg=RED(leaky(A@Wl)·al), GR1=A@Wr (store)
// + SRg=RED(leaky(A@Wr)·ar).
// ---------------------------------------------------------------------------
__global__ __launch_bounds__(256) void mfma_wlwr_kernel(
    const float* __restrict__ A,
    const float* __restrict__ Wl_, const float* __restrict__ Wr_,
    float* __restrict__ GR1,
    const float* __restrict__ al_, const float* __restrict__ ar_,
    float* __restrict__ SL, float* __restrict__ SR)
{
  const int m0 = blockIdx.x * 64;
  const int n0 = blockIdx.y * 64;
  const int t = threadIdx.x;
  const int w = t >> 6, l = t & 63;
  const int wr = w >> 1, wc = w & 1;
  const int l15 = l & 15, l16 = l >> 4;

  __shared__ alignas(16) ushortT As[64][72];
  __shared__ alignas(16) ushortT Bl[64][72];
  __shared__ alignas(16) ushortT Br[64][72];

  f32x4 accl[2][2], accr[2][2];
  #pragma unroll
  for (int mh = 0; mh < 2; ++mh)
    #pragma unroll
    for (int nh = 0; nh < 2; ++nh)
      #pragma unroll
      for (int r = 0; r < 4; ++r) { accl[mh][nh][r] = 0.f; accr[mh][nh][r] = 0.f; }

  for (int k0 = 0; k0 < 256; k0 += 64) {
    #pragma unroll
    for (int rep = 0; rep < 16; ++rep) {
      int flat = rep * 256 + t;
      int r = flat >> 6, k = flat & 63;
      As[r][k] = f2bu(A[(size_t)(m0 + r) * 256 + k0 + k]);
    }
    #pragma unroll
    for (int rep = 0; rep < 16; ++rep) {
      int flat = rep * 256 + t;
      int k = flat >> 6, n = flat & 63;
      Bl[n][k] = f2bu(Wl_[(size_t)(k0 + k) * 256 + n0 + n]);
      Br[n][k] = f2bu(Wr_[(size_t)(k0 + k) * 256 + n0 + n]);
    }
    __syncthreads();
    #pragma unroll
    for (int ks = 0; ks < 2; ++ks) {
      const int kb = ks * 32 + l16 * 8;
      bf16x8 afr[2], blr[2], brr[2];
      #pragma unroll
      for (int mh = 0; mh < 2; ++mh)
        afr[mh] = *reinterpret_cast<const bf16x8*>(&As[wr * 32 + mh * 16 + l15][kb]);
      #pragma unroll
      for (int nh = 0; nh < 2; ++nh) {
        blr[nh] = *reinterpret_cast<const bf16x8*>(&Bl[wc * 32 + nh * 16 + l15][kb]);
        brr[nh] = *reinterpret_cast<const bf16x8*>(&Br[wc * 32 + nh * 16 + l15][kb]);
      }
      #pragma unroll
      for (int mh = 0; mh < 2; ++mh)
        #pragma unroll
        for (int nh = 0; nh < 2; ++nh) {
          accl[mh][nh] = __builtin_amdgcn_mfma_f32_16x16x32_bf16(
              afr[mh], blr[nh], accl[mh][nh], 0, 0, 0);
          accr[mh][nh] = __builtin_amdgcn_mfma_f32_16x16x32_bf16(
              afr[mh], brr[nh], accr[mh][nh], 0, 0, 0);
        }
    }
    __syncthreads();
  }
  // store GR1 = A@Wr
  #pragma unroll
  for (int mh = 0; mh < 2; ++mh)
    #pragma unroll
    for (int nh = 0; nh < 2; ++nh)
      #pragma unroll
      for (int r = 0; r < 4; ++r) {
        const int row = m0 + wr * 32 + mh * 16 + l16 * 4 + r;
        const int col = n0 + wc * 32 + nh * 16 + l15;
        GR1[(size_t)row * 256 + col] = accr[mh][nh][r];
      }
  // RED both
  const float al0 = al_[l15], al1 = al_[16 + l15];
  const float ar0 = ar_[l15], ar1 = ar_[16 + l15];
  #pragma unroll
  for (int mh = 0; mh < 2; ++mh)
    #pragma unroll
    for (int r = 0; r < 4; ++r) {
      float sl = 0.f, sr = 0.f;
      {
        float x = accl[mh][0][r];
        sl = fmaf(x > 0.f ? x : SLOPE * x, al0, sl);
        x = accl[mh][1][r];
        sl = fmaf(x > 0.f ? x : SLOPE * x, al1, sl);
        x = accr[mh][0][r];
        sr = fmaf(x > 0.f ? x : SLOPE * x, ar0, sr);
        x = accr[mh][1][r];
        sr = fmaf(x > 0.f ? x : SLOPE * x, ar1, sr);
      }
      #pragma unroll
      for (int m = 8; m >= 1; m >>= 1) {
        sl += __shfl_xor(sl, m, 64);
        sr += __shfl_xor(sr, m, 64);
      }
      if (l15 == 0) {
        const int row = m0 + wr * 32 + mh * 16 + l16 * 4 + r;
        SL[(size_t)row * 8 + blockIdx.y * 2 + wc] = sl;
        SR[(size_t)row * 8 + blockIdx.y * 2 + wc] = sr;
      }
    }
}

// ---------------------------------------------------------------------------
// GCN aggregate (bf16 input, 2 nodes/block, column pairs)
// ---------------------------------------------------------------------------
__global__ __launch_bounds__(256) void agg2_kernel(
    const int* __restrict__ offs, const int* __restrict__ csr,
    const ushortT* __restrict__ X, const float* __restrict__ n_in,
    const float* __restrict__ bias, float* __restrict__ ghn,
    ushortT* __restrict__ ghb)
{
  const int n  = blockIdx.x * 2 + (threadIdx.x >> 7);
  const int tc = threadIdx.x & 127;
  const uintT* X2 = reinterpret_cast<const uintT*>(X);
  const int s0 = offs[n], s1 = offs[n + 1];
  float a0 = 0.f, a1 = 0.f;
  for (int i = s0; i < s1; ++i) {
    const uintT u = X2[(size_t)csr[i] * 128 + tc];
    a0 += blo(u);
    a1 += bhi(u);
  }
  const float ni = n_in[n];
  const float g0 = fmaxf(fmaf(a0, ni, bias[2 * tc]), 0.f);
  const float g1 = fmaxf(fmaf(a1, ni, bias[2 * tc + 1]), 0.f);
  float2 g2; g2.x = g0; g2.y = g1;
  reinterpret_cast<float2*>(ghn)[(size_t)n * 128 + tc] = g2;
  if (ghb)
    reinterpret_cast<uintT*>(ghb)[(size_t)n * 128 + tc] =
        (uintT)f2bu(g0) | ((uintT)f2bu(g1) << 16);
}

__global__ __launch_bounds__(256) void re_proj(
    const float* __restrict__ R, const float* __restrict__ n_out,
    const float* __restrict__ Wre, const float* __restrict__ wtre,
    const int* __restrict__ nt, float* __restrict__ rtmp)
{
  int g = blockIdx.x * 256 + threadIdx.x;  // NN*4
  int n = g >> 2, j = g & 3;
  float s = 0.f;
  #pragma unroll
  for (int c = 0; c < 4; ++c) s += R[n * 4 + c] * Wre[c * 4 + j];
  rtmp[g] = s * n_out[n] * wtre[nt[n]];
}
__global__ __launch_bounds__(256) void re_agg(
    const int* __restrict__ offs, const int* __restrict__ csr,
    const float* __restrict__ rtmp, const float* __restrict__ n_in,
    const float* __restrict__ bre, float* __restrict__ Rn)
{
  int g = blockIdx.x * 256 + threadIdx.x;  // NN*4
  int n = g >> 2, j = g & 3;
  float a = 0.f;
  for (int i = offs[n]; i < offs[n + 1]; ++i) a += rtmp[csr[i] * 4 + j];
  Rn[g] = fmaxf(fmaf(a, n_in[n], bre[j]), 0.f);
}
__global__ __launch_bounds__(256) void rkq_kernel(
    const float* __restrict__ R, const float* __restrict__ Wrs,
    const float* __restrict__ Wrt, float* __restrict__ RKQ)
{
  int g = blockIdx.x * 256 + threadIdx.x;  // NN*128
  int n = g >> 7, c = g & 127;
  int which = c >> 5, cc = c & 31;
  const float* Wp = (which == 0) ? Wrs : (which == 1) ? Wrt
                   : (which == 2) ? (Wrs + 128) : (Wrt + 128);
  float s = 0.f;
  #pragma unroll
  for (int r = 0; r < 4; ++r) s += R[n * 4 + r] * Wp[r * 32 + cc];
  RKQ[g] = s;
}

// ---------------------------------------------------------------------------
// weight prep: vecs[0]=g1@Wr2, [1]=b1@Wr2, [2]=g1@Wl2, [3]=b1@Wl2
// wg2i: interleaved bf16 of diag(g1)@W for mega MFMA B-operand.
// 8192 threads EXACTLY (ks in [0,8)) — 16384 would read 256 rows past W.
// ---------------------------------------------------------------------------
__global__ __launch_bounds__(256) void vec4_kernel(
    const float* __restrict__ ln_g, const float* __restrict__ ln_b,
    const float* __restrict__ Wr2, const float* __restrict__ Wl2,
    float* __restrict__ vecs)
{
  const int which = blockIdx.x, t = threadIdx.x;
  const float* W = (which < 2) ? Wr2 : Wl2;
  const float* s = (which & 1) ? ln_b : ln_g;
  float a = 0.f;
  for (int k = 0; k < 256; ++k) a = fmaf(s[k], W[(size_t)k * 256 + t], a);
  vecs[which * 256 + t] = a;
}
__global__ __launch_bounds__(256) void wg2i_kernel(
    const float* __restrict__ ln_g, const float* __restrict__ W,
    ushortT* __restrict__ Wi)
{
  const int gid = blockIdx.x * 256 + threadIdx.x;   // 8192
  const int ks  = gid >> 10;                        // [0,8)
  const int cgl = (gid >> 6) & 15;
  const int l   = gid & 63;
  const int col = cgl * 16 + (l & 15);
  const int kb  = ks * 32 + (l >> 4) * 8;
  ushortT v[8];
  #pragma unroll
  for (int e = 0; e < 8; ++e)
    v[e] = f2bu(ln_g[kb + e] * W[(size_t)(kb + e) * 256 + col]);
  *reinterpret_cast<bf16x8*>(&Wi[(size_t)gid * 8]) =
      *reinterpret_cast<const bf16x8*>(v);
}

// ---------------------------------------------------------------------------
// MEGA9: mega7 with fl2 moved onto the y-phase MFMA:
// Z = x @ Wgl2 (interleaved diag(g1)Wl2), keep row 0; fl2 = rs0*z0 - rm0*vl1
// + vl2. Deletes the 768-op serial fl2 VALU block.
// ---------------------------------------------------------------------------
__global__ __launch_bounds__(256) void mega9_kernel(
    const int* __restrict__ seqs,
    const ushortT* __restrict__ ghb,
    const ushortT* __restrict__ GW,
    const float* __restrict__ SLg, const float* __restrict__ SRg,
    const float* __restrict__ RKQ,
    const float* __restrict__ vecs,           // v1,v2,vl1,vl2
    const ushortT* __restrict__ Wg2i,         // interleaved diag(g1)Wr2
    const ushortT* __restrict__ Wgl2i,        // interleaved diag(g1)Wl2
    const float* __restrict__ al2, const float* __restrict__ ar2,
    const float* __restrict__ ln_g, const float* __restrict__ ln_b,
    float* __restrict__ h1r0buf, float* __restrict__ ctx2buf,
    float* __restrict__ out)
{
  __shared__ int idx[32];
  __shared__ alignas(16) ushortT bufA[10240];  // GT(GW^T, swz) -> FR2s[32][268]
  __shared__ alignas(16) ushortT bufB[10240];  // Pl[256][20u] swz -> xb[32][264]
  __shared__ float SRs[8][32];
  __shared__ float RQs[32][36];                // RQ1 then RQ2
  __shared__ float rk2s[32];
  __shared__ float part[32][4], partq[32][4];
  __shared__ float mu_s[32], rs_s[32];
  __shared__ float SR2s[8][32];
  __shared__ float sl2p[8][2];
  __shared__ float scp[8][32];
  __shared__ float h1r0s[256];
  __shared__ float wred4[4];
  __shared__ float nrm1s;

  const int b = blockIdx.x, t = threadIdx.x;
  const int h8 = t >> 5, lo = t & 31;
  const int w = t >> 6, l = t & 63;
  const int l15 = l & 15, l16 = l >> 4;

  if (t < 32) idx[t] = seqs[b * 32 + t];
  __syncthreads();                                             // B1

  const float sli = SLg[(size_t)idx[lo] * 8 + h8];
  const float rk0 = RKQ[(size_t)idx[lo] * 128 + h8 * 4 + 0];
  const float rk1 = RKQ[(size_t)idx[lo] * 128 + h8 * 4 + 1];
  const float rk2_ = RKQ[(size_t)idx[lo] * 128 + h8 * 4 + 2];
  const float rk3 = RKQ[(size_t)idx[lo] * 128 + h8 * 4 + 3];

  // ---- stage GT = GW^T (swizzled), SRs, RQ1, rk2s ----
  {
    const uintT* GWu = reinterpret_cast<const uintT*>(GW);
    #pragma unroll
    for (int rep = 0; rep < 16; ++rep) {
      int flat = rep * 256 + t;
      int j = flat >> 7, cp = flat & 127;
      const uintT u = GWu[(size_t)idx[j] * 128 + cp];
      const int rA = 2 * cp;
      const int k = (rA >> 3) & 3;
      const int off = (((j >> 3) ^ k) << 3) + (j & 7);
      bufA[rA * 40 + off]       = (ushortT)(u & 0xffffu);
      bufA[(rA + 1) * 40 + off] = (ushortT)(u >> 16);
    }
  }
  SRs[h8][lo] = SRg[(size_t)idx[lo] * 8 + h8];
  #pragma unroll
  for (int rep = 0; rep < 4; ++rep) {
    int flat = rep * 256 + t, s3 = flat >> 5, c3 = flat & 31;
    RQs[s3][c3] = RKQ[(size_t)idx[s3] * 128 + 32 + c3];
  }
  if (t < 32) rk2s[t] = RKQ[(size_t)idx[0] * 128 + 64 + t];
  __syncthreads();                                             // B2

  // ---- attn1 softmax -> Pl (swizzled bf16, b128 stores into bufB) ----
  {
    float p1[32];
    float m = -1e30f;
    #pragma unroll
    for (int j = 0; j < 32; ++j) {
      float sc = sli + SRs[h8][j]
               + rk0 * RQs[j][h8 * 4 + 0] + rk1 * RQs[j][h8 * 4 + 1]
               + rk2_ * RQs[j][h8 * 4 + 2] + rk3 * RQs[j][h8 * 4 + 3];
      p1[j] = sc; m = fmaxf(m, sc);
    }
    float sum = 0.f;
    #pragma unroll
    for (int j = 0; j < 32; ++j) { p1[j] = __expf(p1[j] - m); sum += p1[j]; }
    const float inv = 1.f / sum;
    const int row = t;
    const int k = (row >> 3) & 3;
    uintT* pw = reinterpret_cast<uintT*>(bufB) + row * 20;
    #pragma unroll
    for (int o = 0; o < 4; ++o) {
      uint4 v;
      v.x = (uintT)f2bu(p1[8 * o + 0] * inv) | ((uintT)f2bu(p1[8 * o + 1] * inv) << 16);
      v.y = (uintT)f2bu(p1[8 * o + 2] * inv) | ((uintT)f2bu(p1[8 * o + 3] * inv) << 16);
      v.z = (uintT)f2bu(p1[8 * o + 4] * inv) | ((uintT)f2bu(p1[8 * o + 5] * inv) << 16);
      v.w = (uintT)f2bu(p1[8 * o + 6] * inv) | ((uintT)f2bu(p1[8 * o + 7] * inv) << 16);
      *reinterpret_cast<uint4*>(pw + ((o ^ k) << 2)) = v;
    }
  }
  __syncthreads();                                             // B3

  int irow[2][4];
  #pragma unroll
  for (int mh = 0; mh < 2; ++mh)
    #pragma unroll
    for (int r = 0; r < 4; ++r)
      irow[mh][r] = idx[mh * 16 + l16 * 4 + r];

  // A-fragments (P) cached in registers
  bf16x8 af[2][2];
  #pragma unroll
  for (int hh = 0; hh < 2; ++hh) {
    const int h = 2 * w + hh;
    #pragma unroll
    for (int mh = 0; mh < 2; ++mh) {
      const int row = h * 32 + mh * 16 + l15;
      const int k = (row >> 3) & 3;
      af[hh][mh] = *reinterpret_cast<const bf16x8*>(&bufB[row * 40 + ((l16 ^ k) << 3)]);
    }
  }

  // ---- x phase: MFMA + ghb residual + LN stats + h1row0 stash ----
  f32x4 acc[2][2][2];
  #pragma unroll
  for (int hh = 0; hh < 2; ++hh) {
    const int h = 2 * w + hh;
    bf16x8 bf[2];
    #pragma unroll
    for (int nh = 0; nh < 2; ++nh) {
      const int row = h * 32 + nh * 16 + l15;
      const int k = (row >> 3) & 3;
      bf[nh] = *reinterpret_cast<const bf16x8*>(&bufA[row * 40 + ((l16 ^ k) << 3)]);
    }
    #pragma unroll
    for (int mh = 0; mh < 2; ++mh)
      #pragma unroll
      for (int nh = 0; nh < 2; ++nh) {
        f32x4 z = {0.f, 0.f, 0.f, 0.f};
        acc[hh][mh][nh] = __builtin_amdgcn_mfma_f32_16x16x32_bf16(af[hh][mh], bf[nh], z, 0, 0, 0);
      }
  }
  {
    float sum_[2][4], sq_[2][4];
    #pragma unroll
    for (int mh = 0; mh < 2; ++mh)
      #pragma unroll
      for (int r = 0; r < 4; ++r) { sum_[mh][r] = 0.f; sq_[mh][r] = 0.f; }
    #pragma unroll
    for (int hh = 0; hh < 2; ++hh)
      #pragma unroll
      for (int mh = 0; mh < 2; ++mh)
        #pragma unroll
        for (int nh = 0; nh < 2; ++nh) {
          const int col = (2 * w + hh) * 32 + nh * 16 + l15;
          #pragma unroll
          for (int r = 0; r < 4; ++r) {
            float v = acc[hh][mh][nh][r] + b2f(ghb[(size_t)irow[mh][r] * 256 + col]);
            acc[hh][mh][nh][r] = v;
            sum_[mh][r] += v;
            sq_[mh][r] = fmaf(v, v, sq_[mh][r]);
          }
        }
    #pragma unroll
    for (int mh = 0; mh < 2; ++mh)
      #pragma unroll
      for (int r = 0; r < 4; ++r) {
        float s = sum_[mh][r], q = sq_[mh][r];
        #pragma unroll
        for (int m = 8; m >= 1; m >>= 1) {
          s += __shfl_xor(s, m, 64);
          q += __shfl_xor(q, m, 64);
        }
        if (l15 == 0) {
          part[mh * 16 + l16 * 4 + r][w]  = s;
          partq[mh * 16 + l16 * 4 + r][w] = q;
        }
      }
    if (l16 == 0) {
      #pragma unroll
      for (int hh = 0; hh < 2; ++hh)
        #pragma unroll
        for (int nh = 0; nh < 2; ++nh)
          h1r0s[(2 * w + hh) * 32 + nh * 16 + l15] = acc[hh][0][nh][0];
    }
  }
  __syncthreads();                                             // B4

  if (t < 32) {
    float sm = part[t][0] + part[t][1] + part[t][2] + part[t][3];
    float sq = partq[t][0] + partq[t][1] + partq[t][2] + partq[t][3];
    const float m = sm * (1.f / 256.f);
    const float v = fmaxf(sq * (1.f / 256.f) - m * m, 0.f);
    mu_s[t] = m;
    rs_s[t] = rsqrtf(v + LN_EPS);
  }
  __syncthreads();                                             // B5

  // ---- xb = bf16(x) into bufB (Pl dead); RQ2; h1row0 LN + ret1 partials ----
  #pragma unroll
  for (int hh = 0; hh < 2; ++hh)
    #pragma unroll
    for (int mh = 0; mh < 2; ++mh)
      #pragma unroll
      for (int nh = 0; nh < 2; ++nh) {
        const int col = (2 * w + hh) * 32 + nh * 16 + l15;
        #pragma unroll
        for (int r = 0; r < 4; ++r) {
          const int row = mh * 16 + l16 * 4 + r;
          bufB[row * 264 + col] = f2bu(acc[hh][mh][nh][r]);
        }
      }
  #pragma unroll
  for (int rep = 0; rep < 4; ++rep) {
    int flat = rep * 256 + t, s3 = flat >> 5, c3 = flat & 31;
    RQs[s3][c3] = RKQ[(size_t)idx[s3] * 128 + 96 + c3];
  }
  {
    const float mu0 = mu_s[0], rs0 = rs_s[0];
    float hv = fmaf((h1r0s[t] - mu0) * rs0, ln_g[t], ln_b[t]);
    h1r0buf[(size_t)b * 256 + t] = hv;
    float sq = red64(hv * hv);
    h1r0s[t] = hv;
    if ((t & 63) == 0) wred4[t >> 6] = sq;
  }
  __syncthreads();                                             // B6

  if (t == 0) nrm1s = 1.f / fmaxf(sqrtf(wred4[0] + wred4[1] + wred4[2] + wred4[3]), 1e-12f);

  // ---- y phase: y = x@Wg2 (FR2/SR2) and Z = x@Wgl2 row0 (fl2/sl2), MFMA ----
  {
    f32x4 acc2[2][4];   // [mh][cg]  (wave owns cols w*64 .. w*64+63)
    f32x4 acc3[4];      // [cg] rows 0..15 of x@Wgl2 (mh=0 fragment)
    #pragma unroll
    for (int mh = 0; mh < 2; ++mh)
      #pragma unroll
      for (int cg = 0; cg < 4; ++cg)
        #pragma unroll
        for (int r = 0; r < 4; ++r) acc2[mh][cg][r] = 0.f;
    #pragma unroll
    for (int cg = 0; cg < 4; ++cg)
      #pragma unroll
      for (int r = 0; r < 4; ++r) acc3[cg][r] = 0.f;
    #pragma unroll
    for (int ks = 0; ks < 8; ++ks) {
      const int ko = ks * 32 + l16 * 8;
      bf16x8 a2[2];
      #pragma unroll
      for (int mh = 0; mh < 2; ++mh)
        a2[mh] = *reinterpret_cast<const bf16x8*>(&bufB[(mh * 16 + l15) * 264 + ko]);
      #pragma unroll
      for (int cg = 0; cg < 4; ++cg) {
        const size_t bidx = ((size_t)(ks * 16 + (w * 4 + cg)) * 64 + l) * 8;
        const bf16x8 b2 = *reinterpret_cast<const bf16x8*>(&Wg2i[bidx]);
        #pragma unroll
        for (int mh = 0; mh < 2; ++mh)
          acc2[mh][cg] = __builtin_amdgcn_mfma_f32_16x16x32_bf16(a2[mh], b2, acc2[mh][cg], 0, 0, 0);
        const bf16x8 b3 = *reinterpret_cast<const bf16x8*>(&Wgl2i[bidx]);
        acc3[cg] = __builtin_amdgcn_mfma_f32_16x16x32_bf16(a2[0], b3, acc3[cg], 0, 0, 0);
      }
    }
    // epilogue: FR2 + SR2
    float rsv[2][4], rmv[2][4];
    #pragma unroll
    for (int mh = 0; mh < 2; ++mh)
      #pragma unroll
      for (int r = 0; r < 4; ++r) {
        const int row = mh * 16 + l16 * 4 + r;
        rsv[mh][r] = rs_s[row];
        rmv[mh][r] = rsv[mh][r] * mu_s[row];
      }
    float sacc[2][2][4];   // [head-half][mh][r]
    #pragma unroll
    for (int hh = 0; hh < 2; ++hh)
      #pragma unroll
      for (int mh = 0; mh < 2; ++mh)
        #pragma unroll
        for (int r = 0; r < 4; ++r) sacc[hh][mh][r] = 0.f;
    float ar2v[2] = { ar2[l15], ar2[16 + l15] };
    #pragma unroll
    for (int cg = 0; cg < 4; ++cg) {
      const int col = w * 64 + cg * 16 + l15;
      const float v1c = vecs[col], v2c = vecs[256 + col];
      const int hh = cg >> 1;
      #pragma unroll
      for (int mh = 0; mh < 2; ++mh)
        #pragma unroll
        for (int r = 0; r < 4; ++r) {
          const int row = mh * 16 + l16 * 4 + r;
          float fa = fmaf(rsv[mh][r], acc2[mh][cg][r], fmaf(-rmv[mh][r], v1c, v2c));
          bufA[row * 268 + col] = f2bu(fa);       // FR2s[row][col]
          float lr = fa > 0.f ? fa : SLOPE * fa;
          sacc[hh][mh][r] = fmaf(lr, ar2v[cg & 1], sacc[hh][mh][r]);
        }
    }
    #pragma unroll
    for (int hh = 0; hh < 2; ++hh)
      #pragma unroll
      for (int mh = 0; mh < 2; ++mh)
        #pragma unroll
        for (int r = 0; r < 4; ++r) {
          float s = sacc[hh][mh][r];
          #pragma unroll
          for (int m = 8; m >= 1; m >>= 1) s += __shfl_xor(s, m, 64);
          if (l15 == 0) SR2s[2 * w + hh][mh * 16 + l16 * 4 + r] = s;
        }
    // epilogue: fl2 from Z row 0 (lanes l16==0 hold row 0 at r=0)
    if (l16 == 0) {
      const float rs0 = rs_s[0], rm0 = rs_s[0] * mu_s[0];
      #pragma unroll
      for (int cg = 0; cg < 4; ++cg) {
        const int col = w * 64 + cg * 16 + l15;
        float fl = fmaf(rs0, acc3[cg][0], fmaf(-rm0, vecs[512 + col], vecs[768 + col]));
        float lr = (fl > 0.f ? fl : SLOPE * fl) * al2[col & 31];
        #pragma unroll
        for (int m = 8; m >= 1; m >>= 1) lr += __shfl_xor(lr, m, 64);
        if (l15 == 0) sl2p[(w * 4 + cg) >> 1][cg & 1] = lr;
      }
    }
  }
  __syncthreads();                                             // B7

  // ---- attn2 row0 scores ----
  {
    float s2 = sl2p[h8][0] + sl2p[h8][1] + SR2s[h8][lo]
             + rk2s[h8 * 4 + 0] * RQs[lo][h8 * 4 + 0]
             + rk2s[h8 * 4 + 1] * RQs[lo][h8 * 4 + 1]
             + rk2s[h8 * 4 + 2] * RQs[lo][h8 * 4 + 2]
             + rk2s[h8 * 4 + 3] * RQs[lo][h8 * 4 + 3];
    const float m2 = max32(s2);
    const float e = __expf(s2 - m2);
    const float su = red32(e);
    scp[h8][lo] = e / su;
  }
  __syncthreads();                                             // B8

  // ---- ctx2 = p2 ◦ FR2 ; ret1 write ----
  {
    float a = 0.f;
    #pragma unroll
    for (int j = 0; j < 32; ++j) a = fmaf(scp[h8][j], b2f(bufA[j * 268 + t]), a);
    ctx2buf[(size_t)b * 256 + t] = a;
  }
  out[(size_t)b * 768 + 256 + t] = h1r0s[t] * nrm1s;
}

// ---------------------------------------------------------------------------
// LN + l2n epilogue over Y + res -> out[:,512:768]  (one row per block)
// ---------------------------------------------------------------------------
__global__ __launch_bounds__(256) void ln_l2n_kernel(
    const float* __restrict__ Y, const float* __restrict__ res,
    const float* __restrict__ lng, const float* __restrict__ lnb,
    float* __restrict__ out)
{
  const int row = blockIdx.x, t = threadIdx.x;
  __shared__ float s4[4], q4[4];
  const float y = Y[(size_t)row * 256 + t] + res[(size_t)row * 256 + t];
  float s = red64(y);
  float q = red64(y * y);
  if ((t & 63) == 0) { s4[t >> 6] = s; q4[t >> 6] = q; }
  __syncthreads();
  const float mu = (s4[0] + s4[1] + s4[2] + s4[3]) * (1.f / 256.f);
  const float var = fmaxf((q4[0] + q4[1] + q4[2] + q4[3]) * (1.f / 256.f) - mu * mu, 0.f);
  const float rstd = rsqrtf(var + LN_EPS);
  const float yn = fmaf((y - mu) * rstd, lng[t], lnb[t]);
  float nq = red64(yn * yn);
  __syncthreads();
  if ((t & 63) == 0) s4[t >> 6] = nq;
  __syncthreads();
  const float nrm = 1.f / fmaxf(sqrtf(s4[0] + s4[1] + s4[2] + s4[3]), 1e-12f);
  out[(size_t)row * 768 + 512 + t] = yn * nrm;
}

// ---------------------------------------------------------------------------
extern "C" void kernel_launch(void* const* d_in, const int* in_sizes, int n_in,
                              void* d_out, int out_size, void* d_ws, size_t ws_size,
                              hipStream_t stream)
{
  (void)in_sizes; (void)n_in; (void)out_size; (void)ws_size;

  const float* feat[4]; const float* wfc[4]; const float* bfc[4];
  for (int i = 0; i < 4; ++i) {
    feat[i] = (const float*)d_in[i * 3 + 0];
    wfc[i]  = (const float*)d_in[i * 3 + 1];
    bfc[i]  = (const float*)d_in[i * 3 + 2];
  }
  const float* type_emb = (const float*)d_in[12];
  const float* Wgcn = (const float*)d_in[13];
  const float* bgcn = (const float*)d_in[14];
  const float* Wre  = (const float*)d_in[15];
  const float* bre  = (const float*)d_in[16];
  const float* wtre = (const float*)d_in[17];
  const float* Wl   = (const float*)d_in[18];
  const float* Wr   = (const float*)d_in[19];
  const float* al   = (const float*)d_in[20];
  const float* ar   = (const float*)d_in[21];
  const float* Wrs  = (const float*)d_in[22];
  const float* Wrt  = (const float*)d_in[23];
  const float* Wfin = (const float*)d_in[24];
  const float* ln_g = (const float*)d_in[25];
  const float* ln_b = (const float*)d_in[26];
  const int* src       = (const int*)d_in[27];
  const int* dst       = (const int*)d_in[28];
  const int* node_type = (const int*)d_in[29];
  const int* seqs      = (const int*)d_in[30];
  float* out = (float*)d_out;

  // workspace carve-up (~45 MB)
  char* p = (char*)d_ws;
  auto take = [&](size_t n) { char* q = p; p += (n + 255) & ~(size_t)255; return q; };
  float* gh    = (float*)take((size_t)NN * 256 * 4);
  float* Xf    = (float*)take((size_t)NN * 256 * 4);   // ctx2buf
  float* GR1   = (float*)take((size_t)NN * 256 * 4);   // gh@Wr1, then h1r0buf
  float* RKQ   = (float*)take((size_t)NN * 128 * 4);
  float* SLg   = (float*)take((size_t)NN * 8 * 4);
  float* SRg   = (float*)take((size_t)NN * 8 * 4);
  float* n_out = (float*)take((size_t)NN * 4);
  float* n_in_ = (float*)take((size_t)NN * 4);
  int*   outc  = (int*)take((size_t)NN * 4);
  int*   inc   = (int*)take((size_t)NN * 4);
  int*   offs  = (int*)take((size_t)(NN + 1) * 4);
  int*   cur   = (int*)take((size_t)NN * 4);
  int*   csr   = (int*)take((size_t)(EE + NN) * 4);
  float* R     = (float*)take((size_t)NN * 4 * 4);
  float* rtmp  = (float*)take((size_t)NN * 4 * 4);
  ushortT* GW    = (ushortT*)take((size_t)NN * 256 * 2);
  ushortT* ghb   = (ushortT*)take((size_t)NN * 256 * 2);
  ushortT* Xb    = (ushortT*)take((size_t)NN * 256 * 2); // bf16 GCN scratch
  ushortT* Wg2i  = (ushortT*)take((size_t)65536 * 2);
  ushortT* Wgl2i = (ushortT*)take((size_t)65536 * 2);
  float* vecs  = (float*)take((size_t)4 * 256 * 4);
  float* ctx2buf = Xf;
  float* h1r0buf = GR1;    // alias: GR1 dead after GW table GEMM
  float* Yb      = gh;     // alias: gh dead after wlwr GEMM

  const float* Wr2 = Wr + 65536;
  const float* Wl2 = Wl + 65536;

  // 1) FC + ret0
  fc_kernel<<<256, 256, 0, stream>>>(feat[0], feat[1], feat[2], feat[3],
                                     wfc[0], wfc[1], wfc[2], wfc[3],
                                     bfc[0], bfc[1], bfc[2], bfc[3], gh, out);
  // 2) degrees + CSR (scan fused with norm/cur)
  zero_counts<<<64, 256, 0, stream>>>(outc, inc);
  count_deg<<<512, 256, 0, stream>>>(src, dst, outc, inc);
  scan_kernel<<<1, 1024, 0, stream>>>(inc, outc, offs, cur, n_out, n_in_);
  fill_csr<<<544, 256, 0, stream>>>(src, dst, cur, csr);
  init_R<<<128, 256, 0, stream>>>(type_emb, node_type, R);

  // weight prep (wg2i: 32 blocks = exactly 8192 valid fragments)
  vec4_kernel<<<4, 256, 0, stream>>>(ln_g, ln_b, Wr2, Wl2, vecs);
  wg2i_kernel<<<32, 256, 0, stream>>>(ln_g, Wr2, Wg2i);
  wg2i_kernel<<<32, 256, 0, stream>>>(ln_g, Wl2, Wgl2i);

  // 3) GCN + REConv, K=2  (GEMM -> bf16 Xb; agg reads bf16; k=1 emits ghb)
  for (int k = 0; k < 2; ++k) {
    mfma_gemm_kernel<true, true, false, ushortT>
        <<<dim3(128, 4), 256, 0, stream>>>(gh, Wgcn + (size_t)k * 65536,
                                           n_out, Xb, nullptr, nullptr);
    agg2_kernel<<<NN / 2, 256, 0, stream>>>(offs, csr, Xb, n_in_,
                                            bgcn + k * 256, gh,
                                            k == 1 ? ghb : nullptr);
    re_proj<<<128, 256, 0, stream>>>(R, n_out, Wre + k * 16, wtre + k * 4, node_type, rtmp);
    re_agg<<<128, 256, 0, stream>>>(offs, csr, rtmp, n_in_, bre + k * 4, R);
  }

  // 4) attention precomputes (fused Wl/Wr; GW table)
  rkq_kernel<<<4096, 256, 0, stream>>>(R, Wrs, Wrt, RKQ);
  mfma_wlwr_kernel<<<dim3(128, 4), 256, 0, stream>>>(
      gh, Wl, Wr, GR1, al, ar, SLg, SRg);
  mfma_gemm_kernel<false, true, false, ushortT>
      <<<dim3(128, 4), 256, 0, stream>>>(GR1, Wfin, nullptr, GW, nullptr, nullptr);

  // 5) fused transformer -> ret1, h1r0, ctx2
  mega9_kernel<<<NN, 256, 0, stream>>>(seqs, ghb, GW, SLg, SRg, RKQ, vecs,
                                       Wg2i, Wgl2i,
                                       al + 32, ar + 32, ln_g, ln_b,
                                       h1r0buf, ctx2buf, out);

  // 6) epilogue: Y = ctx2@Wfin2 (MFMA, M=8192 batched) ; ret2 = l2n(LN(h1r0+Y))
  mfma_gemm_kernel<false, true, false, float>
      <<<dim3(128, 4), 256, 0, stream>>>(ctx2buf, Wfin + 65536, nullptr,
                                         Yb, nullptr, nullptr);
  ln_l2n_kernel<<<NN, 256, 0, stream>>>(Yb, h1r0buf, ln_g + 256, ln_b + 256, out);
}

// Round 22
// 608.374 us; speedup vs baseline: 1.0012x; 1.0012x over previous
//
#include <hip/hip_runtime.h>
#include <hip/hip_bf16.h>
#include <cstdint>
#include <cstddef>

typedef unsigned short ushortT;
typedef unsigned int uintT;

using bf16x8 = __attribute__((ext_vector_type(8))) short;
using f32x4  = __attribute__((ext_vector_type(4))) float;

static constexpr int NN  = 8192;    // total nodes
static constexpr int EE  = 131072;  // edges
static constexpr float SLOPE  = 0.2f;
static constexpr float LN_EPS = 1e-5f;

#define DEVI __device__ __forceinline__

DEVI float red32(float v) {
  #pragma unroll
  for (int m = 16; m >= 1; m >>= 1) v += __shfl_xor(v, m, 64);
  return v;
}
DEVI float red64(float v) {
  #pragma unroll
  for (int m = 32; m >= 1; m >>= 1) v += __shfl_xor(v, m, 64);
  return v;
}
DEVI float max32(float v) {
  #pragma unroll
  for (int m = 16; m >= 1; m >>= 1) v = fmaxf(v, __shfl_xor(v, m, 64));
  return v;
}
DEVI float blo(uintT u) { union { uintT i; float f; } c; c.i = u << 16; return c.f; }
DEVI float bhi(uintT u) { union { uintT i; float f; } c; c.i = u & 0xffff0000u; return c.f; }
DEVI float b2f(ushortT u) { union { uintT i; float f; } c; c.i = ((uintT)u) << 16; return c.f; }
DEVI ushortT f2bu(float f) {
  __hip_bfloat16 h = __float2bfloat16(f);
  return *reinterpret_cast<ushortT*>(&h);
}
DEVI void storeC(float* p, float v) { *p = v; }
DEVI void storeC(ushortT* p, float v) { *p = f2bu(v); }

// ---------------------------------------------------------------------------
// FC: gh[n] = feat_t[n] @ Wfc_t + bfc_t ; out[n,0:256] = l2n(gh[n])
// ---------------------------------------------------------------------------
__global__ __launch_bounds__(256) void fc_kernel(
    const float* __restrict__ f0, const float* __restrict__ f1,
    const float* __restrict__ f2, const float* __restrict__ f3,
    const float* __restrict__ w0, const float* __restrict__ w1,
    const float* __restrict__ w2, const float* __restrict__ w3,
    const float* __restrict__ b0, const float* __restrict__ b1,
    const float* __restrict__ b2, const float* __restrict__ b3,
    float* __restrict__ gh, float* __restrict__ out)
{
  const int nb = blockIdx.x * 32;
  const int t  = threadIdx.x;
  int base, D;
  const float *F, *W, *Bv;
  if (nb < 4096)      { base = 0;    D = 128; F = f0; W = w0; Bv = b0; }
  else if (nb < 6144) { base = 4096; D = 64;  F = f1; W = w1; Bv = b1; }
  else if (nb < 7168) { base = 6144; D = 32;  F = f2; W = w2; Bv = b2; }
  else                { base = 7168; D = 16;  F = f3; W = w3; Bv = b3; }

  __shared__ float Fs[32 * 128];
  __shared__ float red[32][4];
  __shared__ float nrm[32];

  const int total = 32 * D;
  for (int i = t; i < total; i += 256) Fs[i] = F[(size_t)(nb - base) * D + i];
  __syncthreads();

  float acc[32];
  #pragma unroll
  for (int r = 0; r < 32; ++r) acc[r] = Bv[t];
  for (int d = 0; d < D; ++d) {
    float w = W[(size_t)d * 256 + t];
    #pragma unroll
    for (int r = 0; r < 32; ++r) acc[r] = fmaf(Fs[r * D + d], w, acc[r]);
  }

  const int lane = t & 63, wid = t >> 6;
  #pragma unroll
  for (int r = 0; r < 32; ++r) {
    float v = acc[r] * acc[r];
    for (int o = 32; o > 0; o >>= 1) v += __shfl_down(v, o, 64);
    if (lane == 0) red[r][wid] = v;
  }
  __syncthreads();
  if (t < 32) {
    float s = red[t][0] + red[t][1] + red[t][2] + red[t][3];
    nrm[t] = 1.0f / fmaxf(sqrtf(s), 1e-12f);
  }
  __syncthreads();
  #pragma unroll
  for (int r = 0; r < 32; ++r) {
    gh[(size_t)(nb + r) * 256 + t]  = acc[r];
    out[(size_t)(nb + r) * 768 + t] = acc[r] * nrm[r];
  }
}

// ---------------------------------------------------------------------------
// degree / CSR build
// ---------------------------------------------------------------------------
__global__ __launch_bounds__(256) void zero_counts(int* outc, int* inc) {
  int g = blockIdx.x * 256 + threadIdx.x;
  if (g < NN) outc[g] = 0; else inc[g - NN] = 0;
}
__global__ __launch_bounds__(256) void count_deg(const int* __restrict__ src,
                                                 const int* __restrict__ dst,
                                                 int* outc, int* inc) {
  int g = blockIdx.x * 256 + threadIdx.x;
  atomicAdd(&outc[src[g]], 1);
  atomicAdd(&inc[dst[g]], 1);
}
// scan + norm + cur in one
__global__ __launch_bounds__(1024) void scan_kernel(
    const int* __restrict__ inc, const int* __restrict__ outc,
    int* __restrict__ offs, int* __restrict__ cur,
    float* __restrict__ n_out, float* __restrict__ n_in)
{
  __shared__ int sums[1024];
  const int t = threadIdx.x;
  int x[8];
  const int base = t * 8;
  int s = 0;
  #pragma unroll
  for (int i = 0; i < 8; ++i) { int v = inc[base + i] + 1; x[i] = s; s += v; }
  sums[t] = s;
  __syncthreads();
  for (int off = 1; off < 1024; off <<= 1) {
    int a = (t >= off) ? sums[t - off] : 0;
    __syncthreads();
    sums[t] += a;
    __syncthreads();
  }
  const int pre = (t > 0) ? sums[t - 1] : 0;
  #pragma unroll
  for (int i = 0; i < 8; ++i) {
    const int o = pre + x[i];
    offs[base + i] = o;
    cur[base + i]  = o;
    n_in[base + i]  = rsqrtf((float)inc[base + i] + 1.0f);
    n_out[base + i] = rsqrtf((float)outc[base + i] + 1.0f);
  }
  if (t == 1023) offs[NN] = sums[1023];
}
__global__ __launch_bounds__(256) void fill_csr(const int* __restrict__ src,
                                                const int* __restrict__ dst,
                                                int* cur, int* __restrict__ csr) {
  int g = blockIdx.x * 256 + threadIdx.x;   // EE + NN total
  int s, d;
  if (g < EE) { s = src[g]; d = dst[g]; }
  else        { s = g - EE; d = g - EE; }   // self-loops
  int pos = atomicAdd(&cur[d], 1);
  csr[pos] = s;
}
__global__ __launch_bounds__(256) void init_R(const float* __restrict__ type_emb,
                                              const int* __restrict__ nt,
                                              float* __restrict__ R) {
  int g = blockIdx.x * 256 + threadIdx.x;   // NN*4
  int n = g >> 2, c = g & 3;
  R[g] = type_emb[nt[n] * 4 + c];
}

// ---------------------------------------------------------------------------
// MFMA GEMM (single B): C = (rowscale? diag(rs):I) A @ W ; optional RED
// ---------------------------------------------------------------------------
template<bool ROWSCALE, bool STORE, bool RED, typename CT>
__global__ __launch_bounds__(256) void mfma_gemm_kernel(
    const float* __restrict__ A, const float* __restrict__ W,
    const float* __restrict__ rowscale,
    CT* __restrict__ C, const float* __restrict__ avec,
    float* __restrict__ SSo)
{
  const int m0 = blockIdx.x * 64;
  const int n0 = blockIdx.y * 64;
  const int t = threadIdx.x;
  const int w = t >> 6, l = t & 63;
  const int wr = w >> 1, wc = w & 1;
  const int l15 = l & 15, l16 = l >> 4;

  __shared__ alignas(16) ushortT As[64][72];   // [m][k]
  __shared__ alignas(16) ushortT Bs[64][72];   // [n][k]

  f32x4 acc[2][2];
  #pragma unroll
  for (int mh = 0; mh < 2; ++mh)
    #pragma unroll
    for (int nh = 0; nh < 2; ++nh)
      #pragma unroll
      for (int r = 0; r < 4; ++r) acc[mh][nh][r] = 0.f;

  for (int k0 = 0; k0 < 256; k0 += 64) {
    #pragma unroll
    for (int rep = 0; rep < 16; ++rep) {
      int flat = rep * 256 + t;
      int r = flat >> 6, k = flat & 63;
      float v = A[(size_t)(m0 + r) * 256 + k0 + k];
      if constexpr (ROWSCALE) v *= rowscale[m0 + r];
      As[r][k] = f2bu(v);
    }
    #pragma unroll
    for (int rep = 0; rep < 16; ++rep) {
      int flat = rep * 256 + t;
      int k = flat >> 6, n = flat & 63;
      Bs[n][k] = f2bu(W[(size_t)(k0 + k) * 256 + n0 + n]);
    }
    __syncthreads();
    #pragma unroll
    for (int ks = 0; ks < 2; ++ks) {
      const int kb = ks * 32 + l16 * 8;
      bf16x8 afr[2], bfr[2];
      #pragma unroll
      for (int mh = 0; mh < 2; ++mh)
        afr[mh] = *reinterpret_cast<const bf16x8*>(&As[wr * 32 + mh * 16 + l15][kb]);
      #pragma unroll
      for (int nh = 0; nh < 2; ++nh)
        bfr[nh] = *reinterpret_cast<const bf16x8*>(&Bs[wc * 32 + nh * 16 + l15][kb]);
      #pragma unroll
      for (int mh = 0; mh < 2; ++mh)
        #pragma unroll
        for (int nh = 0; nh < 2; ++nh)
          acc[mh][nh] = __builtin_amdgcn_mfma_f32_16x16x32_bf16(
              afr[mh], bfr[nh], acc[mh][nh], 0, 0, 0);
    }
    __syncthreads();
  }
  if constexpr (STORE) {
    #pragma unroll
    for (int mh = 0; mh < 2; ++mh)
      #pragma unroll
      for (int nh = 0; nh < 2; ++nh)
        #pragma unroll
        for (int r = 0; r < 4; ++r) {
          const int row = m0 + wr * 32 + mh * 16 + l16 * 4 + r;
          const int col = n0 + wc * 32 + nh * 16 + l15;
          storeC(&C[(size_t)row * 256 + col], acc[mh][nh][r]);
        }
  }
  if constexpr (RED) {
    const float av0 = avec[l15], av1 = avec[16 + l15];
    #pragma unroll
    for (int mh = 0; mh < 2; ++mh)
      #pragma unroll
      for (int r = 0; r < 4; ++r) {
        float s = 0.f;
        {
          float x = acc[mh][0][r];
          s = fmaf(x > 0.f ? x : SLOPE * x, av0, s);
          x = acc[mh][1][r];
          s = fmaf(x > 0.f ? x : SLOPE * x, av1, s);
        }
        #pragma unroll
        for (int m = 8; m >= 1; m >>= 1) s += __shfl_xor(s, m, 64);
        if (l15 == 0) {
          const int row = m0 + wr * 32 + mh * 16 + l16 * 4 + r;
          SSo[(size_t)row * 8 + blockIdx.y * 2 + wc] = s;
        }
      }
  }
}

// ---------------------------------------------------------------------------
// Fused Wl/Wr GEMM: A staged once; SLg=RED(leaky(A@Wl)·al), GR1=A@Wr (store)
// + SRg=RED(leaky(A@Wr)·ar).
// ---------------------------------------------------------------------------
__global__ __launch_bounds__(256) void mfma_wlwr_kernel(
    const float* __restrict__ A,
    const float* __restrict__ Wl_, const float* __restrict__ Wr_,
    float* __restrict__ GR1,
    const float* __restrict__ al_, const float* __restrict__ ar_,
    float* __restrict__ SL, float* __restrict__ SR)
{
  const int m0 = blockIdx.x * 64;
  const int n0 = blockIdx.y * 64;
  const int t = threadIdx.x;
  const int w = t >> 6, l = t & 63;
  const int wr = w >> 1, wc = w & 1;
  const int l15 = l & 15, l16 = l >> 4;

  __shared__ alignas(16) ushortT As[64][72];
  __shared__ alignas(16) ushortT Bl[64][72];
  __shared__ alignas(16) ushortT Br[64][72];

  f32x4 accl[2][2], accr[2][2];
  #pragma unroll
  for (int mh = 0; mh < 2; ++mh)
    #pragma unroll
    for (int nh = 0; nh < 2; ++nh)
      #pragma unroll
      for (int r = 0; r < 4; ++r) { accl[mh][nh][r] = 0.f; accr[mh][nh][r] = 0.f; }

  for (int k0 = 0; k0 < 256; k0 += 64) {
    #pragma unroll
    for (int rep = 0; rep < 16; ++rep) {
      int flat = rep * 256 + t;
      int r = flat >> 6, k = flat & 63;
      As[r][k] = f2bu(A[(size_t)(m0 + r) * 256 + k0 + k]);
    }
    #pragma unroll
    for (int rep = 0; rep < 16; ++rep) {
      int flat = rep * 256 + t;
      int k = flat >> 6, n = flat & 63;
      Bl[n][k] = f2bu(Wl_[(size_t)(k0 + k) * 256 + n0 + n]);
      Br[n][k] = f2bu(Wr_[(size_t)(k0 + k) * 256 + n0 + n]);
    }
    __syncthreads();
    #pragma unroll
    for (int ks = 0; ks < 2; ++ks) {
      const int kb = ks * 32 + l16 * 8;
      bf16x8 afr[2], blr[2], brr[2];
      #pragma unroll
      for (int mh = 0; mh < 2; ++mh)
        afr[mh] = *reinterpret_cast<const bf16x8*>(&As[wr * 32 + mh * 16 + l15][kb]);
      #pragma unroll
      for (int nh = 0; nh < 2; ++nh) {
        blr[nh] = *reinterpret_cast<const bf16x8*>(&Bl[wc * 32 + nh * 16 + l15][kb]);
        brr[nh] = *reinterpret_cast<const bf16x8*>(&Br[wc * 32 + nh * 16 + l15][kb]);
      }
      #pragma unroll
      for (int mh = 0; mh < 2; ++mh)
        #pragma unroll
        for (int nh = 0; nh < 2; ++nh) {
          accl[mh][nh] = __builtin_amdgcn_mfma_f32_16x16x32_bf16(
              afr[mh], blr[nh], accl[mh][nh], 0, 0, 0);
          accr[mh][nh] = __builtin_amdgcn_mfma_f32_16x16x32_bf16(
              afr[mh], brr[nh], accr[mh][nh], 0, 0, 0);
        }
    }
    __syncthreads();
  }
  // store GR1 = A@Wr
  #pragma unroll
  for (int mh = 0; mh < 2; ++mh)
    #pragma unroll
    for (int nh = 0; nh < 2; ++nh)
      #pragma unroll
      for (int r = 0; r < 4; ++r) {
        const int row = m0 + wr * 32 + mh * 16 + l16 * 4 + r;
        const int col = n0 + wc * 32 + nh * 16 + l15;
        GR1[(size_t)row * 256 + col] = accr[mh][nh][r];
      }
  // RED both
  const float al0 = al_[l15], al1 = al_[16 + l15];
  const float ar0 = ar_[l15], ar1 = ar_[16 + l15];
  #pragma unroll
  for (int mh = 0; mh < 2; ++mh)
    #pragma unroll
    for (int r = 0; r < 4; ++r) {
      float sl = 0.f, sr = 0.f;
      {
        float x = accl[mh][0][r];
        sl = fmaf(x > 0.f ? x : SLOPE * x, al0, sl);
        x = accl[mh][1][r];
        sl = fmaf(x > 0.f ? x : SLOPE * x, al1, sl);
        x = accr[mh][0][r];
        sr = fmaf(x > 0.f ? x : SLOPE * x, ar0, sr);
        x = accr[mh][1][r];
        sr = fmaf(x > 0.f ? x : SLOPE * x, ar1, sr);
      }
      #pragma unroll
      for (int m = 8; m >= 1; m >>= 1) {
        sl += __shfl_xor(sl, m, 64);
        sr += __shfl_xor(sr, m, 64);
      }
      if (l15 == 0) {
        const int row = m0 + wr * 32 + mh * 16 + l16 * 4 + r;
        SL[(size_t)row * 8 + blockIdx.y * 2 + wc] = sl;
        SR[(size_t)row * 8 + blockIdx.y * 2 + wc] = sr;
      }
    }
}

// ---------------------------------------------------------------------------
// GCN aggregate (bf16 input, 2 nodes/block, column pairs)
// ---------------------------------------------------------------------------
__global__ __launch_bounds__(256) void agg2_kernel(
    const int* __restrict__ offs, const int* __restrict__ csr,
    const ushortT* __restrict__ X, const float* __restrict__ n_in,
    const float* __restrict__ bias, float* __restrict__ ghn,
    ushortT* __restrict__ ghb)
{
  const int n  = blockIdx.x * 2 + (threadIdx.x >> 7);
  const int tc = threadIdx.x & 127;
  const uintT* X2 = reinterpret_cast<const uintT*>(X);
  const int s0 = offs[n], s1 = offs[n + 1];
  float a0 = 0.f, a1 = 0.f;
  for (int i = s0; i < s1; ++i) {
    const uintT u = X2[(size_t)csr[i] * 128 + tc];
    a0 += blo(u);
    a1 += bhi(u);
  }
  const float ni = n_in[n];
  const float g0 = fmaxf(fmaf(a0, ni, bias[2 * tc]), 0.f);
  const float g1 = fmaxf(fmaf(a1, ni, bias[2 * tc + 1]), 0.f);
  float2 g2; g2.x = g0; g2.y = g1;
  reinterpret_cast<float2*>(ghn)[(size_t)n * 128 + tc] = g2;
  if (ghb)
    reinterpret_cast<uintT*>(ghb)[(size_t)n * 128 + tc] =
        (uintT)f2bu(g0) | ((uintT)f2bu(g1) << 16);
}

__global__ __launch_bounds__(256) void re_proj(
    const float* __restrict__ R, const float* __restrict__ n_out,
    const float* __restrict__ Wre, const float* __restrict__ wtre,
    const int* __restrict__ nt, float* __restrict__ rtmp)
{
  int g = blockIdx.x * 256 + threadIdx.x;  // NN*4
  int n = g >> 2, j = g & 3;
  float s = 0.f;
  #pragma unroll
  for (int c = 0; c < 4; ++c) s += R[n * 4 + c] * Wre[c * 4 + j];
  rtmp[g] = s * n_out[n] * wtre[nt[n]];
}
__global__ __launch_bounds__(256) void re_agg(
    const int* __restrict__ offs, const int* __restrict__ csr,
    const float* __restrict__ rtmp, const float* __restrict__ n_in,
    const float* __restrict__ bre, float* __restrict__ Rn)
{
  int g = blockIdx.x * 256 + threadIdx.x;  // NN*4
  int n = g >> 2, j = g & 3;
  float a = 0.f;
  for (int i = offs[n]; i < offs[n + 1]; ++i) a += rtmp[csr[i] * 4 + j];
  Rn[g] = fmaxf(fmaf(a, n_in[n], bre[j]), 0.f);
}
__global__ __launch_bounds__(256) void rkq_kernel(
    const float* __restrict__ R, const float* __restrict__ Wrs,
    const float* __restrict__ Wrt, float* __restrict__ RKQ)
{
  int g = blockIdx.x * 256 + threadIdx.x;  // NN*128
  int n = g >> 7, c = g & 127;
  int which = c >> 5, cc = c & 31;
  const float* Wp = (which == 0) ? Wrs : (which == 1) ? Wrt
                   : (which == 2) ? (Wrs + 128) : (Wrt + 128);
  float s = 0.f;
  #pragma unroll
  for (int r = 0; r < 4; ++r) s += R[n * 4 + r] * Wp[r * 32 + cc];
  RKQ[g] = s;
}

// ---------------------------------------------------------------------------
// weight prep: vecs[0]=g1@Wr2, [1]=b1@Wr2, [2]=g1@Wl2, [3]=b1@Wl2
// wg2i: interleaved bf16 of diag(g1)@W for mega MFMA B-operand.
// 8192 threads EXACTLY (ks in [0,8)) — 16384 would read 256 rows past W.
// ---------------------------------------------------------------------------
__global__ __launch_bounds__(256) void vec4_kernel(
    const float* __restrict__ ln_g, const float* __restrict__ ln_b,
    const float* __restrict__ Wr2, const float* __restrict__ Wl2,
    float* __restrict__ vecs)
{
  const int which = blockIdx.x, t = threadIdx.x;
  const float* W = (which < 2) ? Wr2 : Wl2;
  const float* s = (which & 1) ? ln_b : ln_g;
  float a = 0.f;
  for (int k = 0; k < 256; ++k) a = fmaf(s[k], W[(size_t)k * 256 + t], a);
  vecs[which * 256 + t] = a;
}
__global__ __launch_bounds__(256) void wg2i_kernel(
    const float* __restrict__ ln_g, const float* __restrict__ W,
    ushortT* __restrict__ Wi)
{
  const int gid = blockIdx.x * 256 + threadIdx.x;   // 8192
  const int ks  = gid >> 10;                        // [0,8)
  const int cgl = (gid >> 6) & 15;
  const int l   = gid & 63;
  const int col = cgl * 16 + (l & 15);
  const int kb  = ks * 32 + (l >> 4) * 8;
  ushortT v[8];
  #pragma unroll
  for (int e = 0; e < 8; ++e)
    v[e] = f2bu(ln_g[kb + e] * W[(size_t)(kb + e) * 256 + col]);
  *reinterpret_cast<bf16x8*>(&Wi[(size_t)gid * 8]) =
      *reinterpret_cast<const bf16x8*>(v);
}

// ---------------------------------------------------------------------------
// MEGA10: mega9 with the Z=x@Wgl2 MFMAs DE-INTERLEAVED from the y-loop:
// main acc2 loop is byte-identical to mega7's; Z runs as its own loop whose
// L2 loads overlap the FR2/SR2 VALU epilogue (separate pipes).
// ---------------------------------------------------------------------------
__global__ __launch_bounds__(256) void mega10_kernel(
    const int* __restrict__ seqs,
    const ushortT* __restrict__ ghb,
    const ushortT* __restrict__ GW,
    const float* __restrict__ SLg, const float* __restrict__ SRg,
    const float* __restrict__ RKQ,
    const float* __restrict__ vecs,           // v1,v2,vl1,vl2
    const ushortT* __restrict__ Wg2i,         // interleaved diag(g1)Wr2
    const ushortT* __restrict__ Wgl2i,        // interleaved diag(g1)Wl2
    const float* __restrict__ al2, const float* __restrict__ ar2,
    const float* __restrict__ ln_g, const float* __restrict__ ln_b,
    float* __restrict__ h1r0buf, float* __restrict__ ctx2buf,
    float* __restrict__ out)
{
  __shared__ int idx[32];
  __shared__ alignas(16) ushortT bufA[10240];  // GT(GW^T, swz) -> FR2s[32][268]
  __shared__ alignas(16) ushortT bufB[10240];  // Pl[256][20u] swz -> xb[32][264]
  __shared__ float SRs[8][32];
  __shared__ float RQs[32][36];                // RQ1 then RQ2
  __shared__ float rk2s[32];
  __shared__ float part[32][4], partq[32][4];
  __shared__ float mu_s[32], rs_s[32];
  __shared__ float SR2s[8][32];
  __shared__ float sl2p[8][2];
  __shared__ float scp[8][32];
  __shared__ float h1r0s[256];
  __shared__ float wred4[4];
  __shared__ float nrm1s;

  const int b = blockIdx.x, t = threadIdx.x;
  const int h8 = t >> 5, lo = t & 31;
  const int w = t >> 6, l = t & 63;
  const int l15 = l & 15, l16 = l >> 4;

  if (t < 32) idx[t] = seqs[b * 32 + t];
  __syncthreads();                                             // B1

  const float sli = SLg[(size_t)idx[lo] * 8 + h8];
  const float rk0 = RKQ[(size_t)idx[lo] * 128 + h8 * 4 + 0];
  const float rk1 = RKQ[(size_t)idx[lo] * 128 + h8 * 4 + 1];
  const float rk2_ = RKQ[(size_t)idx[lo] * 128 + h8 * 4 + 2];
  const float rk3 = RKQ[(size_t)idx[lo] * 128 + h8 * 4 + 3];

  // ---- stage GT = GW^T (swizzled), SRs, RQ1, rk2s ----
  {
    const uintT* GWu = reinterpret_cast<const uintT*>(GW);
    #pragma unroll
    for (int rep = 0; rep < 16; ++rep) {
      int flat = rep * 256 + t;
      int j = flat >> 7, cp = flat & 127;
      const uintT u = GWu[(size_t)idx[j] * 128 + cp];
      const int rA = 2 * cp;
      const int k = (rA >> 3) & 3;
      const int off = (((j >> 3) ^ k) << 3) + (j & 7);
      bufA[rA * 40 + off]       = (ushortT)(u & 0xffffu);
      bufA[(rA + 1) * 40 + off] = (ushortT)(u >> 16);
    }
  }
  SRs[h8][lo] = SRg[(size_t)idx[lo] * 8 + h8];
  #pragma unroll
  for (int rep = 0; rep < 4; ++rep) {
    int flat = rep * 256 + t, s3 = flat >> 5, c3 = flat & 31;
    RQs[s3][c3] = RKQ[(size_t)idx[s3] * 128 + 32 + c3];
  }
  if (t < 32) rk2s[t] = RKQ[(size_t)idx[0] * 128 + 64 + t];
  __syncthreads();                                             // B2

  // ---- attn1 softmax -> Pl (swizzled bf16, b128 stores into bufB) ----
  {
    float p1[32];
    float m = -1e30f;
    #pragma unroll
    for (int j = 0; j < 32; ++j) {
      float sc = sli + SRs[h8][j]
               + rk0 * RQs[j][h8 * 4 + 0] + rk1 * RQs[j][h8 * 4 + 1]
               + rk2_ * RQs[j][h8 * 4 + 2] + rk3 * RQs[j][h8 * 4 + 3];
      p1[j] = sc; m = fmaxf(m, sc);
    }
    float sum = 0.f;
    #pragma unroll
    for (int j = 0; j < 32; ++j) { p1[j] = __expf(p1[j] - m); sum += p1[j]; }
    const float inv = 1.f / sum;
    const int row = t;
    const int k = (row >> 3) & 3;
    uintT* pw = reinterpret_cast<uintT*>(bufB) + row * 20;
    #pragma unroll
    for (int o = 0; o < 4; ++o) {
      uint4 v;
      v.x = (uintT)f2bu(p1[8 * o + 0] * inv) | ((uintT)f2bu(p1[8 * o + 1] * inv) << 16);
      v.y = (uintT)f2bu(p1[8 * o + 2] * inv) | ((uintT)f2bu(p1[8 * o + 3] * inv) << 16);
      v.z = (uintT)f2bu(p1[8 * o + 4] * inv) | ((uintT)f2bu(p1[8 * o + 5] * inv) << 16);
      v.w = (uintT)f2bu(p1[8 * o + 6] * inv) | ((uintT)f2bu(p1[8 * o + 7] * inv) << 16);
      *reinterpret_cast<uint4*>(pw + ((o ^ k) << 2)) = v;
    }
  }
  __syncthreads();                                             // B3

  int irow[2][4];
  #pragma unroll
  for (int mh = 0; mh < 2; ++mh)
    #pragma unroll
    for (int r = 0; r < 4; ++r)
      irow[mh][r] = idx[mh * 16 + l16 * 4 + r];

  // A-fragments (P) cached in registers
  bf16x8 af[2][2];
  #pragma unroll
  for (int hh = 0; hh < 2; ++hh) {
    const int h = 2 * w + hh;
    #pragma unroll
    for (int mh = 0; mh < 2; ++mh) {
      const int row = h * 32 + mh * 16 + l15;
      const int k = (row >> 3) & 3;
      af[hh][mh] = *reinterpret_cast<const bf16x8*>(&bufB[row * 40 + ((l16 ^ k) << 3)]);
    }
  }

  // ---- x phase: MFMA + ghb residual + LN stats + h1row0 stash ----
  f32x4 acc[2][2][2];
  #pragma unroll
  for (int hh = 0; hh < 2; ++hh) {
    const int h = 2 * w + hh;
    bf16x8 bf[2];
    #pragma unroll
    for (int nh = 0; nh < 2; ++nh) {
      const int row = h * 32 + nh * 16 + l15;
      const int k = (row >> 3) & 3;
      bf[nh] = *reinterpret_cast<const bf16x8*>(&bufA[row * 40 + ((l16 ^ k) << 3)]);
    }
    #pragma unroll
    for (int mh = 0; mh < 2; ++mh)
      #pragma unroll
      for (int nh = 0; nh < 2; ++nh) {
        f32x4 z = {0.f, 0.f, 0.f, 0.f};
        acc[hh][mh][nh] = __builtin_amdgcn_mfma_f32_16x16x32_bf16(af[hh][mh], bf[nh], z, 0, 0, 0);
      }
  }
  {
    float sum_[2][4], sq_[2][4];
    #pragma unroll
    for (int mh = 0; mh < 2; ++mh)
      #pragma unroll
      for (int r = 0; r < 4; ++r) { sum_[mh][r] = 0.f; sq_[mh][r] = 0.f; }
    #pragma unroll
    for (int hh = 0; hh < 2; ++hh)
      #pragma unroll
      for (int mh = 0; mh < 2; ++mh)
        #pragma unroll
        for (int nh = 0; nh < 2; ++nh) {
          const int col = (2 * w + hh) * 32 + nh * 16 + l15;
          #pragma unroll
          for (int r = 0; r < 4; ++r) {
            float v = acc[hh][mh][nh][r] + b2f(ghb[(size_t)irow[mh][r] * 256 + col]);
            acc[hh][mh][nh][r] = v;
            sum_[mh][r] += v;
            sq_[mh][r] = fmaf(v, v, sq_[mh][r]);
          }
        }
    #pragma unroll
    for (int mh = 0; mh < 2; ++mh)
      #pragma unroll
      for (int r = 0; r < 4; ++r) {
        float s = sum_[mh][r], q = sq_[mh][r];
        #pragma unroll
        for (int m = 8; m >= 1; m >>= 1) {
          s += __shfl_xor(s, m, 64);
          q += __shfl_xor(q, m, 64);
        }
        if (l15 == 0) {
          part[mh * 16 + l16 * 4 + r][w]  = s;
          partq[mh * 16 + l16 * 4 + r][w] = q;
        }
      }
    if (l16 == 0) {
      #pragma unroll
      for (int hh = 0; hh < 2; ++hh)
        #pragma unroll
        for (int nh = 0; nh < 2; ++nh)
          h1r0s[(2 * w + hh) * 32 + nh * 16 + l15] = acc[hh][0][nh][0];
    }
  }
  __syncthreads();                                             // B4

  if (t < 32) {
    float sm = part[t][0] + part[t][1] + part[t][2] + part[t][3];
    float sq = partq[t][0] + partq[t][1] + partq[t][2] + partq[t][3];
    const float m = sm * (1.f / 256.f);
    const float v = fmaxf(sq * (1.f / 256.f) - m * m, 0.f);
    mu_s[t] = m;
    rs_s[t] = rsqrtf(v + LN_EPS);
  }
  __syncthreads();                                             // B5

  // ---- xb = bf16(x) into bufB (Pl dead); RQ2; h1row0 LN + ret1 partials ----
  #pragma unroll
  for (int hh = 0; hh < 2; ++hh)
    #pragma unroll
    for (int mh = 0; mh < 2; ++mh)
      #pragma unroll
      for (int nh = 0; nh < 2; ++nh) {
        const int col = (2 * w + hh) * 32 + nh * 16 + l15;
        #pragma unroll
        for (int r = 0; r < 4; ++r) {
          const int row = mh * 16 + l16 * 4 + r;
          bufB[row * 264 + col] = f2bu(acc[hh][mh][nh][r]);
        }
      }
  #pragma unroll
  for (int rep = 0; rep < 4; ++rep) {
    int flat = rep * 256 + t, s3 = flat >> 5, c3 = flat & 31;
    RQs[s3][c3] = RKQ[(size_t)idx[s3] * 128 + 96 + c3];
  }
  {
    const float mu0 = mu_s[0], rs0 = rs_s[0];
    float hv = fmaf((h1r0s[t] - mu0) * rs0, ln_g[t], ln_b[t]);
    h1r0buf[(size_t)b * 256 + t] = hv;
    float sq = red64(hv * hv);
    h1r0s[t] = hv;
    if ((t & 63) == 0) wred4[t >> 6] = sq;
  }
  __syncthreads();                                             // B6

  if (t == 0) nrm1s = 1.f / fmaxf(sqrtf(wred4[0] + wred4[1] + wred4[2] + wred4[3]), 1e-12f);

  // ---- y phase: y = x@Wg2 (identical schedule to mega7), then Z-loop ----
  {
    f32x4 acc2[2][4];   // [mh][cg]  (wave owns cols w*64 .. w*64+63)
    f32x4 acc3[4];      // [cg] rows 0..15 of x@Wgl2 (mh=0 fragment)
    #pragma unroll
    for (int mh = 0; mh < 2; ++mh)
      #pragma unroll
      for (int cg = 0; cg < 4; ++cg)
        #pragma unroll
        for (int r = 0; r < 4; ++r) acc2[mh][cg][r] = 0.f;
    #pragma unroll
    for (int cg = 0; cg < 4; ++cg)
      #pragma unroll
      for (int r = 0; r < 4; ++r) acc3[cg][r] = 0.f;
    #pragma unroll
    for (int ks = 0; ks < 8; ++ks) {
      const int ko = ks * 32 + l16 * 8;
      bf16x8 a2[2];
      #pragma unroll
      for (int mh = 0; mh < 2; ++mh)
        a2[mh] = *reinterpret_cast<const bf16x8*>(&bufB[(mh * 16 + l15) * 264 + ko]);
      #pragma unroll
      for (int cg = 0; cg < 4; ++cg) {
        const bf16x8 b2 = *reinterpret_cast<const bf16x8*>(
            &Wg2i[((size_t)(ks * 16 + (w * 4 + cg)) * 64 + l) * 8]);
        #pragma unroll
        for (int mh = 0; mh < 2; ++mh)
          acc2[mh][cg] = __builtin_amdgcn_mfma_f32_16x16x32_bf16(a2[mh], b2, acc2[mh][cg], 0, 0, 0);
      }
    }
    // Z-loop (separate; loads overlap the epilogue VALU below)
    #pragma unroll
    for (int ks = 0; ks < 8; ++ks) {
      const int ko = ks * 32 + l16 * 8;
      const bf16x8 a0 = *reinterpret_cast<const bf16x8*>(&bufB[l15 * 264 + ko]);
      #pragma unroll
      for (int cg = 0; cg < 4; ++cg) {
        const bf16x8 b3 = *reinterpret_cast<const bf16x8*>(
            &Wgl2i[((size_t)(ks * 16 + (w * 4 + cg)) * 64 + l) * 8]);
        acc3[cg] = __builtin_amdgcn_mfma_f32_16x16x32_bf16(a0, b3, acc3[cg], 0, 0, 0);
      }
    }
    // epilogue: FR2 + SR2
    float rsv[2][4], rmv[2][4];
    #pragma unroll
    for (int mh = 0; mh < 2; ++mh)
      #pragma unroll
      for (int r = 0; r < 4; ++r) {
        const int row = mh * 16 + l16 * 4 + r;
        rsv[mh][r] = rs_s[row];
        rmv[mh][r] = rsv[mh][r] * mu_s[row];
      }
    float sacc[2][2][4];   // [head-half][mh][r]
    #pragma unroll
    for (int hh = 0; hh < 2; ++hh)
      #pragma unroll
      for (int mh = 0; mh < 2; ++mh)
        #pragma unroll
        for (int r = 0; r < 4; ++r) sacc[hh][mh][r] = 0.f;
    float ar2v[2] = { ar2[l15], ar2[16 + l15] };
    #pragma unroll
    for (int cg = 0; cg < 4; ++cg) {
      const int col = w * 64 + cg * 16 + l15;
      const float v1c = vecs[col], v2c = vecs[256 + col];
      const int hh = cg >> 1;
      #pragma unroll
      for (int mh = 0; mh < 2; ++mh)
        #pragma unroll
        for (int r = 0; r < 4; ++r) {
          const int row = mh * 16 + l16 * 4 + r;
          float fa = fmaf(rsv[mh][r], acc2[mh][cg][r], fmaf(-rmv[mh][r], v1c, v2c));
          bufA[row * 268 + col] = f2bu(fa);       // FR2s[row][col]
          float lr = fa > 0.f ? fa : SLOPE * fa;
          sacc[hh][mh][r] = fmaf(lr, ar2v[cg & 1], sacc[hh][mh][r]);
        }
    }
    #pragma unroll
    for (int hh = 0; hh < 2; ++hh)
      #pragma unroll
      for (int mh = 0; mh < 2; ++mh)
        #pragma unroll
        for (int r = 0; r < 4; ++r) {
          float s = sacc[hh][mh][r];
          #pragma unroll
          for (int m = 8; m >= 1; m >>= 1) s += __shfl_xor(s, m, 64);
          if (l15 == 0) SR2s[2 * w + hh][mh * 16 + l16 * 4 + r] = s;
        }
    // epilogue: fl2 from Z row 0 (lanes l16==0 hold row 0 at r=0)
    if (l16 == 0) {
      const float rs0 = rs_s[0], rm0 = rs_s[0] * mu_s[0];
      #pragma unroll
      for (int cg = 0; cg < 4; ++cg) {
        const int col = w * 64 + cg * 16 + l15;
        float fl = fmaf(rs0, acc3[cg][0], fmaf(-rm0, vecs[512 + col], vecs[768 + col]));
        float lr = (fl > 0.f ? fl : SLOPE * fl) * al2[col & 31];
        #pragma unroll
        for (int m = 8; m >= 1; m >>= 1) lr += __shfl_xor(lr, m, 64);
        if (l15 == 0) sl2p[(w * 4 + cg) >> 1][cg & 1] = lr;
      }
    }
  }
  __syncthreads();                                             // B7

  // ---- attn2 row0 scores ----
  {
    float s2 = sl2p[h8][0] + sl2p[h8][1] + SR2s[h8][lo]
             + rk2s[h8 * 4 + 0] * RQs[lo][h8 * 4 + 0]
             + rk2s[h8 * 4 + 1] * RQs[lo][h8 * 4 + 1]
             + rk2s[h8 * 4 + 2] * RQs[lo][h8 * 4 + 2]
             + rk2s[h8 * 4 + 3] * RQs[lo][h8 * 4 + 3];
    const float m2 = max32(s2);
    const float e = __expf(s2 - m2);
    const float su = red32(e);
    scp[h8][lo] = e / su;
  }
  __syncthreads();                                             // B8

  // ---- ctx2 = p2 ◦ FR2 ; ret1 write ----
  {
    float a = 0.f;
    #pragma unroll
    for (int j = 0; j < 32; ++j) a = fmaf(scp[h8][j], b2f(bufA[j * 268 + t]), a);
    ctx2buf[(size_t)b * 256 + t] = a;
  }
  out[(size_t)b * 768 + 256 + t] = h1r0s[t] * nrm1s;
}

// ---------------------------------------------------------------------------
// LN + l2n epilogue over Y + res -> out[:,512:768]  (one row per block)
// ---------------------------------------------------------------------------
__global__ __launch_bounds__(256) void ln_l2n_kernel(
    const float* __restrict__ Y, const float* __restrict__ res,
    const float* __restrict__ lng, const float* __restrict__ lnb,
    float* __restrict__ out)
{
  const int row = blockIdx.x, t = threadIdx.x;
  __shared__ float s4[4], q4[4];
  const float y = Y[(size_t)row * 256 + t] + res[(size_t)row * 256 + t];
  float s = red64(y);
  float q = red64(y * y);
  if ((t & 63) == 0) { s4[t >> 6] = s; q4[t >> 6] = q; }
  __syncthreads();
  const float mu = (s4[0] + s4[1] + s4[2] + s4[3]) * (1.f / 256.f);
  const float var = fmaxf((q4[0] + q4[1] + q4[2] + q4[3]) * (1.f / 256.f) - mu * mu, 0.f);
  const float rstd = rsqrtf(var + LN_EPS);
  const float yn = fmaf((y - mu) * rstd, lng[t], lnb[t]);
  float nq = red64(yn * yn);
  __syncthreads();
  if ((t & 63) == 0) s4[t >> 6] = nq;
  __syncthreads();
  const float nrm = 1.f / fmaxf(sqrtf(s4[0] + s4[1] + s4[2] + s4[3]), 1e-12f);
  out[(size_t)row * 768 + 512 + t] = yn * nrm;
}

// ---------------------------------------------------------------------------
extern "C" void kernel_launch(void* const* d_in, const int* in_sizes, int n_in,
                              void* d_out, int out_size, void* d_ws, size_t ws_size,
                              hipStream_t stream)
{
  (void)in_sizes; (void)n_in; (void)out_size; (void)ws_size;

  const float* feat[4]; const float* wfc[4]; const float* bfc[4];
  for (int i = 0; i < 4; ++i) {
    feat[i] = (const float*)d_in[i * 3 + 0];
    wfc[i]  = (const float*)d_in[i * 3 + 1];
    bfc[i]  = (const float*)d_in[i * 3 + 2];
  }
  const float* type_emb = (const float*)d_in[12];
  const float* Wgcn = (const float*)d_in[13];
  const float* bgcn = (const float*)d_in[14];
  const float* Wre  = (const float*)d_in[15];
  const float* bre  = (const float*)d_in[16];
  const float* wtre = (const float*)d_in[17];
  const float* Wl   = (const float*)d_in[18];
  const float* Wr   = (const float*)d_in[19];
  const float* al   = (const float*)d_in[20];
  const float* ar   = (const float*)d_in[21];
  const float* Wrs  = (const float*)d_in[22];
  const float* Wrt  = (const float*)d_in[23];
  const float* Wfin = (const float*)d_in[24];
  const float* ln_g = (const float*)d_in[25];
  const float* ln_b = (const float*)d_in[26];
  const int* src       = (const int*)d_in[27];
  const int* dst       = (const int*)d_in[28];
  const int* node_type = (const int*)d_in[29];
  const int* seqs      = (const int*)d_in[30];
  float* out = (float*)d_out;

  // workspace carve-up (~45 MB)
  char* p = (char*)d_ws;
  auto take = [&](size_t n) { char* q = p; p += (n + 255) & ~(size_t)255; return q; };
  float* gh    = (float*)take((size_t)NN * 256 * 4);
  float* Xf    = (float*)take((size_t)NN * 256 * 4);   // ctx2buf
  float* GR1   = (float*)take((size_t)NN * 256 * 4);   // gh@Wr1, then h1r0buf
  float* RKQ   = (float*)take((size_t)NN * 128 * 4);
  float* SLg   = (float*)take((size_t)NN * 8 * 4);
  float* SRg   = (float*)take((size_t)NN * 8 * 4);
  float* n_out = (float*)take((size_t)NN * 4);
  float* n_in_ = (float*)take((size_t)NN * 4);
  int*   outc  = (int*)take((size_t)NN * 4);
  int*   inc   = (int*)take((size_t)NN * 4);
  int*   offs  = (int*)take((size_t)(NN + 1) * 4);
  int*   cur   = (int*)take((size_t)NN * 4);
  int*   csr   = (int*)take((size_t)(EE + NN) * 4);
  float* R     = (float*)take((size_t)NN * 4 * 4);
  float* rtmp  = (float*)take((size_t)NN * 4 * 4);
  ushortT* GW    = (ushortT*)take((size_t)NN * 256 * 2);
  ushortT* ghb   = (ushortT*)take((size_t)NN * 256 * 2);
  ushortT* Xb    = (ushortT*)take((size_t)NN * 256 * 2); // bf16 GCN scratch
  ushortT* Wg2i  = (ushortT*)take((size_t)65536 * 2);
  ushortT* Wgl2i = (ushortT*)take((size_t)65536 * 2);
  float* vecs  = (float*)take((size_t)4 * 256 * 4);
  float* ctx2buf = Xf;
  float* h1r0buf = GR1;    // alias: GR1 dead after GW table GEMM
  float* Yb      = gh;     // alias: gh dead after wlwr GEMM

  const float* Wr2 = Wr + 65536;
  const float* Wl2 = Wl + 65536;

  // 1) FC + ret0
  fc_kernel<<<256, 256, 0, stream>>>(feat[0], feat[1], feat[2], feat[3],
                                     wfc[0], wfc[1], wfc[2], wfc[3],
                                     bfc[0], bfc[1], bfc[2], bfc[3], gh, out);
  // 2) degrees + CSR (scan fused with norm/cur)
  zero_counts<<<64, 256, 0, stream>>>(outc, inc);
  count_deg<<<512, 256, 0, stream>>>(src, dst, outc, inc);
  scan_kernel<<<1, 1024, 0, stream>>>(inc, outc, offs, cur, n_out, n_in_);
  fill_csr<<<544, 256, 0, stream>>>(src, dst, cur, csr);
  init_R<<<128, 256, 0, stream>>>(type_emb, node_type, R);

  // weight prep (wg2i: 32 blocks = exactly 8192 valid fragments)
  vec4_kernel<<<4, 256, 0, stream>>>(ln_g, ln_b, Wr2, Wl2, vecs);
  wg2i_kernel<<<32, 256, 0, stream>>>(ln_g, Wr2, Wg2i);
  wg2i_kernel<<<32, 256, 0, stream>>>(ln_g, Wl2, Wgl2i);

  // 3) GCN + REConv, K=2  (GEMM -> bf16 Xb; agg reads bf16; k=1 emits ghb)
  for (int k = 0; k < 2; ++k) {
    mfma_gemm_kernel<true, true, false, ushortT>
        <<<dim3(128, 4), 256, 0, stream>>>(gh, Wgcn + (size_t)k * 65536,
                                           n_out, Xb, nullptr, nullptr);
    agg2_kernel<<<NN / 2, 256, 0, stream>>>(offs, csr, Xb, n_in_,
                                            bgcn + k * 256, gh,
                                            k == 1 ? ghb : nullptr);
    re_proj<<<128, 256, 0, stream>>>(R, n_out, Wre + k * 16, wtre + k * 4, node_type, rtmp);
    re_agg<<<128, 256, 0, stream>>>(offs, csr, rtmp, n_in_, bre + k * 4, R);
  }

  // 4) attention precomputes (fused Wl/Wr; GW table)
  rkq_kernel<<<4096, 256, 0, stream>>>(R, Wrs, Wrt, RKQ);
  mfma_wlwr_kernel<<<dim3(128, 4), 256, 0, stream>>>(
      gh, Wl, Wr, GR1, al, ar, SLg, SRg);
  mfma_gemm_kernel<false, true, false, ushortT>
      <<<dim3(128, 4), 256, 0, stream>>>(GR1, Wfin, nullptr, GW, nullptr, nullptr);

  // 5) fused transformer -> ret1, h1r0, ctx2
  mega10_kernel<<<NN, 256, 0, stream>>>(seqs, ghb, GW, SLg, SRg, RKQ, vecs,
                                        Wg2i, Wgl2i,
                                        al + 32, ar + 32, ln_g, ln_b,
                                        h1r0buf, ctx2buf, out);

  // 6) epilogue: Y = ctx2@Wfin2 (MFMA, M=8192 batched) ; ret2 = l2n(LN(h1r0+Y))
  mfma_gemm_kernel<false, true, false, float>
      <<<dim3(128, 4), 256, 0, stream>>>(ctx2buf, Wfin + 65536, nullptr,
                                         Yb, nullptr, nullptr);
  ln_l2n_kernel<<<NN, 256, 0, stream>>>(Yb, h1r0buf, ln_g + 256, ln_b + 256, out);
}

// Round 23
// 526.839 us; speedup vs baseline: 1.1562x; 1.1548x over previous
//
#include <hip/hip_runtime.h>
#include <hip/hip_bf16.h>
#include <cstdint>
#include <cstddef>

typedef unsigned short ushortT;
typedef unsigned int uintT;

using bf16x8 = __attribute__((ext_vector_type(8))) short;
using f32x4  = __attribute__((ext_vector_type(4))) float;

static constexpr int NN  = 8192;    // total nodes
static constexpr int EE  = 131072;  // edges
static constexpr float SLOPE  = 0.2f;
static constexpr float LN_EPS = 1e-5f;

#define DEVI __device__ __forceinline__

DEVI float red32(float v) {
  #pragma unroll
  for (int m = 16; m >= 1; m >>= 1) v += __shfl_xor(v, m, 64);
  return v;
}
DEVI float red64(float v) {
  #pragma unroll
  for (int m = 32; m >= 1; m >>= 1) v += __shfl_xor(v, m, 64);
  return v;
}
DEVI float max32(float v) {
  #pragma unroll
  for (int m = 16; m >= 1; m >>= 1) v = fmaxf(v, __shfl_xor(v, m, 64));
  return v;
}
DEVI float blo(uintT u) { union { uintT i; float f; } c; c.i = u << 16; return c.f; }
DEVI float bhi(uintT u) { union { uintT i; float f; } c; c.i = u & 0xffff0000u; return c.f; }
DEVI float b2f(ushortT u) { union { uintT i; float f; } c; c.i = ((uintT)u) << 16; return c.f; }
DEVI ushortT f2bu(float f) {
  __hip_bfloat16 h = __float2bfloat16(f);
  return *reinterpret_cast<ushortT*>(&h);
}
DEVI void storeC(float* p, float v) { *p = v; }
DEVI void storeC(ushortT* p, float v) { *p = f2bu(v); }

// ---------------------------------------------------------------------------
// FC: gh[n] = feat_t[n] @ Wfc_t + bfc_t ; out[n,0:256] = l2n(gh[n])
// ---------------------------------------------------------------------------
__global__ __launch_bounds__(256) void fc_kernel(
    const float* __restrict__ f0, const float* __restrict__ f1,
    const float* __restrict__ f2, const float* __restrict__ f3,
    const float* __restrict__ w0, const float* __restrict__ w1,
    const float* __restrict__ w2, const float* __restrict__ w3,
    const float* __restrict__ b0, const float* __restrict__ b1,
    const float* __restrict__ b2, const float* __restrict__ b3,
    float* __restrict__ gh, float* __restrict__ out)
{
  const int nb = blockIdx.x * 32;
  const int t  = threadIdx.x;
  int base, D;
  const float *F, *W, *Bv;
  if (nb < 4096)      { base = 0;    D = 128; F = f0; W = w0; Bv = b0; }
  else if (nb < 6144) { base = 4096; D = 64;  F = f1; W = w1; Bv = b1; }
  else if (nb < 7168) { base = 6144; D = 32;  F = f2; W = w2; Bv = b2; }
  else                { base = 7168; D = 16;  F = f3; W = w3; Bv = b3; }

  __shared__ float Fs[32 * 128];
  __shared__ float red[32][4];
  __shared__ float nrm[32];

  const int total = 32 * D;
  for (int i = t; i < total; i += 256) Fs[i] = F[(size_t)(nb - base) * D + i];
  __syncthreads();

  float acc[32];
  #pragma unroll
  for (int r = 0; r < 32; ++r) acc[r] = Bv[t];
  for (int d = 0; d < D; ++d) {
    float w = W[(size_t)d * 256 + t];
    #pragma unroll
    for (int r = 0; r < 32; ++r) acc[r] = fmaf(Fs[r * D + d], w, acc[r]);
  }

  const int lane = t & 63, wid = t >> 6;
  #pragma unroll
  for (int r = 0; r < 32; ++r) {
    float v = acc[r] * acc[r];
    for (int o = 32; o > 0; o >>= 1) v += __shfl_down(v, o, 64);
    if (lane == 0) red[r][wid] = v;
  }
  __syncthreads();
  if (t < 32) {
    float s = red[t][0] + red[t][1] + red[t][2] + red[t][3];
    nrm[t] = 1.0f / fmaxf(sqrtf(s), 1e-12f);
  }
  __syncthreads();
  #pragma unroll
  for (int r = 0; r < 32; ++r) {
    gh[(size_t)(nb + r) * 256 + t]  = acc[r];
    out[(size_t)(nb + r) * 768 + t] = acc[r] * nrm[r];
  }
}

// ---------------------------------------------------------------------------
// degree / CSR build
// ---------------------------------------------------------------------------
__global__ __launch_bounds__(256) void zero_counts(int* outc, int* inc) {
  int g = blockIdx.x * 256 + threadIdx.x;
  if (g < NN) outc[g] = 0; else inc[g - NN] = 0;
}
__global__ __launch_bounds__(256) void count_deg(const int* __restrict__ src,
                                                 const int* __restrict__ dst,
                                                 int* outc, int* inc) {
  int g = blockIdx.x * 256 + threadIdx.x;
  atomicAdd(&outc[src[g]], 1);
  atomicAdd(&inc[dst[g]], 1);
}
// scan + norm + cur in one
__global__ __launch_bounds__(1024) void scan_kernel(
    const int* __restrict__ inc, const int* __restrict__ outc,
    int* __restrict__ offs, int* __restrict__ cur,
    float* __restrict__ n_out, float* __restrict__ n_in)
{
  __shared__ int sums[1024];
  const int t = threadIdx.x;
  int x[8];
  const int base = t * 8;
  int s = 0;
  #pragma unroll
  for (int i = 0; i < 8; ++i) { int v = inc[base + i] + 1; x[i] = s; s += v; }
  sums[t] = s;
  __syncthreads();
  for (int off = 1; off < 1024; off <<= 1) {
    int a = (t >= off) ? sums[t - off] : 0;
    __syncthreads();
    sums[t] += a;
    __syncthreads();
  }
  const int pre = (t > 0) ? sums[t - 1] : 0;
  #pragma unroll
  for (int i = 0; i < 8; ++i) {
    const int o = pre + x[i];
    offs[base + i] = o;
    cur[base + i]  = o;
    n_in[base + i]  = rsqrtf((float)inc[base + i] + 1.0f);
    n_out[base + i] = rsqrtf((float)outc[base + i] + 1.0f);
  }
  if (t == 1023) offs[NN] = sums[1023];
}
__global__ __launch_bounds__(256) void fill_csr(const int* __restrict__ src,
                                                const int* __restrict__ dst,
                                                int* cur, int* __restrict__ csr) {
  int g = blockIdx.x * 256 + threadIdx.x;   // EE + NN total
  int s, d;
  if (g < EE) { s = src[g]; d = dst[g]; }
  else        { s = g - EE; d = g - EE; }   // self-loops
  int pos = atomicAdd(&cur[d], 1);
  csr[pos] = s;
}
__global__ __launch_bounds__(256) void init_R(const float* __restrict__ type_emb,
                                              const int* __restrict__ nt,
                                              float* __restrict__ R) {
  int g = blockIdx.x * 256 + threadIdx.x;   // NN*4
  int n = g >> 2, c = g & 3;
  R[g] = type_emb[nt[n] * 4 + c];
}

// ---------------------------------------------------------------------------
// MFMA GEMM (single B): C = (rowscale? diag(rs):I) A @ W ; optional RED
// ---------------------------------------------------------------------------
template<bool ROWSCALE, bool STORE, bool RED, typename CT>
__global__ __launch_bounds__(256) void mfma_gemm_kernel(
    const float* __restrict__ A, const float* __restrict__ W,
    const float* __restrict__ rowscale,
    CT* __restrict__ C, const float* __restrict__ avec,
    float* __restrict__ SSo)
{
  const int m0 = blockIdx.x * 64;
  const int n0 = blockIdx.y * 64;
  const int t = threadIdx.x;
  const int w = t >> 6, l = t & 63;
  const int wr = w >> 1, wc = w & 1;
  const int l15 = l & 15, l16 = l >> 4;

  __shared__ alignas(16) ushortT As[64][72];   // [m][k]
  __shared__ alignas(16) ushortT Bs[64][72];   // [n][k]

  f32x4 acc[2][2];
  #pragma unroll
  for (int mh = 0; mh < 2; ++mh)
    #pragma unroll
    for (int nh = 0; nh < 2; ++nh)
      #pragma unroll
      for (int r = 0; r < 4; ++r) acc[mh][nh][r] = 0.f;

  for (int k0 = 0; k0 < 256; k0 += 64) {
    #pragma unroll
    for (int rep = 0; rep < 16; ++rep) {
      int flat = rep * 256 + t;
      int r = flat >> 6, k = flat & 63;
      float v = A[(size_t)(m0 + r) * 256 + k0 + k];
      if constexpr (ROWSCALE) v *= rowscale[m0 + r];
      As[r][k] = f2bu(v);
    }
    #pragma unroll
    for (int rep = 0; rep < 16; ++rep) {
      int flat = rep * 256 + t;
      int k = flat >> 6, n = flat & 63;
      Bs[n][k] = f2bu(W[(size_t)(k0 + k) * 256 + n0 + n]);
    }
    __syncthreads();
    #pragma unroll
    for (int ks = 0; ks < 2; ++ks) {
      const int kb = ks * 32 + l16 * 8;
      bf16x8 afr[2], bfr[2];
      #pragma unroll
      for (int mh = 0; mh < 2; ++mh)
        afr[mh] = *reinterpret_cast<const bf16x8*>(&As[wr * 32 + mh * 16 + l15][kb]);
      #pragma unroll
      for (int nh = 0; nh < 2; ++nh)
        bfr[nh] = *reinterpret_cast<const bf16x8*>(&Bs[wc * 32 + nh * 16 + l15][kb]);
      #pragma unroll
      for (int mh = 0; mh < 2; ++mh)
        #pragma unroll
        for (int nh = 0; nh < 2; ++nh)
          acc[mh][nh] = __builtin_amdgcn_mfma_f32_16x16x32_bf16(
              afr[mh], bfr[nh], acc[mh][nh], 0, 0, 0);
    }
    __syncthreads();
  }
  if constexpr (STORE) {
    #pragma unroll
    for (int mh = 0; mh < 2; ++mh)
      #pragma unroll
      for (int nh = 0; nh < 2; ++nh)
        #pragma unroll
        for (int r = 0; r < 4; ++r) {
          const int row = m0 + wr * 32 + mh * 16 + l16 * 4 + r;
          const int col = n0 + wc * 32 + nh * 16 + l15;
          storeC(&C[(size_t)row * 256 + col], acc[mh][nh][r]);
        }
  }
  if constexpr (RED) {
    const float av0 = avec[l15], av1 = avec[16 + l15];
    #pragma unroll
    for (int mh = 0; mh < 2; ++mh)
      #pragma unroll
      for (int r = 0; r < 4; ++r) {
        float s = 0.f;
        {
          float x = acc[mh][0][r];
          s = fmaf(x > 0.f ? x : SLOPE * x, av0, s);
          x = acc[mh][1][r];
          s = fmaf(x > 0.f ? x : SLOPE * x, av1, s);
        }
        #pragma unroll
        for (int m = 8; m >= 1; m >>= 1) s += __shfl_xor(s, m, 64);
        if (l15 == 0) {
          const int row = m0 + wr * 32 + mh * 16 + l16 * 4 + r;
          SSo[(size_t)row * 8 + blockIdx.y * 2 + wc] = s;
        }
      }
  }
}

// ---------------------------------------------------------------------------
// Fused Wl/Wr GEMM: A staged once; SLg=RED(leaky(A@Wl)·al), GR1=A@Wr (store)
// + SRg=RED(leaky(A@Wr)·ar).
// ---------------------------------------------------------------------------
__global__ __launch_bounds__(256) void mfma_wlwr_kernel(
    const float* __restrict__ A,
    const float* __restrict__ Wl_, const float* __restrict__ Wr_,
    float* __restrict__ GR1,
    const float* __restrict__ al_, const float* __restrict__ ar_,
    float* __restrict__ SL, float* __restrict__ SR)
{
  const int m0 = blockIdx.x * 64;
  const int n0 = blockIdx.y * 64;
  const int t = threadIdx.x;
  const int w = t >> 6, l = t & 63;
  const int wr = w >> 1, wc = w & 1;
  const int l15 = l & 15, l16 = l >> 4;

  __shared__ alignas(16) ushortT As[64][72];
  __shared__ alignas(16) ushortT Bl[64][72];
  __shared__ alignas(16) ushortT Br[64][72];

  f32x4 accl[2][2], accr[2][2];
  #pragma unroll
  for (int mh = 0; mh < 2; ++mh)
    #pragma unroll
    for (int nh = 0; nh < 2; ++nh)
      #pragma unroll
      for (int r = 0; r < 4; ++r) { accl[mh][nh][r] = 0.f; accr[mh][nh][r] = 0.f; }

  for (int k0 = 0; k0 < 256; k0 += 64) {
    #pragma unroll
    for (int rep = 0; rep < 16; ++rep) {
      int flat = rep * 256 + t;
      int r = flat >> 6, k = flat & 63;
      As[r][k] = f2bu(A[(size_t)(m0 + r) * 256 + k0 + k]);
    }
    #pragma unroll
    for (int rep = 0; rep < 16; ++rep) {
      int flat = rep * 256 + t;
      int k = flat >> 6, n = flat & 63;
      Bl[n][k] = f2bu(Wl_[(size_t)(k0 + k) * 256 + n0 + n]);
      Br[n][k] = f2bu(Wr_[(size_t)(k0 + k) * 256 + n0 + n]);
    }
    __syncthreads();
    #pragma unroll
    for (int ks = 0; ks < 2; ++ks) {
      const int kb = ks * 32 + l16 * 8;
      bf16x8 afr[2], blr[2], brr[2];
      #pragma unroll
      for (int mh = 0; mh < 2; ++mh)
        afr[mh] = *reinterpret_cast<const bf16x8*>(&As[wr * 32 + mh * 16 + l15][kb]);
      #pragma unroll
      for (int nh = 0; nh < 2; ++nh) {
        blr[nh] = *reinterpret_cast<const bf16x8*>(&Bl[wc * 32 + nh * 16 + l15][kb]);
        brr[nh] = *reinterpret_cast<const bf16x8*>(&Br[wc * 32 + nh * 16 + l15][kb]);
      }
      #pragma unroll
      for (int mh = 0; mh < 2; ++mh)
        #pragma unroll
        for (int nh = 0; nh < 2; ++nh) {
          accl[mh][nh] = __builtin_amdgcn_mfma_f32_16x16x32_bf16(
              afr[mh], blr[nh], accl[mh][nh], 0, 0, 0);
          accr[mh][nh] = __builtin_amdgcn_mfma_f32_16x16x32_bf16(
              afr[mh], brr[nh], accr[mh][nh], 0, 0, 0);
        }
    }
    __syncthreads();
  }
  // store GR1 = A@Wr
  #pragma unroll
  for (int mh = 0; mh < 2; ++mh)
    #pragma unroll
    for (int nh = 0; nh < 2; ++nh)
      #pragma unroll
      for (int r = 0; r < 4; ++r) {
        const int row = m0 + wr * 32 + mh * 16 + l16 * 4 + r;
        const int col = n0 + wc * 32 + nh * 16 + l15;
        GR1[(size_t)row * 256 + col] = accr[mh][nh][r];
      }
  // RED both
  const float al0 = al_[l15], al1 = al_[16 + l15];
  const float ar0 = ar_[l15], ar1 = ar_[16 + l15];
  #pragma unroll
  for (int mh = 0; mh < 2; ++mh)
    #pragma unroll
    for (int r = 0; r < 4; ++r) {
      float sl = 0.f, sr = 0.f;
      {
        float x = accl[mh][0][r];
        sl = fmaf(x > 0.f ? x : SLOPE * x, al0, sl);
        x = accl[mh][1][r];
        sl = fmaf(x > 0.f ? x : SLOPE * x, al1, sl);
        x = accr[mh][0][r];
        sr = fmaf(x > 0.f ? x : SLOPE * x, ar0, sr);
        x = accr[mh][1][r];
        sr = fmaf(x > 0.f ? x : SLOPE * x, ar1, sr);
      }
      #pragma unroll
      for (int m = 8; m >= 1; m >>= 1) {
        sl += __shfl_xor(sl, m, 64);
        sr += __shfl_xor(sr, m, 64);
      }
      if (l15 == 0) {
        const int row = m0 + wr * 32 + mh * 16 + l16 * 4 + r;
        SL[(size_t)row * 8 + blockIdx.y * 2 + wc] = sl;
        SR[(size_t)row * 8 + blockIdx.y * 2 + wc] = sr;
      }
    }
}

// ---------------------------------------------------------------------------
// GCN aggregate (bf16 input, 2 nodes/block, column pairs)
// ---------------------------------------------------------------------------
__global__ __launch_bounds__(256) void agg2_kernel(
    const int* __restrict__ offs, const int* __restrict__ csr,
    const ushortT* __restrict__ X, const float* __restrict__ n_in,
    const float* __restrict__ bias, float* __restrict__ ghn,
    ushortT* __restrict__ ghb)
{
  const int n  = blockIdx.x * 2 + (threadIdx.x >> 7);
  const int tc = threadIdx.x & 127;
  const uintT* X2 = reinterpret_cast<const uintT*>(X);
  const int s0 = offs[n], s1 = offs[n + 1];
  float a0 = 0.f, a1 = 0.f;
  for (int i = s0; i < s1; ++i) {
    const uintT u = X2[(size_t)csr[i] * 128 + tc];
    a0 += blo(u);
    a1 += bhi(u);
  }
  const float ni = n_in[n];
  const float g0 = fmaxf(fmaf(a0, ni, bias[2 * tc]), 0.f);
  const float g1 = fmaxf(fmaf(a1, ni, bias[2 * tc + 1]), 0.f);
  float2 g2; g2.x = g0; g2.y = g1;
  reinterpret_cast<float2*>(ghn)[(size_t)n * 128 + tc] = g2;
  if (ghb)
    reinterpret_cast<uintT*>(ghb)[(size_t)n * 128 + tc] =
        (uintT)f2bu(g0) | ((uintT)f2bu(g1) << 16);
}

__global__ __launch_bounds__(256) void re_proj(
    const float* __restrict__ R, const float* __restrict__ n_out,
    const float* __restrict__ Wre, const float* __restrict__ wtre,
    const int* __restrict__ nt, float* __restrict__ rtmp)
{
  int g = blockIdx.x * 256 + threadIdx.x;  // NN*4
  int n = g >> 2, j = g & 3;
  float s = 0.f;
  #pragma unroll
  for (int c = 0; c < 4; ++c) s += R[n * 4 + c] * Wre[c * 4 + j];
  rtmp[g] = s * n_out[n] * wtre[nt[n]];
}
__global__ __launch_bounds__(256) void re_agg(
    const int* __restrict__ offs, const int* __restrict__ csr,
    const float* __restrict__ rtmp, const float* __restrict__ n_in,
    const float* __restrict__ bre, float* __restrict__ Rn)
{
  int g = blockIdx.x * 256 + threadIdx.x;  // NN*4
  int n = g >> 2, j = g & 3;
  float a = 0.f;
  for (int i = offs[n]; i < offs[n + 1]; ++i) a += rtmp[csr[i] * 4 + j];
  Rn[g] = fmaxf(fmaf(a, n_in[n], bre[j]), 0.f);
}
__global__ __launch_bounds__(256) void rkq_kernel(
    const float* __restrict__ R, const float* __restrict__ Wrs,
    const float* __restrict__ Wrt, float* __restrict__ RKQ)
{
  int g = blockIdx.x * 256 + threadIdx.x;  // NN*128
  int n = g >> 7, c = g & 127;
  int which = c >> 5, cc = c & 31;
  const float* Wp = (which == 0) ? Wrs : (which == 1) ? Wrt
                   : (which == 2) ? (Wrs + 128) : (Wrt + 128);
  float s = 0.f;
  #pragma unroll
  for (int r = 0; r < 4; ++r) s += R[n * 4 + r] * Wp[r * 32 + cc];
  RKQ[g] = s;
}

// ---------------------------------------------------------------------------
// weight prep
// ---------------------------------------------------------------------------
__global__ __launch_bounds__(256) void vec4_kernel(
    const float* __restrict__ ln_g, const float* __restrict__ ln_b,
    const float* __restrict__ Wr2, float* __restrict__ vecs)
{
  const int which = blockIdx.x, t = threadIdx.x;
  const float* s = (which & 1) ? ln_b : ln_g;
  float a = 0.f;
  for (int k = 0; k < 256; ++k) a = fmaf(s[k], Wr2[(size_t)k * 256 + t], a);
  vecs[which * 256 + t] = a;
}
__global__ __launch_bounds__(256) void wg2i_kernel(
    const float* __restrict__ ln_g, const float* __restrict__ Wr2,
    ushortT* __restrict__ Wg2i)
{
  const int gid = blockIdx.x * 256 + threadIdx.x;   // 8192
  const int ks  = gid >> 10;                        // [0,8)
  const int cgl = (gid >> 6) & 15;
  const int l   = gid & 63;
  const int col = cgl * 16 + (l & 15);
  const int kb  = ks * 32 + (l >> 4) * 8;
  ushortT v[8];
  #pragma unroll
  for (int e = 0; e < 8; ++e)
    v[e] = f2bu(ln_g[kb + e] * Wr2[(size_t)(kb + e) * 256 + col]);
  *reinterpret_cast<bf16x8*>(&Wg2i[(size_t)gid * 8]) =
      *reinterpret_cast<const bf16x8*>(v);
}
__global__ __launch_bounds__(256) void wl2b_kernel(
    const float* __restrict__ Wl2, ushortT* __restrict__ Wl2b)
{
  int g = blockIdx.x * 256 + threadIdx.x;   // 65536
  Wl2b[g] = f2bu(Wl2[g]);
}

// ---------------------------------------------------------------------------
// MEGA7 (verified round-15/17/19 version)
// ---------------------------------------------------------------------------
__global__ __launch_bounds__(256) void mega7_kernel(
    const int* __restrict__ seqs,
    const ushortT* __restrict__ ghb,
    const ushortT* __restrict__ GW,
    const float* __restrict__ SLg, const float* __restrict__ SRg,
    const float* __restrict__ RKQ,
    const float* __restrict__ vecs,           // v1,v2
    const ushortT* __restrict__ Wg2i,         // interleaved bf16
    const ushortT* __restrict__ Wl2b,         // [k][col] bf16
    const float* __restrict__ al2, const float* __restrict__ ar2,
    const float* __restrict__ ln_g, const float* __restrict__ ln_b,
    float* __restrict__ h1r0buf, float* __restrict__ ctx2buf,
    float* __restrict__ out)
{
  __shared__ int idx[32];
  __shared__ alignas(16) ushortT bufA[10240];  // GT(GW^T, swz) -> FR2s[32][268]
  __shared__ alignas(16) ushortT bufB[10240];  // Pl[256][20u] swz -> xb[32][264]
  __shared__ float SRs[8][32];
  __shared__ float RQs[32][36];                // RQ1 then RQ2
  __shared__ float rk2s[32];
  __shared__ float part[32][4], partq[32][4];
  __shared__ float mu_s[32], rs_s[32];
  __shared__ float SR2s[8][32];
  __shared__ float sl2s[8];
  __shared__ float scp[8][32];
  __shared__ float h1r0s[256];
  __shared__ float wred4[4];
  __shared__ float nrm1s;

  const int b = blockIdx.x, t = threadIdx.x;
  const int h8 = t >> 5, lo = t & 31;
  const int w = t >> 6, l = t & 63;
  const int l15 = l & 15, l16 = l >> 4;

  if (t < 32) idx[t] = seqs[b * 32 + t];
  __syncthreads();                                             // B1

  const float sli = SLg[(size_t)idx[lo] * 8 + h8];
  const float rk0 = RKQ[(size_t)idx[lo] * 128 + h8 * 4 + 0];
  const float rk1 = RKQ[(size_t)idx[lo] * 128 + h8 * 4 + 1];
  const float rk2_ = RKQ[(size_t)idx[lo] * 128 + h8 * 4 + 2];
  const float rk3 = RKQ[(size_t)idx[lo] * 128 + h8 * 4 + 3];

  // ---- stage GT = GW^T (swizzled), SRs, RQ1, rk2s ----
  {
    const uintT* GWu = reinterpret_cast<const uintT*>(GW);
    #pragma unroll
    for (int rep = 0; rep < 16; ++rep) {
      int flat = rep * 256 + t;
      int j = flat >> 7, cp = flat & 127;
      const uintT u = GWu[(size_t)idx[j] * 128 + cp];
      const int rA = 2 * cp;
      const int k = (rA >> 3) & 3;
      const int off = (((j >> 3) ^ k) << 3) + (j & 7);
      bufA[rA * 40 + off]       = (ushortT)(u & 0xffffu);
      bufA[(rA + 1) * 40 + off] = (ushortT)(u >> 16);
    }
  }
  SRs[h8][lo] = SRg[(size_t)idx[lo] * 8 + h8];
  #pragma unroll
  for (int rep = 0; rep < 4; ++rep) {
    int flat = rep * 256 + t, s3 = flat >> 5, c3 = flat & 31;
    RQs[s3][c3] = RKQ[(size_t)idx[s3] * 128 + 32 + c3];
  }
  if (t < 32) rk2s[t] = RKQ[(size_t)idx[0] * 128 + 64 + t];
  __syncthreads();                                             // B2

  // ---- attn1 softmax -> Pl (swizzled bf16, b128 stores into bufB) ----
  {
    float p1[32];
    float m = -1e30f;
    #pragma unroll
    for (int j = 0; j < 32; ++j) {
      float sc = sli + SRs[h8][j]
               + rk0 * RQs[j][h8 * 4 + 0] + rk1 * RQs[j][h8 * 4 + 1]
               + rk2_ * RQs[j][h8 * 4 + 2] + rk3 * RQs[j][h8 * 4 + 3];
      p1[j] = sc; m = fmaxf(m, sc);
    }
    float sum = 0.f;
    #pragma unroll
    for (int j = 0; j < 32; ++j) { p1[j] = __expf(p1[j] - m); sum += p1[j]; }
    const float inv = 1.f / sum;
    const int row = t;
    const int k = (row >> 3) & 3;
    uintT* pw = reinterpret_cast<uintT*>(bufB) + row * 20;
    #pragma unroll
    for (int o = 0; o < 4; ++o) {
      uint4 v;
      v.x = (uintT)f2bu(p1[8 * o + 0] * inv) | ((uintT)f2bu(p1[8 * o + 1] * inv) << 16);
      v.y = (uintT)f2bu(p1[8 * o + 2] * inv) | ((uintT)f2bu(p1[8 * o + 3] * inv) << 16);
      v.z = (uintT)f2bu(p1[8 * o + 4] * inv) | ((uintT)f2bu(p1[8 * o + 5] * inv) << 16);
      v.w = (uintT)f2bu(p1[8 * o + 6] * inv) | ((uintT)f2bu(p1[8 * o + 7] * inv) << 16);
      *reinterpret_cast<uint4*>(pw + ((o ^ k) << 2)) = v;
    }
  }
  __syncthreads();                                             // B3

  int irow[2][4];
  #pragma unroll
  for (int mh = 0; mh < 2; ++mh)
    #pragma unroll
    for (int r = 0; r < 4; ++r)
      irow[mh][r] = idx[mh * 16 + l16 * 4 + r];

  // A-fragments (P) cached in registers
  bf16x8 af[2][2];
  #pragma unroll
  for (int hh = 0; hh < 2; ++hh) {
    const int h = 2 * w + hh;
    #pragma unroll
    for (int mh = 0; mh < 2; ++mh) {
      const int row = h * 32 + mh * 16 + l15;
      const int k = (row >> 3) & 3;
      af[hh][mh] = *reinterpret_cast<const bf16x8*>(&bufB[row * 40 + ((l16 ^ k) << 3)]);
    }
  }

  // ---- x phase: MFMA + ghb residual + LN stats + h1row0 stash ----
  f32x4 acc[2][2][2];
  #pragma unroll
  for (int hh = 0; hh < 2; ++hh) {
    const int h = 2 * w + hh;
    bf16x8 bf[2];
    #pragma unroll
    for (int nh = 0; nh < 2; ++nh) {
      const int row = h * 32 + nh * 16 + l15;
      const int k = (row >> 3) & 3;
      bf[nh] = *reinterpret_cast<const bf16x8*>(&bufA[row * 40 + ((l16 ^ k) << 3)]);
    }
    #pragma unroll
    for (int mh = 0; mh < 2; ++mh)
      #pragma unroll
      for (int nh = 0; nh < 2; ++nh) {
        f32x4 z = {0.f, 0.f, 0.f, 0.f};
        acc[hh][mh][nh] = __builtin_amdgcn_mfma_f32_16x16x32_bf16(af[hh][mh], bf[nh], z, 0, 0, 0);
      }
  }
  {
    float sum_[2][4], sq_[2][4];
    #pragma unroll
    for (int mh = 0; mh < 2; ++mh)
      #pragma unroll
      for (int r = 0; r < 4; ++r) { sum_[mh][r] = 0.f; sq_[mh][r] = 0.f; }
    #pragma unroll
    for (int hh = 0; hh < 2; ++hh)
      #pragma unroll
      for (int mh = 0; mh < 2; ++mh)
        #pragma unroll
        for (int nh = 0; nh < 2; ++nh) {
          const int col = (2 * w + hh) * 32 + nh * 16 + l15;
          #pragma unroll
          for (int r = 0; r < 4; ++r) {
            float v = acc[hh][mh][nh][r] + b2f(ghb[(size_t)irow[mh][r] * 256 + col]);
            acc[hh][mh][nh][r] = v;
            sum_[mh][r] += v;
            sq_[mh][r] = fmaf(v, v, sq_[mh][r]);
          }
        }
    #pragma unroll
    for (int mh = 0; mh < 2; ++mh)
      #pragma unroll
      for (int r = 0; r < 4; ++r) {
        float s = sum_[mh][r], q = sq_[mh][r];
        #pragma unroll
        for (int m = 8; m >= 1; m >>= 1) {
          s += __shfl_xor(s, m, 64);
          q += __shfl_xor(q, m, 64);
        }
        if (l15 == 0) {
          part[mh * 16 + l16 * 4 + r][w]  = s;
          partq[mh * 16 + l16 * 4 + r][w] = q;
        }
      }
    if (l16 == 0) {
      #pragma unroll
      for (int hh = 0; hh < 2; ++hh)
        #pragma unroll
        for (int nh = 0; nh < 2; ++nh)
          h1r0s[(2 * w + hh) * 32 + nh * 16 + l15] = acc[hh][0][nh][0];
    }
  }
  __syncthreads();                                             // B4

  if (t < 32) {
    float sm = part[t][0] + part[t][1] + part[t][2] + part[t][3];
    float sq = partq[t][0] + partq[t][1] + partq[t][2] + partq[t][3];
    const float m = sm * (1.f / 256.f);
    const float v = fmaxf(sq * (1.f / 256.f) - m * m, 0.f);
    mu_s[t] = m;
    rs_s[t] = rsqrtf(v + LN_EPS);
  }
  __syncthreads();                                             // B5

  // ---- xb = bf16(x) into bufB (Pl dead); RQ2; h1row0 LN + ret1 partials ----
  #pragma unroll
  for (int hh = 0; hh < 2; ++hh)
    #pragma unroll
    for (int mh = 0; mh < 2; ++mh)
      #pragma unroll
      for (int nh = 0; nh < 2; ++nh) {
        const int col = (2 * w + hh) * 32 + nh * 16 + l15;
        #pragma unroll
        for (int r = 0; r < 4; ++r) {
          const int row = mh * 16 + l16 * 4 + r;
          bufB[row * 264 + col] = f2bu(acc[hh][mh][nh][r]);
        }
      }
  #pragma unroll
  for (int rep = 0; rep < 4; ++rep) {
    int flat = rep * 256 + t, s3 = flat >> 5, c3 = flat & 31;
    RQs[s3][c3] = RKQ[(size_t)idx[s3] * 128 + 96 + c3];
  }
  {
    const float mu0 = mu_s[0], rs0 = rs_s[0];
    float hv = fmaf((h1r0s[t] - mu0) * rs0, ln_g[t], ln_b[t]);
    h1r0buf[(size_t)b * 256 + t] = hv;
    float sq = red64(hv * hv);
    h1r0s[t] = hv;
    if ((t & 63) == 0) wred4[t >> 6] = sq;
  }
  __syncthreads();                                             // B6

  if (t == 0) nrm1s = 1.f / fmaxf(sqrtf(wred4[0] + wred4[1] + wred4[2] + wred4[3]), 1e-12f);

  // ---- y phase: y = x @ Wg2 (MFMA, K=256, B from interleaved Wg2i) ----
  {
    f32x4 acc2[2][4];   // [mh][cg]  (wave owns cols w*64 .. w*64+63)
    #pragma unroll
    for (int mh = 0; mh < 2; ++mh)
      #pragma unroll
      for (int cg = 0; cg < 4; ++cg)
        #pragma unroll
        for (int r = 0; r < 4; ++r) acc2[mh][cg][r] = 0.f;
    #pragma unroll
    for (int ks = 0; ks < 8; ++ks) {
      const int ko = ks * 32 + l16 * 8;
      bf16x8 a2[2];
      #pragma unroll
      for (int mh = 0; mh < 2; ++mh)
        a2[mh] = *reinterpret_cast<const bf16x8*>(&bufB[(mh * 16 + l15) * 264 + ko]);
      #pragma unroll
      for (int cg = 0; cg < 4; ++cg) {
        const bf16x8 b2 = *reinterpret_cast<const bf16x8*>(
            &Wg2i[((size_t)(ks * 16 + (w * 4 + cg)) * 64 + l) * 8]);
        #pragma unroll
        for (int mh = 0; mh < 2; ++mh)
          acc2[mh][cg] = __builtin_amdgcn_mfma_f32_16x16x32_bf16(a2[mh], b2, acc2[mh][cg], 0, 0, 0);
      }
    }
    // epilogue: FR2 + SR2
    float rsv[2][4], rmv[2][4];
    #pragma unroll
    for (int mh = 0; mh < 2; ++mh)
      #pragma unroll
      for (int r = 0; r < 4; ++r) {
        const int row = mh * 16 + l16 * 4 + r;
        rsv[mh][r] = rs_s[row];
        rmv[mh][r] = rsv[mh][r] * mu_s[row];
      }
    float sacc[2][2][4];   // [head-half][mh][r]
    #pragma unroll
    for (int hh = 0; hh < 2; ++hh)
      #pragma unroll
      for (int mh = 0; mh < 2; ++mh)
        #pragma unroll
        for (int r = 0; r < 4; ++r) sacc[hh][mh][r] = 0.f;
    float ar2v[2] = { ar2[l15], ar2[16 + l15] };
    #pragma unroll
    for (int cg = 0; cg < 4; ++cg) {
      const int col = w * 64 + cg * 16 + l15;
      const float v1c = vecs[col], v2c = vecs[256 + col];
      const int hh = cg >> 1;
      #pragma unroll
      for (int mh = 0; mh < 2; ++mh)
        #pragma unroll
        for (int r = 0; r < 4; ++r) {
          const int row = mh * 16 + l16 * 4 + r;
          float fa = fmaf(rsv[mh][r], acc2[mh][cg][r], fmaf(-rmv[mh][r], v1c, v2c));
          bufA[row * 268 + col] = f2bu(fa);       // FR2s[row][col]
          float lr = fa > 0.f ? fa : SLOPE * fa;
          sacc[hh][mh][r] = fmaf(lr, ar2v[cg & 1], sacc[hh][mh][r]);
        }
    }
    #pragma unroll
    for (int hh = 0; hh < 2; ++hh)
      #pragma unroll
      for (int mh = 0; mh < 2; ++mh)
        #pragma unroll
        for (int r = 0; r < 4; ++r) {
          float s = sacc[hh][mh][r];
          #pragma unroll
          for (int m = 8; m >= 1; m >>= 1) s += __shfl_xor(s, m, 64);
          if (l15 == 0) SR2s[2 * w + hh][mh * 16 + l16 * 4 + r] = s;
        }
  }
  // ---- fl2 = h1row0 @ Wl2 (coalesced k-major bf16) -> sl2 ----
  {
    float fl = 0.f;
    #pragma unroll 8
    for (int k = 0; k < 256; ++k)
      fl = fmaf(h1r0s[k], b2f(Wl2b[(size_t)k * 256 + t]), fl);
    float lr = (fl > 0.f ? fl : SLOPE * fl) * al2[lo];
    lr = red32(lr);
    if (lo == 0) sl2s[h8] = lr;
  }
  __syncthreads();                                             // B7

  // ---- attn2 row0 scores ----
  {
    float s2 = sl2s[h8] + SR2s[h8][lo]
             + rk2s[h8 * 4 + 0] * RQs[lo][h8 * 4 + 0]
             + rk2s[h8 * 4 + 1] * RQs[lo][h8 * 4 + 1]
             + rk2s[h8 * 4 + 2] * RQs[lo][h8 * 4 + 2]
             + rk2s[h8 * 4 + 3] * RQs[lo][h8 * 4 + 3];
    const float m2 = max32(s2);
    const float e = __expf(s2 - m2);
    const float su = red32(e);
    scp[h8][lo] = e / su;
  }
  __syncthreads();                                             // B8

  // ---- ctx2 = p2 ◦ FR2 ; ret1 write ----
  {
    float a = 0.f;
    #pragma unroll
    for (int j = 0; j < 32; ++j) a = fmaf(scp[h8][j], b2f(bufA[j * 268 + t]), a);
    ctx2buf[(size_t)b * 256 + t] = a;
  }
  out[(size_t)b * 768 + 256 + t] = h1r0s[t] * nrm1s;
}

// ---------------------------------------------------------------------------
// LN + l2n epilogue over Y + res -> out[:,512:768]  (one row per block)
// ---------------------------------------------------------------------------
__global__ __launch_bounds__(256) void ln_l2n_kernel(
    const float* __restrict__ Y, const float* __restrict__ res,
    const float* __restrict__ lng, const float* __restrict__ lnb,
    float* __restrict__ out)
{
  const int row = blockIdx.x, t = threadIdx.x;
  __shared__ float s4[4], q4[4];
  const float y = Y[(size_t)row * 256 + t] + res[(size_t)row * 256 + t];
  float s = red64(y);
  float q = red64(y * y);
  if ((t & 63) == 0) { s4[t >> 6] = s; q4[t >> 6] = q; }
  __syncthreads();
  const float mu = (s4[0] + s4[1] + s4[2] + s4[3]) * (1.f / 256.f);
  const float var = fmaxf((q4[0] + q4[1] + q4[2] + q4[3]) * (1.f / 256.f) - mu * mu, 0.f);
  const float rstd = rsqrtf(var + LN_EPS);
  const float yn = fmaf((y - mu) * rstd, lng[t], lnb[t]);
  float nq = red64(yn * yn);
  __syncthreads();
  if ((t & 63) == 0) s4[t >> 6] = nq;
  __syncthreads();
  const float nrm = 1.f / fmaxf(sqrtf(s4[0] + s4[1] + s4[2] + s4[3]), 1e-12f);
  out[(size_t)row * 768 + 512 + t] = yn * nrm;
}

// ---------------------------------------------------------------------------
extern "C" void kernel_launch(void* const* d_in, const int* in_sizes, int n_in,
                              void* d_out, int out_size, void* d_ws, size_t ws_size,
                              hipStream_t stream)
{
  (void)in_sizes; (void)n_in; (void)out_size; (void)ws_size;

  const float* feat[4]; const float* wfc[4]; const float* bfc[4];
  for (int i = 0; i < 4; ++i) {
    feat[i] = (const float*)d_in[i * 3 + 0];
    wfc[i]  = (const float*)d_in[i * 3 + 1];
    bfc[i]  = (const float*)d_in[i * 3 + 2];
  }
  const float* type_emb = (const float*)d_in[12];
  const float* Wgcn = (const float*)d_in[13];
  const float* bgcn = (const float*)d_in[14];
  const float* Wre  = (const float*)d_in[15];
  const float* bre  = (const float*)d_in[16];
  const float* wtre = (const float*)d_in[17];
  const float* Wl   = (const float*)d_in[18];
  const float* Wr   = (const float*)d_in[19];
  const float* al   = (const float*)d_in[20];
  const float* ar   = (const float*)d_in[21];
  const float* Wrs  = (const float*)d_in[22];
  const float* Wrt  = (const float*)d_in[23];
  const float* Wfin = (const float*)d_in[24];
  const float* ln_g = (const float*)d_in[25];
  const float* ln_b = (const float*)d_in[26];
  const int* src       = (const int*)d_in[27];
  const int* dst       = (const int*)d_in[28];
  const int* node_type = (const int*)d_in[29];
  const int* seqs      = (const int*)d_in[30];
  float* out = (float*)d_out;

  // workspace carve-up (~45 MB)
  char* p = (char*)d_ws;
  auto take = [&](size_t n) { char* q = p; p += (n + 255) & ~(size_t)255; return q; };
  float* gh    = (float*)take((size_t)NN * 256 * 4);
  float* Xf    = (float*)take((size_t)NN * 256 * 4);   // ctx2buf
  float* GR1   = (float*)take((size_t)NN * 256 * 4);   // gh@Wr1, then h1r0buf
  float* RKQ   = (float*)take((size_t)NN * 128 * 4);
  float* SLg   = (float*)take((size_t)NN * 8 * 4);
  float* SRg   = (float*)take((size_t)NN * 8 * 4);
  float* n_out = (float*)take((size_t)NN * 4);
  float* n_in_ = (float*)take((size_t)NN * 4);
  int*   outc  = (int*)take((size_t)NN * 4);
  int*   inc   = (int*)take((size_t)NN * 4);
  int*   offs  = (int*)take((size_t)(NN + 1) * 4);
  int*   cur   = (int*)take((size_t)NN * 4);
  int*   csr   = (int*)take((size_t)(EE + NN) * 4);
  float* R     = (float*)take((size_t)NN * 4 * 4);
  float* rtmp  = (float*)take((size_t)NN * 4 * 4);
  ushortT* GW   = (ushortT*)take((size_t)NN * 256 * 2);
  ushortT* ghb  = (ushortT*)take((size_t)NN * 256 * 2);
  ushortT* Xb   = (ushortT*)take((size_t)NN * 256 * 2); // bf16 GCN scratch
  ushortT* Wg2i = (ushortT*)take((size_t)65536 * 2);
  ushortT* Wl2b = (ushortT*)take((size_t)65536 * 2);
  float* vecs  = (float*)take((size_t)2 * 256 * 4);
  float* ctx2buf = Xf;
  float* h1r0buf = GR1;    // alias: GR1 dead after GW table GEMM
  float* Yb      = gh;     // alias: gh dead after wlwr GEMM

  const float* Wr2 = Wr + 65536;
  const float* Wl2 = Wl + 65536;

  // 1) FC + ret0
  fc_kernel<<<256, 256, 0, stream>>>(feat[0], feat[1], feat[2], feat[3],
                                     wfc[0], wfc[1], wfc[2], wfc[3],
                                     bfc[0], bfc[1], bfc[2], bfc[3], gh, out);
  // 2) degrees + CSR (scan fused with norm/cur)
  zero_counts<<<64, 256, 0, stream>>>(outc, inc);
  count_deg<<<512, 256, 0, stream>>>(src, dst, outc, inc);
  scan_kernel<<<1, 1024, 0, stream>>>(inc, outc, offs, cur, n_out, n_in_);
  fill_csr<<<544, 256, 0, stream>>>(src, dst, cur, csr);
  init_R<<<128, 256, 0, stream>>>(type_emb, node_type, R);

  // weight prep (wg2i: 32 blocks = exactly 8192 valid fragments)
  vec4_kernel<<<2, 256, 0, stream>>>(ln_g, ln_b, Wr2, vecs);
  wg2i_kernel<<<32, 256, 0, stream>>>(ln_g, Wr2, Wg2i);
  wl2b_kernel<<<256, 256, 0, stream>>>(Wl2, Wl2b);

  // 3) GCN + REConv, K=2  (GEMM -> bf16 Xb; agg reads bf16; k=1 emits ghb)
  for (int k = 0; k < 2; ++k) {
    mfma_gemm_kernel<true, true, false, ushortT>
        <<<dim3(128, 4), 256, 0, stream>>>(gh, Wgcn + (size_t)k * 65536,
                                           n_out, Xb, nullptr, nullptr);
    agg2_kernel<<<NN / 2, 256, 0, stream>>>(offs, csr, Xb, n_in_,
                                            bgcn + k * 256, gh,
                                            k == 1 ? ghb : nullptr);
    re_proj<<<128, 256, 0, stream>>>(R, n_out, Wre + k * 16, wtre + k * 4, node_type, rtmp);
    re_agg<<<128, 256, 0, stream>>>(offs, csr, rtmp, n_in_, bre + k * 4, R);
  }

  // 4) attention precomputes (fused Wl/Wr; GW table)
  rkq_kernel<<<4096, 256, 0, stream>>>(R, Wrs, Wrt, RKQ);
  mfma_wlwr_kernel<<<dim3(128, 4), 256, 0, stream>>>(
      gh, Wl, Wr, GR1, al, ar, SLg, SRg);
  mfma_gemm_kernel<false, true, false, ushortT>
      <<<dim3(128, 4), 256, 0, stream>>>(GR1, Wfin, nullptr, GW, nullptr, nullptr);

  // 5) fused transformer -> ret1, h1r0, ctx2
  mega7_kernel<<<NN, 256, 0, stream>>>(seqs, ghb, GW, SLg, SRg, RKQ, vecs,
                                       Wg2i, Wl2b,
                                       al + 32, ar + 32, ln_g, ln_b,
                                       h1r0buf, ctx2buf, out);

  // 6) epilogue: Y = ctx2@Wfin2 (MFMA, M=8192 batched) ; ret2 = l2n(LN(h1r0+Y))
  mfma_gemm_kernel<false, true, false, float>
      <<<dim3(128, 4), 256, 0, stream>>>(ctx2buf, Wfin + 65536, nullptr,
                                         Yb, nullptr, nullptr);
  ln_l2n_kernel<<<NN, 256, 0, stream>>>(Yb, h1r0buf, ln_g + 256, ln_b + 256, out);
}

// Round 24
// 515.839 us; speedup vs baseline: 1.1809x; 1.0213x over previous
//
#include <hip/hip_runtime.h>
#include <hip/hip_bf16.h>
#include <cstdint>
#include <cstddef>

typedef unsigned short ushortT;
typedef unsigned int uintT;

using bf16x8 = __attribute__((ext_vector_type(8))) short;
using f32x4  = __attribute__((ext_vector_type(4))) float;

static constexpr int NN  = 8192;    // total nodes
static constexpr int EE  = 131072;  // edges
static constexpr float SLOPE  = 0.2f;
static constexpr float LN_EPS = 1e-5f;

#define DEVI __device__ __forceinline__

DEVI float red32(float v) {
  #pragma unroll
  for (int m = 16; m >= 1; m >>= 1) v += __shfl_xor(v, m, 64);
  return v;
}
DEVI float red64(float v) {
  #pragma unroll
  for (int m = 32; m >= 1; m >>= 1) v += __shfl_xor(v, m, 64);
  return v;
}
DEVI float max32(float v) {
  #pragma unroll
  for (int m = 16; m >= 1; m >>= 1) v = fmaxf(v, __shfl_xor(v, m, 64));
  return v;
}
DEVI float blo(uintT u) { union { uintT i; float f; } c; c.i = u << 16; return c.f; }
DEVI float bhi(uintT u) { union { uintT i; float f; } c; c.i = u & 0xffff0000u; return c.f; }
DEVI float b2f(ushortT u) { union { uintT i; float f; } c; c.i = ((uintT)u) << 16; return c.f; }
DEVI ushortT f2bu(float f) {
  __hip_bfloat16 h = __float2bfloat16(f);
  return *reinterpret_cast<ushortT*>(&h);
}
DEVI void storeC(float* p, float v) { *p = v; }
DEVI void storeC(ushortT* p, float v) { *p = f2bu(v); }

// ---------------------------------------------------------------------------
// FC: gh[n] = feat_t[n] @ Wfc_t + bfc_t ; out[n,0:256] = l2n(gh[n])
// ---------------------------------------------------------------------------
__global__ __launch_bounds__(256) void fc_kernel(
    const float* __restrict__ f0, const float* __restrict__ f1,
    const float* __restrict__ f2, const float* __restrict__ f3,
    const float* __restrict__ w0, const float* __restrict__ w1,
    const float* __restrict__ w2, const float* __restrict__ w3,
    const float* __restrict__ b0, const float* __restrict__ b1,
    const float* __restrict__ b2, const float* __restrict__ b3,
    float* __restrict__ gh, float* __restrict__ out)
{
  const int nb = blockIdx.x * 32;
  const int t  = threadIdx.x;
  int base, D;
  const float *F, *W, *Bv;
  if (nb < 4096)      { base = 0;    D = 128; F = f0; W = w0; Bv = b0; }
  else if (nb < 6144) { base = 4096; D = 64;  F = f1; W = w1; Bv = b1; }
  else if (nb < 7168) { base = 6144; D = 32;  F = f2; W = w2; Bv = b2; }
  else                { base = 7168; D = 16;  F = f3; W = w3; Bv = b3; }

  __shared__ float Fs[32 * 128];
  __shared__ float red[32][4];
  __shared__ float nrm[32];

  const int total = 32 * D;
  for (int i = t; i < total; i += 256) Fs[i] = F[(size_t)(nb - base) * D + i];
  __syncthreads();

  float acc[32];
  #pragma unroll
  for (int r = 0; r < 32; ++r) acc[r] = Bv[t];
  for (int d = 0; d < D; ++d) {
    float w = W[(size_t)d * 256 + t];
    #pragma unroll
    for (int r = 0; r < 32; ++r) acc[r] = fmaf(Fs[r * D + d], w, acc[r]);
  }

  const int lane = t & 63, wid = t >> 6;
  #pragma unroll
  for (int r = 0; r < 32; ++r) {
    float v = acc[r] * acc[r];
    for (int o = 32; o > 0; o >>= 1) v += __shfl_down(v, o, 64);
    if (lane == 0) red[r][wid] = v;
  }
  __syncthreads();
  if (t < 32) {
    float s = red[t][0] + red[t][1] + red[t][2] + red[t][3];
    nrm[t] = 1.0f / fmaxf(sqrtf(s), 1e-12f);
  }
  __syncthreads();
  #pragma unroll
  for (int r = 0; r < 32; ++r) {
    gh[(size_t)(nb + r) * 256 + t]  = acc[r];
    out[(size_t)(nb + r) * 768 + t] = acc[r] * nrm[r];
  }
}

// ---------------------------------------------------------------------------
// degree / CSR build
// ---------------------------------------------------------------------------
__global__ __launch_bounds__(256) void zero_counts(int* outc, int* inc) {
  int g = blockIdx.x * 256 + threadIdx.x;
  if (g < NN) outc[g] = 0; else inc[g - NN] = 0;
}
__global__ __launch_bounds__(256) void count_deg(const int* __restrict__ src,
                                                 const int* __restrict__ dst,
                                                 int* outc, int* inc) {
  int g = blockIdx.x * 256 + threadIdx.x;
  atomicAdd(&outc[src[g]], 1);
  atomicAdd(&inc[dst[g]], 1);
}
// scan + norm + cur in one
__global__ __launch_bounds__(1024) void scan_kernel(
    const int* __restrict__ inc, const int* __restrict__ outc,
    int* __restrict__ offs, int* __restrict__ cur,
    float* __restrict__ n_out, float* __restrict__ n_in)
{
  __shared__ int sums[1024];
  const int t = threadIdx.x;
  int x[8];
  const int base = t * 8;
  int s = 0;
  #pragma unroll
  for (int i = 0; i < 8; ++i) { int v = inc[base + i] + 1; x[i] = s; s += v; }
  sums[t] = s;
  __syncthreads();
  for (int off = 1; off < 1024; off <<= 1) {
    int a = (t >= off) ? sums[t - off] : 0;
    __syncthreads();
    sums[t] += a;
    __syncthreads();
  }
  const int pre = (t > 0) ? sums[t - 1] : 0;
  #pragma unroll
  for (int i = 0; i < 8; ++i) {
    const int o = pre + x[i];
    offs[base + i] = o;
    cur[base + i]  = o;
    n_in[base + i]  = rsqrtf((float)inc[base + i] + 1.0f);
    n_out[base + i] = rsqrtf((float)outc[base + i] + 1.0f);
  }
  if (t == 1023) offs[NN] = sums[1023];
}
__global__ __launch_bounds__(256) void fill_csr(const int* __restrict__ src,
                                                const int* __restrict__ dst,
                                                int* cur, int* __restrict__ csr) {
  int g = blockIdx.x * 256 + threadIdx.x;   // EE + NN total
  int s, d;
  if (g < EE) { s = src[g]; d = dst[g]; }
  else        { s = g - EE; d = g - EE; }   // self-loops
  int pos = atomicAdd(&cur[d], 1);
  csr[pos] = s;
}

// ---------------------------------------------------------------------------
// MFMA GEMM (single B): C = (rowscale? diag(rs):I) A @ W ; optional RED
// ---------------------------------------------------------------------------
template<bool ROWSCALE, bool STORE, bool RED, typename CT>
__global__ __launch_bounds__(256) void mfma_gemm_kernel(
    const float* __restrict__ A, const float* __restrict__ W,
    const float* __restrict__ rowscale,
    CT* __restrict__ C, const float* __restrict__ avec,
    float* __restrict__ SSo)
{
  const int m0 = blockIdx.x * 64;
  const int n0 = blockIdx.y * 64;
  const int t = threadIdx.x;
  const int w = t >> 6, l = t & 63;
  const int wr = w >> 1, wc = w & 1;
  const int l15 = l & 15, l16 = l >> 4;

  __shared__ alignas(16) ushortT As[64][72];   // [m][k]
  __shared__ alignas(16) ushortT Bs[64][72];   // [n][k]

  f32x4 acc[2][2];
  #pragma unroll
  for (int mh = 0; mh < 2; ++mh)
    #pragma unroll
    for (int nh = 0; nh < 2; ++nh)
      #pragma unroll
      for (int r = 0; r < 4; ++r) acc[mh][nh][r] = 0.f;

  for (int k0 = 0; k0 < 256; k0 += 64) {
    #pragma unroll
    for (int rep = 0; rep < 16; ++rep) {
      int flat = rep * 256 + t;
      int r = flat >> 6, k = flat & 63;
      float v = A[(size_t)(m0 + r) * 256 + k0 + k];
      if constexpr (ROWSCALE) v *= rowscale[m0 + r];
      As[r][k] = f2bu(v);
    }
    #pragma unroll
    for (int rep = 0; rep < 16; ++rep) {
      int flat = rep * 256 + t;
      int k = flat >> 6, n = flat & 63;
      Bs[n][k] = f2bu(W[(size_t)(k0 + k) * 256 + n0 + n]);
    }
    __syncthreads();
    #pragma unroll
    for (int ks = 0; ks < 2; ++ks) {
      const int kb = ks * 32 + l16 * 8;
      bf16x8 afr[2], bfr[2];
      #pragma unroll
      for (int mh = 0; mh < 2; ++mh)
        afr[mh] = *reinterpret_cast<const bf16x8*>(&As[wr * 32 + mh * 16 + l15][kb]);
      #pragma unroll
      for (int nh = 0; nh < 2; ++nh)
        bfr[nh] = *reinterpret_cast<const bf16x8*>(&Bs[wc * 32 + nh * 16 + l15][kb]);
      #pragma unroll
      for (int mh = 0; mh < 2; ++mh)
        #pragma unroll
        for (int nh = 0; nh < 2; ++nh)
          acc[mh][nh] = __builtin_amdgcn_mfma_f32_16x16x32_bf16(
              afr[mh], bfr[nh], acc[mh][nh], 0, 0, 0);
    }
    __syncthreads();
  }
  if constexpr (STORE) {
    #pragma unroll
    for (int mh = 0; mh < 2; ++mh)
      #pragma unroll
      for (int nh = 0; nh < 2; ++nh)
        #pragma unroll
        for (int r = 0; r < 4; ++r) {
          const int row = m0 + wr * 32 + mh * 16 + l16 * 4 + r;
          const int col = n0 + wc * 32 + nh * 16 + l15;
          storeC(&C[(size_t)row * 256 + col], acc[mh][nh][r]);
        }
  }
  if constexpr (RED) {
    const float av0 = avec[l15], av1 = avec[16 + l15];
    #pragma unroll
    for (int mh = 0; mh < 2; ++mh)
      #pragma unroll
      for (int r = 0; r < 4; ++r) {
        float s = 0.f;
        {
          float x = acc[mh][0][r];
          s = fmaf(x > 0.f ? x : SLOPE * x, av0, s);
          x = acc[mh][1][r];
          s = fmaf(x > 0.f ? x : SLOPE * x, av1, s);
        }
        #pragma unroll
        for (int m = 8; m >= 1; m >>= 1) s += __shfl_xor(s, m, 64);
        if (l15 == 0) {
          const int row = m0 + wr * 32 + mh * 16 + l16 * 4 + r;
          SSo[(size_t)row * 8 + blockIdx.y * 2 + wc] = s;
        }
      }
  }
}

// ---------------------------------------------------------------------------
// Fused Wl/Wr GEMM: A staged once; SLg=RED(leaky(A@Wl)·al), GR1=A@Wr (store)
// + SRg=RED(leaky(A@Wr)·ar).
// ---------------------------------------------------------------------------
__global__ __launch_bounds__(256) void mfma_wlwr_kernel(
    const float* __restrict__ A,
    const float* __restrict__ Wl_, const float* __restrict__ Wr_,
    float* __restrict__ GR1,
    const float* __restrict__ al_, const float* __restrict__ ar_,
    float* __restrict__ SL, float* __restrict__ SR)
{
  const int m0 = blockIdx.x * 64;
  const int n0 = blockIdx.y * 64;
  const int t = threadIdx.x;
  const int w = t >> 6, l = t & 63;
  const int wr = w >> 1, wc = w & 1;
  const int l15 = l & 15, l16 = l >> 4;

  __shared__ alignas(16) ushortT As[64][72];
  __shared__ alignas(16) ushortT Bl[64][72];
  __shared__ alignas(16) ushortT Br[64][72];

  f32x4 accl[2][2], accr[2][2];
  #pragma unroll
  for (int mh = 0; mh < 2; ++mh)
    #pragma unroll
    for (int nh = 0; nh < 2; ++nh)
      #pragma unroll
      for (int r = 0; r < 4; ++r) { accl[mh][nh][r] = 0.f; accr[mh][nh][r] = 0.f; }

  for (int k0 = 0; k0 < 256; k0 += 64) {
    #pragma unroll
    for (int rep = 0; rep < 16; ++rep) {
      int flat = rep * 256 + t;
      int r = flat >> 6, k = flat & 63;
      As[r][k] = f2bu(A[(size_t)(m0 + r) * 256 + k0 + k]);
    }
    #pragma unroll
    for (int rep = 0; rep < 16; ++rep) {
      int flat = rep * 256 + t;
      int k = flat >> 6, n = flat & 63;
      Bl[n][k] = f2bu(Wl_[(size_t)(k0 + k) * 256 + n0 + n]);
      Br[n][k] = f2bu(Wr_[(size_t)(k0 + k) * 256 + n0 + n]);
    }
    __syncthreads();
    #pragma unroll
    for (int ks = 0; ks < 2; ++ks) {
      const int kb = ks * 32 + l16 * 8;
      bf16x8 afr[2], blr[2], brr[2];
      #pragma unroll
      for (int mh = 0; mh < 2; ++mh)
        afr[mh] = *reinterpret_cast<const bf16x8*>(&As[wr * 32 + mh * 16 + l15][kb]);
      #pragma unroll
      for (int nh = 0; nh < 2; ++nh) {
        blr[nh] = *reinterpret_cast<const bf16x8*>(&Bl[wc * 32 + nh * 16 + l15][kb]);
        brr[nh] = *reinterpret_cast<const bf16x8*>(&Br[wc * 32 + nh * 16 + l15][kb]);
      }
      #pragma unroll
      for (int mh = 0; mh < 2; ++mh)
        #pragma unroll
        for (int nh = 0; nh < 2; ++nh) {
          accl[mh][nh] = __builtin_amdgcn_mfma_f32_16x16x32_bf16(
              afr[mh], blr[nh], accl[mh][nh], 0, 0, 0);
          accr[mh][nh] = __builtin_amdgcn_mfma_f32_16x16x32_bf16(
              afr[mh], brr[nh], accr[mh][nh], 0, 0, 0);
        }
    }
    __syncthreads();
  }
  // store GR1 = A@Wr
  #pragma unroll
  for (int mh = 0; mh < 2; ++mh)
    #pragma unroll
    for (int nh = 0; nh < 2; ++nh)
      #pragma unroll
      for (int r = 0; r < 4; ++r) {
        const int row = m0 + wr * 32 + mh * 16 + l16 * 4 + r;
        const int col = n0 + wc * 32 + nh * 16 + l15;
        GR1[(size_t)row * 256 + col] = accr[mh][nh][r];
      }
  // RED both
  const float al0 = al_[l15], al1 = al_[16 + l15];
  const float ar0 = ar_[l15], ar1 = ar_[16 + l15];
  #pragma unroll
  for (int mh = 0; mh < 2; ++mh)
    #pragma unroll
    for (int r = 0; r < 4; ++r) {
      float sl = 0.f, sr = 0.f;
      {
        float x = accl[mh][0][r];
        sl = fmaf(x > 0.f ? x : SLOPE * x, al0, sl);
        x = accl[mh][1][r];
        sl = fmaf(x > 0.f ? x : SLOPE * x, al1, sl);
        x = accr[mh][0][r];
        sr = fmaf(x > 0.f ? x : SLOPE * x, ar0, sr);
        x = accr[mh][1][r];
        sr = fmaf(x > 0.f ? x : SLOPE * x, ar1, sr);
      }
      #pragma unroll
      for (int m = 8; m >= 1; m >>= 1) {
        sl += __shfl_xor(sl, m, 64);
        sr += __shfl_xor(sr, m, 64);
      }
      if (l15 == 0) {
        const int row = m0 + wr * 32 + mh * 16 + l16 * 4 + r;
        SL[(size_t)row * 8 + blockIdx.y * 2 + wc] = sl;
        SR[(size_t)row * 8 + blockIdx.y * 2 + wc] = sr;
      }
    }
}

// ---------------------------------------------------------------------------
// GCN aggregate (bf16 input, 2 nodes/block) WITH fused REConv aggregation:
// lanes tc<4 additionally gather rtmp along the same CSR walk and write R.
// Summation order identical to the standalone re_agg -> bit-identical.
// ---------------------------------------------------------------------------
__global__ __launch_bounds__(256) void agg3_kernel(
    const int* __restrict__ offs, const int* __restrict__ csr,
    const ushortT* __restrict__ X, const float* __restrict__ n_in,
    const float* __restrict__ bias,
    const float* __restrict__ rtmp, const float* __restrict__ bre,
    float* __restrict__ ghn, float* __restrict__ Rn,
    ushortT* __restrict__ ghb)
{
  const int n  = blockIdx.x * 2 + (threadIdx.x >> 7);
  const int tc = threadIdx.x & 127;
  const uintT* X2 = reinterpret_cast<const uintT*>(X);
  const int s0 = offs[n], s1 = offs[n + 1];
  float a0 = 0.f, a1 = 0.f, ra = 0.f;
  for (int i = s0; i < s1; ++i) {
    const int s = csr[i];
    const uintT u = X2[(size_t)s * 128 + tc];
    a0 += blo(u);
    a1 += bhi(u);
    if (tc < 4) ra += rtmp[(size_t)s * 4 + tc];
  }
  const float ni = n_in[n];
  const float g0 = fmaxf(fmaf(a0, ni, bias[2 * tc]), 0.f);
  const float g1 = fmaxf(fmaf(a1, ni, bias[2 * tc + 1]), 0.f);
  float2 g2; g2.x = g0; g2.y = g1;
  reinterpret_cast<float2*>(ghn)[(size_t)n * 128 + tc] = g2;
  if (ghb)
    reinterpret_cast<uintT*>(ghb)[(size_t)n * 128 + tc] =
        (uintT)f2bu(g0) | ((uintT)f2bu(g1) << 16);
  if (tc < 4) Rn[n * 4 + tc] = fmaxf(fmaf(ra, ni, bre[tc]), 0.f);
}

// re_proj (FIRST: R comes from type_emb[nt] directly -> deletes init_R)
template<bool FIRST>
__global__ __launch_bounds__(256) void re_proj_k(
    const float* __restrict__ R, const float* __restrict__ type_emb,
    const int* __restrict__ nt, const float* __restrict__ n_out,
    const float* __restrict__ Wre, const float* __restrict__ wtre,
    float* __restrict__ rtmp)
{
  int g = blockIdx.x * 256 + threadIdx.x;  // NN*4
  int n = g >> 2, j = g & 3;
  const int ty = nt[n];
  float s = 0.f;
  if constexpr (FIRST) {
    #pragma unroll
    for (int c = 0; c < 4; ++c) s += type_emb[ty * 4 + c] * Wre[c * 4 + j];
  } else {
    #pragma unroll
    for (int c = 0; c < 4; ++c) s += R[n * 4 + c] * Wre[c * 4 + j];
  }
  rtmp[g] = s * n_out[n] * wtre[ty];
}

__global__ __launch_bounds__(256) void rkq_kernel(
    const float* __restrict__ R, const float* __restrict__ Wrs,
    const float* __restrict__ Wrt, float* __restrict__ RKQ)
{
  int g = blockIdx.x * 256 + threadIdx.x;  // NN*128
  int n = g >> 7, c = g & 127;
  int which = c >> 5, cc = c & 31;
  const float* Wp = (which == 0) ? Wrs : (which == 1) ? Wrt
                   : (which == 2) ? (Wrs + 128) : (Wrt + 128);
  float s = 0.f;
  #pragma unroll
  for (int r = 0; r < 4; ++r) s += R[n * 4 + r] * Wp[r * 32 + cc];
  RKQ[g] = s;
}

// ---------------------------------------------------------------------------
// weight prep
// ---------------------------------------------------------------------------
__global__ __launch_bounds__(256) void vec4_kernel(
    const float* __restrict__ ln_g, const float* __restrict__ ln_b,
    const float* __restrict__ Wr2, float* __restrict__ vecs)
{
  const int which = blockIdx.x, t = threadIdx.x;
  const float* s = (which & 1) ? ln_b : ln_g;
  float a = 0.f;
  for (int k = 0; k < 256; ++k) a = fmaf(s[k], Wr2[(size_t)k * 256 + t], a);
  vecs[which * 256 + t] = a;
}
__global__ __launch_bounds__(256) void wg2i_kernel(
    const float* __restrict__ ln_g, const float* __restrict__ Wr2,
    ushortT* __restrict__ Wg2i)
{
  const int gid = blockIdx.x * 256 + threadIdx.x;   // 8192
  const int ks  = gid >> 10;                        // [0,8)
  const int cgl = (gid >> 6) & 15;
  const int l   = gid & 63;
  const int col = cgl * 16 + (l & 15);
  const int kb  = ks * 32 + (l >> 4) * 8;
  ushortT v[8];
  #pragma unroll
  for (int e = 0; e < 8; ++e)
    v[e] = f2bu(ln_g[kb + e] * Wr2[(size_t)(kb + e) * 256 + col]);
  *reinterpret_cast<bf16x8*>(&Wg2i[(size_t)gid * 8]) =
      *reinterpret_cast<const bf16x8*>(v);
}
__global__ __launch_bounds__(256) void wl2b_kernel(
    const float* __restrict__ Wl2, ushortT* __restrict__ Wl2b)
{
  int g = blockIdx.x * 256 + threadIdx.x;   // 65536
  Wl2b[g] = f2bu(Wl2[g]);
}

// ---------------------------------------------------------------------------
// MEGA7 (verified round-15/17/19/23 version)
// ---------------------------------------------------------------------------
__global__ __launch_bounds__(256) void mega7_kernel(
    const int* __restrict__ seqs,
    const ushortT* __restrict__ ghb,
    const ushortT* __restrict__ GW,
    const float* __restrict__ SLg, const float* __restrict__ SRg,
    const float* __restrict__ RKQ,
    const float* __restrict__ vecs,           // v1,v2
    const ushortT* __restrict__ Wg2i,         // interleaved bf16
    const ushortT* __restrict__ Wl2b,         // [k][col] bf16
    const float* __restrict__ al2, const float* __restrict__ ar2,
    const float* __restrict__ ln_g, const float* __restrict__ ln_b,
    float* __restrict__ h1r0buf, float* __restrict__ ctx2buf,
    float* __restrict__ out)
{
  __shared__ int idx[32];
  __shared__ alignas(16) ushortT bufA[10240];  // GT(GW^T, swz) -> FR2s[32][268]
  __shared__ alignas(16) ushortT bufB[10240];  // Pl[256][20u] swz -> xb[32][264]
  __shared__ float SRs[8][32];
  __shared__ float RQs[32][36];                // RQ1 then RQ2
  __shared__ float rk2s[32];
  __shared__ float part[32][4], partq[32][4];
  __shared__ float mu_s[32], rs_s[32];
  __shared__ float SR2s[8][32];
  __shared__ float sl2s[8];
  __shared__ float scp[8][32];
  __shared__ float h1r0s[256];
  __shared__ float wred4[4];
  __shared__ float nrm1s;

  const int b = blockIdx.x, t = threadIdx.x;
  const int h8 = t >> 5, lo = t & 31;
  const int w = t >> 6, l = t & 63;
  const int l15 = l & 15, l16 = l >> 4;

  if (t < 32) idx[t] = seqs[b * 32 + t];
  __syncthreads();                                             // B1

  const float sli = SLg[(size_t)idx[lo] * 8 + h8];
  const float rk0 = RKQ[(size_t)idx[lo] * 128 + h8 * 4 + 0];
  const float rk1 = RKQ[(size_t)idx[lo] * 128 + h8 * 4 + 1];
  const float rk2_ = RKQ[(size_t)idx[lo] * 128 + h8 * 4 + 2];
  const float rk3 = RKQ[(size_t)idx[lo] * 128 + h8 * 4 + 3];

  // ---- stage GT = GW^T (swizzled), SRs, RQ1, rk2s ----
  {
    const uintT* GWu = reinterpret_cast<const uintT*>(GW);
    #pragma unroll
    for (int rep = 0; rep < 16; ++rep) {
      int flat = rep * 256 + t;
      int j = flat >> 7, cp = flat & 127;
      const uintT u = GWu[(size_t)idx[j] * 128 + cp];
      const int rA = 2 * cp;
      const int k = (rA >> 3) & 3;
      const int off = (((j >> 3) ^ k) << 3) + (j & 7);
      bufA[rA * 40 + off]       = (ushortT)(u & 0xffffu);
      bufA[(rA + 1) * 40 + off] = (ushortT)(u >> 16);
    }
  }
  SRs[h8][lo] = SRg[(size_t)idx[lo] * 8 + h8];
  #pragma unroll
  for (int rep = 0; rep < 4; ++rep) {
    int flat = rep * 256 + t, s3 = flat >> 5, c3 = flat & 31;
    RQs[s3][c3] = RKQ[(size_t)idx[s3] * 128 + 32 + c3];
  }
  if (t < 32) rk2s[t] = RKQ[(size_t)idx[0] * 128 + 64 + t];
  __syncthreads();                                             // B2

  // ---- attn1 softmax -> Pl (swizzled bf16, b128 stores into bufB) ----
  {
    float p1[32];
    float m = -1e30f;
    #pragma unroll
    for (int j = 0; j < 32; ++j) {
      float sc = sli + SRs[h8][j]
               + rk0 * RQs[j][h8 * 4 + 0] + rk1 * RQs[j][h8 * 4 + 1]
               + rk2_ * RQs[j][h8 * 4 + 2] + rk3 * RQs[j][h8 * 4 + 3];
      p1[j] = sc; m = fmaxf(m, sc);
    }
    float sum = 0.f;
    #pragma unroll
    for (int j = 0; j < 32; ++j) { p1[j] = __expf(p1[j] - m); sum += p1[j]; }
    const float inv = 1.f / sum;
    const int row = t;
    const int k = (row >> 3) & 3;
    uintT* pw = reinterpret_cast<uintT*>(bufB) + row * 20;
    #pragma unroll
    for (int o = 0; o < 4; ++o) {
      uint4 v;
      v.x = (uintT)f2bu(p1[8 * o + 0] * inv) | ((uintT)f2bu(p1[8 * o + 1] * inv) << 16);
      v.y = (uintT)f2bu(p1[8 * o + 2] * inv) | ((uintT)f2bu(p1[8 * o + 3] * inv) << 16);
      v.z = (uintT)f2bu(p1[8 * o + 4] * inv) | ((uintT)f2bu(p1[8 * o + 5] * inv) << 16);
      v.w = (uintT)f2bu(p1[8 * o + 6] * inv) | ((uintT)f2bu(p1[8 * o + 7] * inv) << 16);
      *reinterpret_cast<uint4*>(pw + ((o ^ k) << 2)) = v;
    }
  }
  __syncthreads();                                             // B3

  int irow[2][4];
  #pragma unroll
  for (int mh = 0; mh < 2; ++mh)
    #pragma unroll
    for (int r = 0; r < 4; ++r)
      irow[mh][r] = idx[mh * 16 + l16 * 4 + r];

  // A-fragments (P) cached in registers
  bf16x8 af[2][2];
  #pragma unroll
  for (int hh = 0; hh < 2; ++hh) {
    const int h = 2 * w + hh;
    #pragma unroll
    for (int mh = 0; mh < 2; ++mh) {
      const int row = h * 32 + mh * 16 + l15;
      const int k = (row >> 3) & 3;
      af[hh][mh] = *reinterpret_cast<const bf16x8*>(&bufB[row * 40 + ((l16 ^ k) << 3)]);
    }
  }

  // ---- x phase: MFMA + ghb residual + LN stats + h1row0 stash ----
  f32x4 acc[2][2][2];
  #pragma unroll
  for (int hh = 0; hh < 2; ++hh) {
    const int h = 2 * w + hh;
    bf16x8 bf[2];
    #pragma unroll
    for (int nh = 0; nh < 2; ++nh) {
      const int row = h * 32 + nh * 16 + l15;
      const int k = (row >> 3) & 3;
      bf[nh] = *reinterpret_cast<const bf16x8*>(&bufA[row * 40 + ((l16 ^ k) << 3)]);
    }
    #pragma unroll
    for (int mh = 0; mh < 2; ++mh)
      #pragma unroll
      for (int nh = 0; nh < 2; ++nh) {
        f32x4 z = {0.f, 0.f, 0.f, 0.f};
        acc[hh][mh][nh] = __builtin_amdgcn_mfma_f32_16x16x32_bf16(af[hh][mh], bf[nh], z, 0, 0, 0);
      }
  }
  {
    float sum_[2][4], sq_[2][4];
    #pragma unroll
    for (int mh = 0; mh < 2; ++mh)
      #pragma unroll
      for (int r = 0; r < 4; ++r) { sum_[mh][r] = 0.f; sq_[mh][r] = 0.f; }
    #pragma unroll
    for (int hh = 0; hh < 2; ++hh)
      #pragma unroll
      for (int mh = 0; mh < 2; ++mh)
        #pragma unroll
        for (int nh = 0; nh < 2; ++nh) {
          const int col = (2 * w + hh) * 32 + nh * 16 + l15;
          #pragma unroll
          for (int r = 0; r < 4; ++r) {
            float v = acc[hh][mh][nh][r] + b2f(ghb[(size_t)irow[mh][r] * 256 + col]);
            acc[hh][mh][nh][r] = v;
            sum_[mh][r] += v;
            sq_[mh][r] = fmaf(v, v, sq_[mh][r]);
          }
        }
    #pragma unroll
    for (int mh = 0; mh < 2; ++mh)
      #pragma unroll
      for (int r = 0; r < 4; ++r) {
        float s = sum_[mh][r], q = sq_[mh][r];
        #pragma unroll
        for (int m = 8; m >= 1; m >>= 1) {
          s += __shfl_xor(s, m, 64);
          q += __shfl_xor(q, m, 64);
        }
        if (l15 == 0) {
          part[mh * 16 + l16 * 4 + r][w]  = s;
          partq[mh * 16 + l16 * 4 + r][w] = q;
        }
      }
    if (l16 == 0) {
      #pragma unroll
      for (int hh = 0; hh < 2; ++hh)
        #pragma unroll
        for (int nh = 0; nh < 2; ++nh)
          h1r0s[(2 * w + hh) * 32 + nh * 16 + l15] = acc[hh][0][nh][0];
    }
  }
  __syncthreads();                                             // B4

  if (t < 32) {
    float sm = part[t][0] + part[t][1] + part[t][2] + part[t][3];
    float sq = partq[t][0] + partq[t][1] + partq[t][2] + partq[t][3];
    const float m = sm * (1.f / 256.f);
    const float v = fmaxf(sq * (1.f / 256.f) - m * m, 0.f);
    mu_s[t] = m;
    rs_s[t] = rsqrtf(v + LN_EPS);
  }
  __syncthreads();                                             // B5

  // ---- xb = bf16(x) into bufB (Pl dead); RQ2; h1row0 LN + ret1 partials ----
  #pragma unroll
  for (int hh = 0; hh < 2; ++hh)
    #pragma unroll
    for (int mh = 0; mh < 2; ++mh)
      #pragma unroll
      for (int nh = 0; nh < 2; ++nh) {
        const int col = (2 * w + hh) * 32 + nh * 16 + l15;
        #pragma unroll
        for (int r = 0; r < 4; ++r) {
          const int row = mh * 16 + l16 * 4 + r;
          bufB[row * 264 + col] = f2bu(acc[hh][mh][nh][r]);
        }
      }
  #pragma unroll
  for (int rep = 0; rep < 4; ++rep) {
    int flat = rep * 256 + t, s3 = flat >> 5, c3 = flat & 31;
    RQs[s3][c3] = RKQ[(size_t)idx[s3] * 128 + 96 + c3];
  }
  {
    const float mu0 = mu_s[0], rs0 = rs_s[0];
    float hv = fmaf((h1r0s[t] - mu0) * rs0, ln_g[t], ln_b[t]);
    h1r0buf[(size_t)b * 256 + t] = hv;
    float sq = red64(hv * hv);
    h1r0s[t] = hv;
    if ((t & 63) == 0) wred4[t >> 6] = sq;
  }
  __syncthreads();                                             // B6

  if (t == 0) nrm1s = 1.f / fmaxf(sqrtf(wred4[0] + wred4[1] + wred4[2] + wred4[3]), 1e-12f);

  // ---- y phase: y = x @ Wg2 (MFMA, K=256, B from interleaved Wg2i) ----
  {
    f32x4 acc2[2][4];   // [mh][cg]  (wave owns cols w*64 .. w*64+63)
    #pragma unroll
    for (int mh = 0; mh < 2; ++mh)
      #pragma unroll
      for (int cg = 0; cg < 4; ++cg)
        #pragma unroll
        for (int r = 0; r < 4; ++r) acc2[mh][cg][r] = 0.f;
    #pragma unroll
    for (int ks = 0; ks < 8; ++ks) {
      const int ko = ks * 32 + l16 * 8;
      bf16x8 a2[2];
      #pragma unroll
      for (int mh = 0; mh < 2; ++mh)
        a2[mh] = *reinterpret_cast<const bf16x8*>(&bufB[(mh * 16 + l15) * 264 + ko]);
      #pragma unroll
      for (int cg = 0; cg < 4; ++cg) {
        const bf16x8 b2 = *reinterpret_cast<const bf16x8*>(
            &Wg2i[((size_t)(ks * 16 + (w * 4 + cg)) * 64 + l) * 8]);
        #pragma unroll
        for (int mh = 0; mh < 2; ++mh)
          acc2[mh][cg] = __builtin_amdgcn_mfma_f32_16x16x32_bf16(a2[mh], b2, acc2[mh][cg], 0, 0, 0);
      }
    }
    // epilogue: FR2 + SR2
    float rsv[2][4], rmv[2][4];
    #pragma unroll
    for (int mh = 0; mh < 2; ++mh)
      #pragma unroll
      for (int r = 0; r < 4; ++r) {
        const int row = mh * 16 + l16 * 4 + r;
        rsv[mh][r] = rs_s[row];
        rmv[mh][r] = rsv[mh][r] * mu_s[row];
      }
    float sacc[2][2][4];   // [head-half][mh][r]
    #pragma unroll
    for (int hh = 0; hh < 2; ++hh)
      #pragma unroll
      for (int mh = 0; mh < 2; ++mh)
        #pragma unroll
        for (int r = 0; r < 4; ++r) sacc[hh][mh][r] = 0.f;
    float ar2v[2] = { ar2[l15], ar2[16 + l15] };
    #pragma unroll
    for (int cg = 0; cg < 4; ++cg) {
      const int col = w * 64 + cg * 16 + l15;
      const float v1c = vecs[col], v2c = vecs[256 + col];
      const int hh = cg >> 1;
      #pragma unroll
      for (int mh = 0; mh < 2; ++mh)
        #pragma unroll
        for (int r = 0; r < 4; ++r) {
          const int row = mh * 16 + l16 * 4 + r;
          float fa = fmaf(rsv[mh][r], acc2[mh][cg][r], fmaf(-rmv[mh][r], v1c, v2c));
          bufA[row * 268 + col] = f2bu(fa);       // FR2s[row][col]
          float lr = fa > 0.f ? fa : SLOPE * fa;
          sacc[hh][mh][r] = fmaf(lr, ar2v[cg & 1], sacc[hh][mh][r]);
        }
    }
    #pragma unroll
    for (int hh = 0; hh < 2; ++hh)
      #pragma unroll
      for (int mh = 0; mh < 2; ++mh)
        #pragma unroll
        for (int r = 0; r < 4; ++r) {
          float s = sacc[hh][mh][r];
          #pragma unroll
          for (int m = 8; m >= 1; m >>= 1) s += __shfl_xor(s, m, 64);
          if (l15 == 0) SR2s[2 * w + hh][mh * 16 + l16 * 4 + r] = s;
        }
  }
  // ---- fl2 = h1row0 @ Wl2 (coalesced k-major bf16) -> sl2 ----
  {
    float fl = 0.f;
    #pragma unroll 8
    for (int k = 0; k < 256; ++k)
      fl = fmaf(h1r0s[k], b2f(Wl2b[(size_t)k * 256 + t]), fl);
    float lr = (fl > 0.f ? fl : SLOPE * fl) * al2[lo];
    lr = red32(lr);
    if (lo == 0) sl2s[h8] = lr;
  }
  __syncthreads();                                             // B7

  // ---- attn2 row0 scores ----
  {
    float s2 = sl2s[h8] + SR2s[h8][lo]
             + rk2s[h8 * 4 + 0] * RQs[lo][h8 * 4 + 0]
             + rk2s[h8 * 4 + 1] * RQs[lo][h8 * 4 + 1]
             + rk2s[h8 * 4 + 2] * RQs[lo][h8 * 4 + 2]
             + rk2s[h8 * 4 + 3] * RQs[lo][h8 * 4 + 3];
    const float m2 = max32(s2);
    const float e = __expf(s2 - m2);
    const float su = red32(e);
    scp[h8][lo] = e / su;
  }
  __syncthreads();                                             // B8

  // ---- ctx2 = p2 ◦ FR2 ; ret1 write ----
  {
    float a = 0.f;
    #pragma unroll
    for (int j = 0; j < 32; ++j) a = fmaf(scp[h8][j], b2f(bufA[j * 268 + t]), a);
    ctx2buf[(size_t)b * 256 + t] = a;
  }
  out[(size_t)b * 768 + 256 + t] = h1r0s[t] * nrm1s;
}

// ---------------------------------------------------------------------------
// LN + l2n epilogue over Y + res -> out[:,512:768]  (one row per block)
// ---------------------------------------------------------------------------
__global__ __launch_bounds__(256) void ln_l2n_kernel(
    const float* __restrict__ Y, const float* __restrict__ res,
    const float* __restrict__ lng, const float* __restrict__ lnb,
    float* __restrict__ out)
{
  const int row = blockIdx.x, t = threadIdx.x;
  __shared__ float s4[4], q4[4];
  const float y = Y[(size_t)row * 256 + t] + res[(size_t)row * 256 + t];
  float s = red64(y);
  float q = red64(y * y);
  if ((t & 63) == 0) { s4[t >> 6] = s; q4[t >> 6] = q; }
  __syncthreads();
  const float mu = (s4[0] + s4[1] + s4[2] + s4[3]) * (1.f / 256.f);
  const float var = fmaxf((q4[0] + q4[1] + q4[2] + q4[3]) * (1.f / 256.f) - mu * mu, 0.f);
  const float rstd = rsqrtf(var + LN_EPS);
  const float yn = fmaf((y - mu) * rstd, lng[t], lnb[t]);
  float nq = red64(yn * yn);
  __syncthreads();
  if ((t & 63) == 0) s4[t >> 6] = nq;
  __syncthreads();
  const float nrm = 1.f / fmaxf(sqrtf(s4[0] + s4[1] + s4[2] + s4[3]), 1e-12f);
  out[(size_t)row * 768 + 512 + t] = yn * nrm;
}

// ---------------------------------------------------------------------------
extern "C" void kernel_launch(void* const* d_in, const int* in_sizes, int n_in,
                              void* d_out, int out_size, void* d_ws, size_t ws_size,
                              hipStream_t stream)
{
  (void)in_sizes; (void)n_in; (void)out_size; (void)ws_size;

  const float* feat[4]; const float* wfc[4]; const float* bfc[4];
  for (int i = 0; i < 4; ++i) {
    feat[i] = (const float*)d_in[i * 3 + 0];
    wfc[i]  = (const float*)d_in[i * 3 + 1];
    bfc[i]  = (const float*)d_in[i * 3 + 2];
  }
  const float* type_emb = (const float*)d_in[12];
  const float* Wgcn = (const float*)d_in[13];
  const float* bgcn = (const float*)d_in[14];
  const float* Wre  = (const float*)d_in[15];
  const float* bre  = (const float*)d_in[16];
  const float* wtre = (const float*)d_in[17];
  const float* Wl   = (const float*)d_in[18];
  const float* Wr   = (const float*)d_in[19];
  const float* al   = (const float*)d_in[20];
  const float* ar   = (const float*)d_in[21];
  const float* Wrs  = (const float*)d_in[22];
  const float* Wrt  = (const float*)d_in[23];
  const float* Wfin = (const float*)d_in[24];
  const float* ln_g = (const float*)d_in[25];
  const float* ln_b = (const float*)d_in[26];
  const int* src       = (const int*)d_in[27];
  const int* dst       = (const int*)d_in[28];
  const int* node_type = (const int*)d_in[29];
  const int* seqs      = (const int*)d_in[30];
  float* out = (float*)d_out;

  // workspace carve-up (~45 MB)
  char* p = (char*)d_ws;
  auto take = [&](size_t n) { char* q = p; p += (n + 255) & ~(size_t)255; return q; };
  float* gh    = (float*)take((size_t)NN * 256 * 4);
  float* Xf    = (float*)take((size_t)NN * 256 * 4);   // ctx2buf
  float* GR1   = (float*)take((size_t)NN * 256 * 4);   // gh@Wr1, then h1r0buf
  float* RKQ   = (float*)take((size_t)NN * 128 * 4);
  float* SLg   = (float*)take((size_t)NN * 8 * 4);
  float* SRg   = (float*)take((size_t)NN * 8 * 4);
  float* n_out = (float*)take((size_t)NN * 4);
  float* n_in_ = (float*)take((size_t)NN * 4);
  int*   outc  = (int*)take((size_t)NN * 4);
  int*   inc   = (int*)take((size_t)NN * 4);
  int*   offs  = (int*)take((size_t)(NN + 1) * 4);
  int*   cur   = (int*)take((size_t)NN * 4);
  int*   csr   = (int*)take((size_t)(EE + NN) * 4);
  float* R     = (float*)take((size_t)NN * 4 * 4);
  float* rtmp  = (float*)take((size_t)NN * 4 * 4);
  ushortT* GW   = (ushortT*)take((size_t)NN * 256 * 2);
  ushortT* ghb  = (ushortT*)take((size_t)NN * 256 * 2);
  ushortT* Xb   = (ushortT*)take((size_t)NN * 256 * 2); // bf16 GCN scratch
  ushortT* Wg2i = (ushortT*)take((size_t)65536 * 2);
  ushortT* Wl2b = (ushortT*)take((size_t)65536 * 2);
  float* vecs  = (float*)take((size_t)2 * 256 * 4);
  float* ctx2buf = Xf;
  float* h1r0buf = GR1;    // alias: GR1 dead after GW table GEMM
  float* Yb      = gh;     // alias: gh dead after wlwr GEMM

  const float* Wr2 = Wr + 65536;
  const float* Wl2 = Wl + 65536;

  // 1) FC + ret0
  fc_kernel<<<256, 256, 0, stream>>>(feat[0], feat[1], feat[2], feat[3],
                                     wfc[0], wfc[1], wfc[2], wfc[3],
                                     bfc[0], bfc[1], bfc[2], bfc[3], gh, out);
  // 2) degrees + CSR (scan fused with norm/cur)
  zero_counts<<<64, 256, 0, stream>>>(outc, inc);
  count_deg<<<512, 256, 0, stream>>>(src, dst, outc, inc);
  scan_kernel<<<1, 1024, 0, stream>>>(inc, outc, offs, cur, n_out, n_in_);
  fill_csr<<<544, 256, 0, stream>>>(src, dst, cur, csr);

  // weight prep (wg2i: 32 blocks = exactly 8192 valid fragments)
  vec4_kernel<<<2, 256, 0, stream>>>(ln_g, ln_b, Wr2, vecs);
  wg2i_kernel<<<32, 256, 0, stream>>>(ln_g, Wr2, Wg2i);
  wl2b_kernel<<<256, 256, 0, stream>>>(Wl2, Wl2b);

  // 3) GCN + REConv, K=2 (GEMM -> bf16 Xb; re_proj; fused agg+re_agg)
  for (int k = 0; k < 2; ++k) {
    mfma_gemm_kernel<true, true, false, ushortT>
        <<<dim3(128, 4), 256, 0, stream>>>(gh, Wgcn + (size_t)k * 65536,
                                           n_out, Xb, nullptr, nullptr);
    if (k == 0)
      re_proj_k<true><<<128, 256, 0, stream>>>(nullptr, type_emb, node_type,
                                               n_out, Wre, wtre, rtmp);
    else
      re_proj_k<false><<<128, 256, 0, stream>>>(R, nullptr, node_type,
                                                n_out, Wre + 16, wtre + 4, rtmp);
    agg3_kernel<<<NN / 2, 256, 0, stream>>>(offs, csr, Xb, n_in_,
                                            bgcn + k * 256, rtmp, bre + k * 4,
                                            gh, R, k == 1 ? ghb : nullptr);
  }

  // 4) attention precomputes (fused Wl/Wr; GW table)
  rkq_kernel<<<4096, 256, 0, stream>>>(R, Wrs, Wrt, RKQ);
  mfma_wlwr_kernel<<<dim3(128, 4), 256, 0, stream>>>(
      gh, Wl, Wr, GR1, al, ar, SLg, SRg);
  mfma_gemm_kernel<false, true, false, ushortT>
      <<<dim3(128, 4), 256, 0, stream>>>(GR1, Wfin, nullptr, GW, nullptr, nullptr);

  // 5) fused transformer -> ret1, h1r0, ctx2
  mega7_kernel<<<NN, 256, 0, stream>>>(seqs, ghb, GW, SLg, SRg, RKQ, vecs,
                                       Wg2i, Wl2b,
                                       al + 32, ar + 32, ln_g, ln_b,
                                       h1r0buf, ctx2buf, out);

  // 6) epilogue: Y = ctx2@Wfin2 (MFMA, M=8192 batched) ; ret2 = l2n(LN(h1r0+Y))
  mfma_gemm_kernel<false, true, false, float>
      <<<dim3(128, 4), 256, 0, stream>>>(ctx2buf, Wfin + 65536, nullptr,
                                         Yb, nullptr, nullptr);
  ln_l2n_kernel<<<NN, 256, 0, stream>>>(Yb, h1r0buf, ln_g + 256, ln_b + 256, out);
}

// Round 25
// 510.416 us; speedup vs baseline: 1.1934x; 1.0106x over previous
//
#include <hip/hip_runtime.h>
#include <hip/hip_bf16.h>
#include <cstdint>
#include <cstddef>

typedef unsigned short ushortT;
typedef unsigned int uintT;

using bf16x8 = __attribute__((ext_vector_type(8))) short;
using f32x4  = __attribute__((ext_vector_type(4))) float;

static constexpr int NN  = 8192;    // total nodes
static constexpr int EE  = 131072;  // edges
static constexpr float SLOPE  = 0.2f;
static constexpr float LN_EPS = 1e-5f;

#define DEVI __device__ __forceinline__

DEVI float red32(float v) {
  #pragma unroll
  for (int m = 16; m >= 1; m >>= 1) v += __shfl_xor(v, m, 64);
  return v;
}
DEVI float red64(float v) {
  #pragma unroll
  for (int m = 32; m >= 1; m >>= 1) v += __shfl_xor(v, m, 64);
  return v;
}
DEVI float max32(float v) {
  #pragma unroll
  for (int m = 16; m >= 1; m >>= 1) v = fmaxf(v, __shfl_xor(v, m, 64));
  return v;
}
DEVI float blo(uintT u) { union { uintT i; float f; } c; c.i = u << 16; return c.f; }
DEVI float bhi(uintT u) { union { uintT i; float f; } c; c.i = u & 0xffff0000u; return c.f; }
DEVI float b2f(ushortT u) { union { uintT i; float f; } c; c.i = ((uintT)u) << 16; return c.f; }
DEVI ushortT f2bu(float f) {
  __hip_bfloat16 h = __float2bfloat16(f);
  return *reinterpret_cast<ushortT*>(&h);
}
DEVI void storeC(float* p, float v) { *p = v; }
DEVI void storeC(ushortT* p, float v) { *p = f2bu(v); }

// ---------------------------------------------------------------------------
// FC: gh[n] = feat_t[n] @ Wfc_t + bfc_t ; out[n,0:256] = l2n(gh[n])
// Blocks 0..63 also zero outc/inc (count_deg launches after fc completes).
// ---------------------------------------------------------------------------
__global__ __launch_bounds__(256) void fc_kernel(
    const float* __restrict__ f0, const float* __restrict__ f1,
    const float* __restrict__ f2, const float* __restrict__ f3,
    const float* __restrict__ w0, const float* __restrict__ w1,
    const float* __restrict__ w2, const float* __restrict__ w3,
    const float* __restrict__ b0, const float* __restrict__ b1,
    const float* __restrict__ b2, const float* __restrict__ b3,
    float* __restrict__ gh, float* __restrict__ out,
    int* __restrict__ outc, int* __restrict__ inc)
{
  const int nb = blockIdx.x * 32;
  const int t  = threadIdx.x;
  if (blockIdx.x < 64) {
    const int g = blockIdx.x * 256 + t;   // 16384 = 2*NN
    if (g < NN) outc[g] = 0; else inc[g - NN] = 0;
  }
  int base, D;
  const float *F, *W, *Bv;
  if (nb < 4096)      { base = 0;    D = 128; F = f0; W = w0; Bv = b0; }
  else if (nb < 6144) { base = 4096; D = 64;  F = f1; W = w1; Bv = b1; }
  else if (nb < 7168) { base = 6144; D = 32;  F = f2; W = w2; Bv = b2; }
  else                { base = 7168; D = 16;  F = f3; W = w3; Bv = b3; }

  __shared__ float Fs[32 * 128];
  __shared__ float red[32][4];
  __shared__ float nrm[32];

  const int total = 32 * D;
  for (int i = t; i < total; i += 256) Fs[i] = F[(size_t)(nb - base) * D + i];
  __syncthreads();

  float acc[32];
  #pragma unroll
  for (int r = 0; r < 32; ++r) acc[r] = Bv[t];
  for (int d = 0; d < D; ++d) {
    float w = W[(size_t)d * 256 + t];
    #pragma unroll
    for (int r = 0; r < 32; ++r) acc[r] = fmaf(Fs[r * D + d], w, acc[r]);
  }

  const int lane = t & 63, wid = t >> 6;
  #pragma unroll
  for (int r = 0; r < 32; ++r) {
    float v = acc[r] * acc[r];
    for (int o = 32; o > 0; o >>= 1) v += __shfl_down(v, o, 64);
    if (lane == 0) red[r][wid] = v;
  }
  __syncthreads();
  if (t < 32) {
    float s = red[t][0] + red[t][1] + red[t][2] + red[t][3];
    nrm[t] = 1.0f / fmaxf(sqrtf(s), 1e-12f);
  }
  __syncthreads();
  #pragma unroll
  for (int r = 0; r < 32; ++r) {
    gh[(size_t)(nb + r) * 256 + t]  = acc[r];
    out[(size_t)(nb + r) * 768 + t] = acc[r] * nrm[r];
  }
}

// ---------------------------------------------------------------------------
// degree / CSR build
// ---------------------------------------------------------------------------
__global__ __launch_bounds__(256) void count_deg(const int* __restrict__ src,
                                                 const int* __restrict__ dst,
                                                 int* outc, int* inc) {
  int g = blockIdx.x * 256 + threadIdx.x;
  atomicAdd(&outc[src[g]], 1);
  atomicAdd(&inc[dst[g]], 1);
}
// scan + norm + cur in one
__global__ __launch_bounds__(1024) void scan_kernel(
    const int* __restrict__ inc, const int* __restrict__ outc,
    int* __restrict__ offs, int* __restrict__ cur,
    float* __restrict__ n_out, float* __restrict__ n_in)
{
  __shared__ int sums[1024];
  const int t = threadIdx.x;
  int x[8];
  const int base = t * 8;
  int s = 0;
  #pragma unroll
  for (int i = 0; i < 8; ++i) { int v = inc[base + i] + 1; x[i] = s; s += v; }
  sums[t] = s;
  __syncthreads();
  for (int off = 1; off < 1024; off <<= 1) {
    int a = (t >= off) ? sums[t - off] : 0;
    __syncthreads();
    sums[t] += a;
    __syncthreads();
  }
  const int pre = (t > 0) ? sums[t - 1] : 0;
  #pragma unroll
  for (int i = 0; i < 8; ++i) {
    const int o = pre + x[i];
    offs[base + i] = o;
    cur[base + i]  = o;
    n_in[base + i]  = rsqrtf((float)inc[base + i] + 1.0f);
    n_out[base + i] = rsqrtf((float)outc[base + i] + 1.0f);
  }
  if (t == 1023) offs[NN] = sums[1023];
}
__global__ __launch_bounds__(256) void fill_csr(const int* __restrict__ src,
                                                const int* __restrict__ dst,
                                                int* cur, int* __restrict__ csr) {
  int g = blockIdx.x * 256 + threadIdx.x;   // EE + NN total
  int s, d;
  if (g < EE) { s = src[g]; d = dst[g]; }
  else        { s = g - EE; d = g - EE; }   // self-loops
  int pos = atomicAdd(&cur[d], 1);
  csr[pos] = s;
}

// ---------------------------------------------------------------------------
// MFMA GEMM (single B): C = (rowscale? diag(rs):I) A @ W ; optional RED
// ---------------------------------------------------------------------------
template<bool ROWSCALE, bool STORE, bool RED, typename CT>
__global__ __launch_bounds__(256) void mfma_gemm_kernel(
    const float* __restrict__ A, const float* __restrict__ W,
    const float* __restrict__ rowscale,
    CT* __restrict__ C, const float* __restrict__ avec,
    float* __restrict__ SSo)
{
  const int m0 = blockIdx.x * 64;
  const int n0 = blockIdx.y * 64;
  const int t = threadIdx.x;
  const int w = t >> 6, l = t & 63;
  const int wr = w >> 1, wc = w & 1;
  const int l15 = l & 15, l16 = l >> 4;

  __shared__ alignas(16) ushortT As[64][72];   // [m][k]
  __shared__ alignas(16) ushortT Bs[64][72];   // [n][k]

  f32x4 acc[2][2];
  #pragma unroll
  for (int mh = 0; mh < 2; ++mh)
    #pragma unroll
    for (int nh = 0; nh < 2; ++nh)
      #pragma unroll
      for (int r = 0; r < 4; ++r) acc[mh][nh][r] = 0.f;

  for (int k0 = 0; k0 < 256; k0 += 64) {
    #pragma unroll
    for (int rep = 0; rep < 16; ++rep) {
      int flat = rep * 256 + t;
      int r = flat >> 6, k = flat & 63;
      float v = A[(size_t)(m0 + r) * 256 + k0 + k];
      if constexpr (ROWSCALE) v *= rowscale[m0 + r];
      As[r][k] = f2bu(v);
    }
    #pragma unroll
    for (int rep = 0; rep < 16; ++rep) {
      int flat = rep * 256 + t;
      int k = flat >> 6, n = flat & 63;
      Bs[n][k] = f2bu(W[(size_t)(k0 + k) * 256 + n0 + n]);
    }
    __syncthreads();
    #pragma unroll
    for (int ks = 0; ks < 2; ++ks) {
      const int kb = ks * 32 + l16 * 8;
      bf16x8 afr[2], bfr[2];
      #pragma unroll
      for (int mh = 0; mh < 2; ++mh)
        afr[mh] = *reinterpret_cast<const bf16x8*>(&As[wr * 32 + mh * 16 + l15][kb]);
      #pragma unroll
      for (int nh = 0; nh < 2; ++nh)
        bfr[nh] = *reinterpret_cast<const bf16x8*>(&Bs[wc * 32 + nh * 16 + l15][kb]);
      #pragma unroll
      for (int mh = 0; mh < 2; ++mh)
        #pragma unroll
        for (int nh = 0; nh < 2; ++nh)
          acc[mh][nh] = __builtin_amdgcn_mfma_f32_16x16x32_bf16(
              afr[mh], bfr[nh], acc[mh][nh], 0, 0, 0);
    }
    __syncthreads();
  }
  if constexpr (STORE) {
    #pragma unroll
    for (int mh = 0; mh < 2; ++mh)
      #pragma unroll
      for (int nh = 0; nh < 2; ++nh)
        #pragma unroll
        for (int r = 0; r < 4; ++r) {
          const int row = m0 + wr * 32 + mh * 16 + l16 * 4 + r;
          const int col = n0 + wc * 32 + nh * 16 + l15;
          storeC(&C[(size_t)row * 256 + col], acc[mh][nh][r]);
        }
  }
  if constexpr (RED) {
    const float av0 = avec[l15], av1 = avec[16 + l15];
    #pragma unroll
    for (int mh = 0; mh < 2; ++mh)
      #pragma unroll
      for (int r = 0; r < 4; ++r) {
        float s = 0.f;
        {
          float x = acc[mh][0][r];
          s = fmaf(x > 0.f ? x : SLOPE * x, av0, s);
          x = acc[mh][1][r];
          s = fmaf(x > 0.f ? x : SLOPE * x, av1, s);
        }
        #pragma unroll
        for (int m = 8; m >= 1; m >>= 1) s += __shfl_xor(s, m, 64);
        if (l15 == 0) {
          const int row = m0 + wr * 32 + mh * 16 + l16 * 4 + r;
          SSo[(size_t)row * 8 + blockIdx.y * 2 + wc] = s;
        }
      }
  }
}

// ---------------------------------------------------------------------------
// Fused Wl/Wr GEMM: A staged once; SLg=RED(leaky(A@Wl)·al), GR1=A@Wr (store)
// + SRg=RED(leaky(A@Wr)·ar). Tail: RKQ = R @ {Wrs,Wrt} (folded rkq kernel).
// ---------------------------------------------------------------------------
__global__ __launch_bounds__(256) void mfma_wlwr_kernel(
    const float* __restrict__ A,
    const float* __restrict__ Wl_, const float* __restrict__ Wr_,
    float* __restrict__ GR1,
    const float* __restrict__ al_, const float* __restrict__ ar_,
    float* __restrict__ SL, float* __restrict__ SR,
    const float* __restrict__ R, const float* __restrict__ Wrs,
    const float* __restrict__ Wrt, float* __restrict__ RKQ)
{
  const int m0 = blockIdx.x * 64;
  const int n0 = blockIdx.y * 64;
  const int t = threadIdx.x;
  const int w = t >> 6, l = t & 63;
  const int wr = w >> 1, wc = w & 1;
  const int l15 = l & 15, l16 = l >> 4;

  __shared__ alignas(16) ushortT As[64][72];
  __shared__ alignas(16) ushortT Bl[64][72];
  __shared__ alignas(16) ushortT Br[64][72];

  f32x4 accl[2][2], accr[2][2];
  #pragma unroll
  for (int mh = 0; mh < 2; ++mh)
    #pragma unroll
    for (int nh = 0; nh < 2; ++nh)
      #pragma unroll
      for (int r = 0; r < 4; ++r) { accl[mh][nh][r] = 0.f; accr[mh][nh][r] = 0.f; }

  for (int k0 = 0; k0 < 256; k0 += 64) {
    #pragma unroll
    for (int rep = 0; rep < 16; ++rep) {
      int flat = rep * 256 + t;
      int r = flat >> 6, k = flat & 63;
      As[r][k] = f2bu(A[(size_t)(m0 + r) * 256 + k0 + k]);
    }
    #pragma unroll
    for (int rep = 0; rep < 16; ++rep) {
      int flat = rep * 256 + t;
      int k = flat >> 6, n = flat & 63;
      Bl[n][k] = f2bu(Wl_[(size_t)(k0 + k) * 256 + n0 + n]);
      Br[n][k] = f2bu(Wr_[(size_t)(k0 + k) * 256 + n0 + n]);
    }
    __syncthreads();
    #pragma unroll
    for (int ks = 0; ks < 2; ++ks) {
      const int kb = ks * 32 + l16 * 8;
      bf16x8 afr[2], blr[2], brr[2];
      #pragma unroll
      for (int mh = 0; mh < 2; ++mh)
        afr[mh] = *reinterpret_cast<const bf16x8*>(&As[wr * 32 + mh * 16 + l15][kb]);
      #pragma unroll
      for (int nh = 0; nh < 2; ++nh) {
        blr[nh] = *reinterpret_cast<const bf16x8*>(&Bl[wc * 32 + nh * 16 + l15][kb]);
        brr[nh] = *reinterpret_cast<const bf16x8*>(&Br[wc * 32 + nh * 16 + l15][kb]);
      }
      #pragma unroll
      for (int mh = 0; mh < 2; ++mh)
        #pragma unroll
        for (int nh = 0; nh < 2; ++nh) {
          accl[mh][nh] = __builtin_amdgcn_mfma_f32_16x16x32_bf16(
              afr[mh], blr[nh], accl[mh][nh], 0, 0, 0);
          accr[mh][nh] = __builtin_amdgcn_mfma_f32_16x16x32_bf16(
              afr[mh], brr[nh], accr[mh][nh], 0, 0, 0);
        }
    }
    __syncthreads();
  }
  // store GR1 = A@Wr
  #pragma unroll
  for (int mh = 0; mh < 2; ++mh)
    #pragma unroll
    for (int nh = 0; nh < 2; ++nh)
      #pragma unroll
      for (int r = 0; r < 4; ++r) {
        const int row = m0 + wr * 32 + mh * 16 + l16 * 4 + r;
        const int col = n0 + wc * 32 + nh * 16 + l15;
        GR1[(size_t)row * 256 + col] = accr[mh][nh][r];
      }
  // RED both
  const float al0 = al_[l15], al1 = al_[16 + l15];
  const float ar0 = ar_[l15], ar1 = ar_[16 + l15];
  #pragma unroll
  for (int mh = 0; mh < 2; ++mh)
    #pragma unroll
    for (int r = 0; r < 4; ++r) {
      float sl = 0.f, sr = 0.f;
      {
        float x = accl[mh][0][r];
        sl = fmaf(x > 0.f ? x : SLOPE * x, al0, sl);
        x = accl[mh][1][r];
        sl = fmaf(x > 0.f ? x : SLOPE * x, al1, sl);
        x = accr[mh][0][r];
        sr = fmaf(x > 0.f ? x : SLOPE * x, ar0, sr);
        x = accr[mh][1][r];
        sr = fmaf(x > 0.f ? x : SLOPE * x, ar1, sr);
      }
      #pragma unroll
      for (int m = 8; m >= 1; m >>= 1) {
        sl += __shfl_xor(sl, m, 64);
        sr += __shfl_xor(sr, m, 64);
      }
      if (l15 == 0) {
        const int row = m0 + wr * 32 + mh * 16 + l16 * 4 + r;
        SL[(size_t)row * 8 + blockIdx.y * 2 + wc] = sl;
        SR[(size_t)row * 8 + blockIdx.y * 2 + wc] = sr;
      }
    }
  // ---- rkq tail: RKQ over NN*128 elems, 512 blocks x 256 thr x 8 ----
  {
    const int flat = blockIdx.y * 128 + blockIdx.x;   // 0..511
    #pragma unroll
    for (int e = 0; e < 8; ++e) {
      const int g = flat * 2048 + e * 256 + t;
      const int n = g >> 7, c = g & 127;
      const int which = c >> 5, cc = c & 31;
      const float* Wp = (which == 0) ? Wrs : (which == 1) ? Wrt
                       : (which == 2) ? (Wrs + 128) : (Wrt + 128);
      float s = 0.f;
      #pragma unroll
      for (int r = 0; r < 4; ++r) s += R[n * 4 + r] * Wp[r * 32 + cc];
      RKQ[g] = s;
    }
  }
}

// ---------------------------------------------------------------------------
// GCN aggregate (bf16 input, 2 nodes/block) WITH fused REConv aggregation
// ---------------------------------------------------------------------------
__global__ __launch_bounds__(256) void agg3_kernel(
    const int* __restrict__ offs, const int* __restrict__ csr,
    const ushortT* __restrict__ X, const float* __restrict__ n_in,
    const float* __restrict__ bias,
    const float* __restrict__ rtmp, const float* __restrict__ bre,
    float* __restrict__ ghn, float* __restrict__ Rn,
    ushortT* __restrict__ ghb)
{
  const int n  = blockIdx.x * 2 + (threadIdx.x >> 7);
  const int tc = threadIdx.x & 127;
  const uintT* X2 = reinterpret_cast<const uintT*>(X);
  const int s0 = offs[n], s1 = offs[n + 1];
  float a0 = 0.f, a1 = 0.f, ra = 0.f;
  for (int i = s0; i < s1; ++i) {
    const int s = csr[i];
    const uintT u = X2[(size_t)s * 128 + tc];
    a0 += blo(u);
    a1 += bhi(u);
    if (tc < 4) ra += rtmp[(size_t)s * 4 + tc];
  }
  const float ni = n_in[n];
  const float g0 = fmaxf(fmaf(a0, ni, bias[2 * tc]), 0.f);
  const float g1 = fmaxf(fmaf(a1, ni, bias[2 * tc + 1]), 0.f);
  float2 g2; g2.x = g0; g2.y = g1;
  reinterpret_cast<float2*>(ghn)[(size_t)n * 128 + tc] = g2;
  if (ghb)
    reinterpret_cast<uintT*>(ghb)[(size_t)n * 128 + tc] =
        (uintT)f2bu(g0) | ((uintT)f2bu(g1) << 16);
  if (tc < 4) Rn[n * 4 + tc] = fmaxf(fmaf(ra, ni, bre[tc]), 0.f);
}

// re_proj (FIRST: R comes from type_emb[nt] directly)
template<bool FIRST>
__global__ __launch_bounds__(256) void re_proj_k(
    const float* __restrict__ R, const float* __restrict__ type_emb,
    const int* __restrict__ nt, const float* __restrict__ n_out,
    const float* __restrict__ Wre, const float* __restrict__ wtre,
    float* __restrict__ rtmp)
{
  int g = blockIdx.x * 256 + threadIdx.x;  // NN*4
  int n = g >> 2, j = g & 3;
  const int ty = nt[n];
  float s = 0.f;
  if constexpr (FIRST) {
    #pragma unroll
    for (int c = 0; c < 4; ++c) s += type_emb[ty * 4 + c] * Wre[c * 4 + j];
  } else {
    #pragma unroll
    for (int c = 0; c < 4; ++c) s += R[n * 4 + c] * Wre[c * 4 + j];
  }
  rtmp[g] = s * n_out[n] * wtre[ty];
}

// ---------------------------------------------------------------------------
// merged weight prep: b<2 vec4 | b<34 wg2i | b<290 wl2b
// ---------------------------------------------------------------------------
__global__ __launch_bounds__(256) void prep_kernel(
    const float* __restrict__ ln_g, const float* __restrict__ ln_b,
    const float* __restrict__ Wr2, const float* __restrict__ Wl2,
    float* __restrict__ vecs, ushortT* __restrict__ Wg2i,
    ushortT* __restrict__ Wl2b)
{
  const int b = blockIdx.x, t = threadIdx.x;
  if (b < 2) {
    const float* s = (b & 1) ? ln_b : ln_g;
    float a = 0.f;
    for (int k = 0; k < 256; ++k) a = fmaf(s[k], Wr2[(size_t)k * 256 + t], a);
    vecs[b * 256 + t] = a;
  } else if (b < 34) {
    const int gid = (b - 2) * 256 + t;   // 8192
    const int ks  = gid >> 10;           // [0,8)
    const int cgl = (gid >> 6) & 15;
    const int l   = gid & 63;
    const int col = cgl * 16 + (l & 15);
    const int kb  = ks * 32 + (l >> 4) * 8;
    ushortT v[8];
    #pragma unroll
    for (int e = 0; e < 8; ++e)
      v[e] = f2bu(ln_g[kb + e] * Wr2[(size_t)(kb + e) * 256 + col]);
    *reinterpret_cast<bf16x8*>(&Wg2i[(size_t)gid * 8]) =
        *reinterpret_cast<const bf16x8*>(v);
  } else {
    const int g = (b - 34) * 256 + t;    // 65536
    Wl2b[g] = f2bu(Wl2[g]);
  }
}

// ---------------------------------------------------------------------------
// MEGA7 (verified round-15/17/19/23 version)
// ---------------------------------------------------------------------------
__global__ __launch_bounds__(256) void mega7_kernel(
    const int* __restrict__ seqs,
    const ushortT* __restrict__ ghb,
    const ushortT* __restrict__ GW,
    const float* __restrict__ SLg, const float* __restrict__ SRg,
    const float* __restrict__ RKQ,
    const float* __restrict__ vecs,           // v1,v2
    const ushortT* __restrict__ Wg2i,         // interleaved bf16
    const ushortT* __restrict__ Wl2b,         // [k][col] bf16
    const float* __restrict__ al2, const float* __restrict__ ar2,
    const float* __restrict__ ln_g, const float* __restrict__ ln_b,
    float* __restrict__ h1r0buf, float* __restrict__ ctx2buf,
    float* __restrict__ out)
{
  __shared__ int idx[32];
  __shared__ alignas(16) ushortT bufA[10240];  // GT(GW^T, swz) -> FR2s[32][268]
  __shared__ alignas(16) ushortT bufB[10240];  // Pl[256][20u] swz -> xb[32][264]
  __shared__ float SRs[8][32];
  __shared__ float RQs[32][36];                // RQ1 then RQ2
  __shared__ float rk2s[32];
  __shared__ float part[32][4], partq[32][4];
  __shared__ float mu_s[32], rs_s[32];
  __shared__ float SR2s[8][32];
  __shared__ float sl2s[8];
  __shared__ float scp[8][32];
  __shared__ float h1r0s[256];
  __shared__ float wred4[4];
  __shared__ float nrm1s;

  const int b = blockIdx.x, t = threadIdx.x;
  const int h8 = t >> 5, lo = t & 31;
  const int w = t >> 6, l = t & 63;
  const int l15 = l & 15, l16 = l >> 4;

  if (t < 32) idx[t] = seqs[b * 32 + t];
  __syncthreads();                                             // B1

  const float sli = SLg[(size_t)idx[lo] * 8 + h8];
  const float rk0 = RKQ[(size_t)idx[lo] * 128 + h8 * 4 + 0];
  const float rk1 = RKQ[(size_t)idx[lo] * 128 + h8 * 4 + 1];
  const float rk2_ = RKQ[(size_t)idx[lo] * 128 + h8 * 4 + 2];
  const float rk3 = RKQ[(size_t)idx[lo] * 128 + h8 * 4 + 3];

  // ---- stage GT = GW^T (swizzled), SRs, RQ1, rk2s ----
  {
    const uintT* GWu = reinterpret_cast<const uintT*>(GW);
    #pragma unroll
    for (int rep = 0; rep < 16; ++rep) {
      int flat = rep * 256 + t;
      int j = flat >> 7, cp = flat & 127;
      const uintT u = GWu[(size_t)idx[j] * 128 + cp];
      const int rA = 2 * cp;
      const int k = (rA >> 3) & 3;
      const int off = (((j >> 3) ^ k) << 3) + (j & 7);
      bufA[rA * 40 + off]       = (ushortT)(u & 0xffffu);
      bufA[(rA + 1) * 40 + off] = (ushortT)(u >> 16);
    }
  }
  SRs[h8][lo] = SRg[(size_t)idx[lo] * 8 + h8];
  #pragma unroll
  for (int rep = 0; rep < 4; ++rep) {
    int flat = rep * 256 + t, s3 = flat >> 5, c3 = flat & 31;
    RQs[s3][c3] = RKQ[(size_t)idx[s3] * 128 + 32 + c3];
  }
  if (t < 32) rk2s[t] = RKQ[(size_t)idx[0] * 128 + 64 + t];
  __syncthreads();                                             // B2

  // ---- attn1 softmax -> Pl (swizzled bf16, b128 stores into bufB) ----
  {
    float p1[32];
    float m = -1e30f;
    #pragma unroll
    for (int j = 0; j < 32; ++j) {
      float sc = sli + SRs[h8][j]
               + rk0 * RQs[j][h8 * 4 + 0] + rk1 * RQs[j][h8 * 4 + 1]
               + rk2_ * RQs[j][h8 * 4 + 2] + rk3 * RQs[j][h8 * 4 + 3];
      p1[j] = sc; m = fmaxf(m, sc);
    }
    float sum = 0.f;
    #pragma unroll
    for (int j = 0; j < 32; ++j) { p1[j] = __expf(p1[j] - m); sum += p1[j]; }
    const float inv = 1.f / sum;
    const int row = t;
    const int k = (row >> 3) & 3;
    uintT* pw = reinterpret_cast<uintT*>(bufB) + row * 20;
    #pragma unroll
    for (int o = 0; o < 4; ++o) {
      uint4 v;
      v.x = (uintT)f2bu(p1[8 * o + 0] * inv) | ((uintT)f2bu(p1[8 * o + 1] * inv) << 16);
      v.y = (uintT)f2bu(p1[8 * o + 2] * inv) | ((uintT)f2bu(p1[8 * o + 3] * inv) << 16);
      v.z = (uintT)f2bu(p1[8 * o + 4] * inv) | ((uintT)f2bu(p1[8 * o + 5] * inv) << 16);
      v.w = (uintT)f2bu(p1[8 * o + 6] * inv) | ((uintT)f2bu(p1[8 * o + 7] * inv) << 16);
      *reinterpret_cast<uint4*>(pw + ((o ^ k) << 2)) = v;
    }
  }
  __syncthreads();                                             // B3

  int irow[2][4];
  #pragma unroll
  for (int mh = 0; mh < 2; ++mh)
    #pragma unroll
    for (int r = 0; r < 4; ++r)
      irow[mh][r] = idx[mh * 16 + l16 * 4 + r];

  // A-fragments (P) cached in registers
  bf16x8 af[2][2];
  #pragma unroll
  for (int hh = 0; hh < 2; ++hh) {
    const int h = 2 * w + hh;
    #pragma unroll
    for (int mh = 0; mh < 2; ++mh) {
      const int row = h * 32 + mh * 16 + l15;
      const int k = (row >> 3) & 3;
      af[hh][mh] = *reinterpret_cast<const bf16x8*>(&bufB[row * 40 + ((l16 ^ k) << 3)]);
    }
  }

  // ---- x phase: MFMA + ghb residual + LN stats + h1row0 stash ----
  f32x4 acc[2][2][2];
  #pragma unroll
  for (int hh = 0; hh < 2; ++hh) {
    const int h = 2 * w + hh;
    bf16x8 bf[2];
    #pragma unroll
    for (int nh = 0; nh < 2; ++nh) {
      const int row = h * 32 + nh * 16 + l15;
      const int k = (row >> 3) & 3;
      bf[nh] = *reinterpret_cast<const bf16x8*>(&bufA[row * 40 + ((l16 ^ k) << 3)]);
    }
    #pragma unroll
    for (int mh = 0; mh < 2; ++mh)
      #pragma unroll
      for (int nh = 0; nh < 2; ++nh) {
        f32x4 z = {0.f, 0.f, 0.f, 0.f};
        acc[hh][mh][nh] = __builtin_amdgcn_mfma_f32_16x16x32_bf16(af[hh][mh], bf[nh], z, 0, 0, 0);
      }
  }
  {
    float sum_[2][4], sq_[2][4];
    #pragma unroll
    for (int mh = 0; mh < 2; ++mh)
      #pragma unroll
      for (int r = 0; r < 4; ++r) { sum_[mh][r] = 0.f; sq_[mh][r] = 0.f; }
    #pragma unroll
    for (int hh = 0; hh < 2; ++hh)
      #pragma unroll
      for (int mh = 0; mh < 2; ++mh)
        #pragma unroll
        for (int nh = 0; nh < 2; ++nh) {
          const int col = (2 * w + hh) * 32 + nh * 16 + l15;
          #pragma unroll
          for (int r = 0; r < 4; ++r) {
            float v = acc[hh][mh][nh][r] + b2f(ghb[(size_t)irow[mh][r] * 256 + col]);
            acc[hh][mh][nh][r] = v;
            sum_[mh][r] += v;
            sq_[mh][r] = fmaf(v, v, sq_[mh][r]);
          }
        }
    #pragma unroll
    for (int mh = 0; mh < 2; ++mh)
      #pragma unroll
      for (int r = 0; r < 4; ++r) {
        float s = sum_[mh][r], q = sq_[mh][r];
        #pragma unroll
        for (int m = 8; m >= 1; m >>= 1) {
          s += __shfl_xor(s, m, 64);
          q += __shfl_xor(q, m, 64);
        }
        if (l15 == 0) {
          part[mh * 16 + l16 * 4 + r][w]  = s;
          partq[mh * 16 + l16 * 4 + r][w] = q;
        }
      }
    if (l16 == 0) {
      #pragma unroll
      for (int hh = 0; hh < 2; ++hh)
        #pragma unroll
        for (int nh = 0; nh < 2; ++nh)
          h1r0s[(2 * w + hh) * 32 + nh * 16 + l15] = acc[hh][0][nh][0];
    }
  }
  __syncthreads();                                             // B4

  if (t < 32) {
    float sm = part[t][0] + part[t][1] + part[t][2] + part[t][3];
    float sq = partq[t][0] + partq[t][1] + partq[t][2] + partq[t][3];
    const float m = sm * (1.f / 256.f);
    const float v = fmaxf(sq * (1.f / 256.f) - m * m, 0.f);
    mu_s[t] = m;
    rs_s[t] = rsqrtf(v + LN_EPS);
  }
  __syncthreads();                                             // B5

  // ---- xb = bf16(x) into bufB (Pl dead); RQ2; h1row0 LN + ret1 partials ----
  #pragma unroll
  for (int hh = 0; hh < 2; ++hh)
    #pragma unroll
    for (int mh = 0; mh < 2; ++mh)
      #pragma unroll
      for (int nh = 0; nh < 2; ++nh) {
        const int col = (2 * w + hh) * 32 + nh * 16 + l15;
        #pragma unroll
        for (int r = 0; r < 4; ++r) {
          const int row = mh * 16 + l16 * 4 + r;
          bufB[row * 264 + col] = f2bu(acc[hh][mh][nh][r]);
        }
      }
  #pragma unroll
  for (int rep = 0; rep < 4; ++rep) {
    int flat = rep * 256 + t, s3 = flat >> 5, c3 = flat & 31;
    RQs[s3][c3] = RKQ[(size_t)idx[s3] * 128 + 96 + c3];
  }
  {
    const float mu0 = mu_s[0], rs0 = rs_s[0];
    float hv = fmaf((h1r0s[t] - mu0) * rs0, ln_g[t], ln_b[t]);
    h1r0buf[(size_t)b * 256 + t] = hv;
    float sq = red64(hv * hv);
    h1r0s[t] = hv;
    if ((t & 63) == 0) wred4[t >> 6] = sq;
  }
  __syncthreads();                                             // B6

  if (t == 0) nrm1s = 1.f / fmaxf(sqrtf(wred4[0] + wred4[1] + wred4[2] + wred4[3]), 1e-12f);

  // ---- y phase: y = x @ Wg2 (MFMA, K=256, B from interleaved Wg2i) ----
  {
    f32x4 acc2[2][4];   // [mh][cg]  (wave owns cols w*64 .. w*64+63)
    #pragma unroll
    for (int mh = 0; mh < 2; ++mh)
      #pragma unroll
      for (int cg = 0; cg < 4; ++cg)
        #pragma unroll
        for (int r = 0; r < 4; ++r) acc2[mh][cg][r] = 0.f;
    #pragma unroll
    for (int ks = 0; ks < 8; ++ks) {
      const int ko = ks * 32 + l16 * 8;
      bf16x8 a2[2];
      #pragma unroll
      for (int mh = 0; mh < 2; ++mh)
        a2[mh] = *reinterpret_cast<const bf16x8*>(&bufB[(mh * 16 + l15) * 264 + ko]);
      #pragma unroll
      for (int cg = 0; cg < 4; ++cg) {
        const bf16x8 b2 = *reinterpret_cast<const bf16x8*>(
            &Wg2i[((size_t)(ks * 16 + (w * 4 + cg)) * 64 + l) * 8]);
        #pragma unroll
        for (int mh = 0; mh < 2; ++mh)
          acc2[mh][cg] = __builtin_amdgcn_mfma_f32_16x16x32_bf16(a2[mh], b2, acc2[mh][cg], 0, 0, 0);
      }
    }
    // epilogue: FR2 + SR2
    float rsv[2][4], rmv[2][4];
    #pragma unroll
    for (int mh = 0; mh < 2; ++mh)
      #pragma unroll
      for (int r = 0; r < 4; ++r) {
        const int row = mh * 16 + l16 * 4 + r;
        rsv[mh][r] = rs_s[row];
        rmv[mh][r] = rsv[mh][r] * mu_s[row];
      }
    float sacc[2][2][4];   // [head-half][mh][r]
    #pragma unroll
    for (int hh = 0; hh < 2; ++hh)
      #pragma unroll
      for (int mh = 0; mh < 2; ++mh)
        #pragma unroll
        for (int r = 0; r < 4; ++r) sacc[hh][mh][r] = 0.f;
    float ar2v[2] = { ar2[l15], ar2[16 + l15] };
    #pragma unroll
    for (int cg = 0; cg < 4; ++cg) {
      const int col = w * 64 + cg * 16 + l15;
      const float v1c = vecs[col], v2c = vecs[256 + col];
      const int hh = cg >> 1;
      #pragma unroll
      for (int mh = 0; mh < 2; ++mh)
        #pragma unroll
        for (int r = 0; r < 4; ++r) {
          const int row = mh * 16 + l16 * 4 + r;
          float fa = fmaf(rsv[mh][r], acc2[mh][cg][r], fmaf(-rmv[mh][r], v1c, v2c));
          bufA[row * 268 + col] = f2bu(fa);       // FR2s[row][col]
          float lr = fa > 0.f ? fa : SLOPE * fa;
          sacc[hh][mh][r] = fmaf(lr, ar2v[cg & 1], sacc[hh][mh][r]);
        }
    }
    #pragma unroll
    for (int hh = 0; hh < 2; ++hh)
      #pragma unroll
      for (int mh = 0; mh < 2; ++mh)
        #pragma unroll
        for (int r = 0; r < 4; ++r) {
          float s = sacc[hh][mh][r];
          #pragma unroll
          for (int m = 8; m >= 1; m >>= 1) s += __shfl_xor(s, m, 64);
          if (l15 == 0) SR2s[2 * w + hh][mh * 16 + l16 * 4 + r] = s;
        }
  }
  // ---- fl2 = h1row0 @ Wl2 (coalesced k-major bf16) -> sl2 ----
  {
    float fl = 0.f;
    #pragma unroll 8
    for (int k = 0; k < 256; ++k)
      fl = fmaf(h1r0s[k], b2f(Wl2b[(size_t)k * 256 + t]), fl);
    float lr = (fl > 0.f ? fl : SLOPE * fl) * al2[lo];
    lr = red32(lr);
    if (lo == 0) sl2s[h8] = lr;
  }
  __syncthreads();                                             // B7

  // ---- attn2 row0 scores ----
  {
    float s2 = sl2s[h8] + SR2s[h8][lo]
             + rk2s[h8 * 4 + 0] * RQs[lo][h8 * 4 + 0]
             + rk2s[h8 * 4 + 1] * RQs[lo][h8 * 4 + 1]
             + rk2s[h8 * 4 + 2] * RQs[lo][h8 * 4 + 2]
             + rk2s[h8 * 4 + 3] * RQs[lo][h8 * 4 + 3];
    const float m2 = max32(s2);
    const float e = __expf(s2 - m2);
    const float su = red32(e);
    scp[h8][lo] = e / su;
  }
  __syncthreads();                                             // B8

  // ---- ctx2 = p2 ◦ FR2 ; ret1 write ----
  {
    float a = 0.f;
    #pragma unroll
    for (int j = 0; j < 32; ++j) a = fmaf(scp[h8][j], b2f(bufA[j * 268 + t]), a);
    ctx2buf[(size_t)b * 256 + t] = a;
  }
  out[(size_t)b * 768 + 256 + t] = h1r0s[t] * nrm1s;
}

// ---------------------------------------------------------------------------
// LN + l2n epilogue over Y + res -> out[:,512:768]  (one row per block)
// ---------------------------------------------------------------------------
__global__ __launch_bounds__(256) void ln_l2n_kernel(
    const float* __restrict__ Y, const float* __restrict__ res,
    const float* __restrict__ lng, const float* __restrict__ lnb,
    float* __restrict__ out)
{
  const int row = blockIdx.x, t = threadIdx.x;
  __shared__ float s4[4], q4[4];
  const float y = Y[(size_t)row * 256 + t] + res[(size_t)row * 256 + t];
  float s = red64(y);
  float q = red64(y * y);
  if ((t & 63) == 0) { s4[t >> 6] = s; q4[t >> 6] = q; }
  __syncthreads();
  const float mu = (s4[0] + s4[1] + s4[2] + s4[3]) * (1.f / 256.f);
  const float var = fmaxf((q4[0] + q4[1] + q4[2] + q4[3]) * (1.f / 256.f) - mu * mu, 0.f);
  const float rstd = rsqrtf(var + LN_EPS);
  const float yn = fmaf((y - mu) * rstd, lng[t], lnb[t]);
  float nq = red64(yn * yn);
  __syncthreads();
  if ((t & 63) == 0) s4[t >> 6] = nq;
  __syncthreads();
  const float nrm = 1.f / fmaxf(sqrtf(s4[0] + s4[1] + s4[2] + s4[3]), 1e-12f);
  out[(size_t)row * 768 + 512 + t] = yn * nrm;
}

// ---------------------------------------------------------------------------
extern "C" void kernel_launch(void* const* d_in, const int* in_sizes, int n_in,
                              void* d_out, int out_size, void* d_ws, size_t ws_size,
                              hipStream_t stream)
{
  (void)in_sizes; (void)n_in; (void)out_size; (void)ws_size;

  const float* feat[4]; const float* wfc[4]; const float* bfc[4];
  for (int i = 0; i < 4; ++i) {
    feat[i] = (const float*)d_in[i * 3 + 0];
    wfc[i]  = (const float*)d_in[i * 3 + 1];
    bfc[i]  = (const float*)d_in[i * 3 + 2];
  }
  const float* type_emb = (const float*)d_in[12];
  const float* Wgcn = (const float*)d_in[13];
  const float* bgcn = (const float*)d_in[14];
  const float* Wre  = (const float*)d_in[15];
  const float* bre  = (const float*)d_in[16];
  const float* wtre = (const float*)d_in[17];
  const float* Wl   = (const float*)d_in[18];
  const float* Wr   = (const float*)d_in[19];
  const float* al   = (const float*)d_in[20];
  const float* ar   = (const float*)d_in[21];
  const float* Wrs  = (const float*)d_in[22];
  const float* Wrt  = (const float*)d_in[23];
  const float* Wfin = (const float*)d_in[24];
  const float* ln_g = (const float*)d_in[25];
  const float* ln_b = (const float*)d_in[26];
  const int* src       = (const int*)d_in[27];
  const int* dst       = (const int*)d_in[28];
  const int* node_type = (const int*)d_in[29];
  const int* seqs      = (const int*)d_in[30];
  float* out = (float*)d_out;

  // workspace carve-up (~45 MB)
  char* p = (char*)d_ws;
  auto take = [&](size_t n) { char* q = p; p += (n + 255) & ~(size_t)255; return q; };
  float* gh    = (float*)take((size_t)NN * 256 * 4);
  float* Xf    = (float*)take((size_t)NN * 256 * 4);   // ctx2buf
  float* GR1   = (float*)take((size_t)NN * 256 * 4);   // gh@Wr1, then h1r0buf
  float* RKQ   = (float*)take((size_t)NN * 128 * 4);
  float* SLg   = (float*)take((size_t)NN * 8 * 4);
  float* SRg   = (float*)take((size_t)NN * 8 * 4);
  float* n_out = (float*)take((size_t)NN * 4);
  float* n_in_ = (float*)take((size_t)NN * 4);
  int*   outc  = (int*)take((size_t)NN * 4);
  int*   inc   = (int*)take((size_t)NN * 4);
  int*   offs  = (int*)take((size_t)(NN + 1) * 4);
  int*   cur   = (int*)take((size_t)NN * 4);
  int*   csr   = (int*)take((size_t)(EE + NN) * 4);
  float* R     = (float*)take((size_t)NN * 4 * 4);
  float* rtmp  = (float*)take((size_t)NN * 4 * 4);
  ushortT* GW   = (ushortT*)take((size_t)NN * 256 * 2);
  ushortT* ghb  = (ushortT*)take((size_t)NN * 256 * 2);
  ushortT* Xb   = (ushortT*)take((size_t)NN * 256 * 2); // bf16 GCN scratch
  ushortT* Wg2i = (ushortT*)take((size_t)65536 * 2);
  ushortT* Wl2b = (ushortT*)take((size_t)65536 * 2);
  float* vecs  = (float*)take((size_t)2 * 256 * 4);
  float* ctx2buf = Xf;
  float* h1r0buf = GR1;    // alias: GR1 dead after GW table GEMM
  float* Yb      = gh;     // alias: gh dead after wlwr GEMM

  const float* Wr2 = Wr + 65536;
  const float* Wl2 = Wl + 65536;

  // 1) FC + ret0 (+ zero outc/inc)
  fc_kernel<<<256, 256, 0, stream>>>(feat[0], feat[1], feat[2], feat[3],
                                     wfc[0], wfc[1], wfc[2], wfc[3],
                                     bfc[0], bfc[1], bfc[2], bfc[3], gh, out,
                                     outc, inc);
  // 2) degrees + CSR (scan fused with norm/cur)
  count_deg<<<512, 256, 0, stream>>>(src, dst, outc, inc);
  scan_kernel<<<1, 1024, 0, stream>>>(inc, outc, offs, cur, n_out, n_in_);
  fill_csr<<<544, 256, 0, stream>>>(src, dst, cur, csr);

  // weight prep (merged vec4 + wg2i + wl2b)
  prep_kernel<<<290, 256, 0, stream>>>(ln_g, ln_b, Wr2, Wl2, vecs, Wg2i, Wl2b);

  // 3) GCN + REConv, K=2 (GEMM -> bf16 Xb; re_proj; fused agg+re_agg)
  for (int k = 0; k < 2; ++k) {
    mfma_gemm_kernel<true, true, false, ushortT>
        <<<dim3(128, 4), 256, 0, stream>>>(gh, Wgcn + (size_t)k * 65536,
                                           n_out, Xb, nullptr, nullptr);
    if (k == 0)
      re_proj_k<true><<<128, 256, 0, stream>>>(nullptr, type_emb, node_type,
                                               n_out, Wre, wtre, rtmp);
    else
      re_proj_k<false><<<128, 256, 0, stream>>>(R, nullptr, node_type,
                                                n_out, Wre + 16, wtre + 4, rtmp);
    agg3_kernel<<<NN / 2, 256, 0, stream>>>(offs, csr, Xb, n_in_,
                                            bgcn + k * 256, rtmp, bre + k * 4,
                                            gh, R, k == 1 ? ghb : nullptr);
  }

  // 4) attention precomputes (fused Wl/Wr GEMM + rkq tail; GW table)
  mfma_wlwr_kernel<<<dim3(128, 4), 256, 0, stream>>>(
      gh, Wl, Wr, GR1, al, ar, SLg, SRg, R, Wrs, Wrt, RKQ);
  mfma_gemm_kernel<false, true, false, ushortT>
      <<<dim3(128, 4), 256, 0, stream>>>(GR1, Wfin, nullptr, GW, nullptr, nullptr);

  // 5) fused transformer -> ret1, h1r0, ctx2
  mega7_kernel<<<NN, 256, 0, stream>>>(seqs, ghb, GW, SLg, SRg, RKQ, vecs,
                                       Wg2i, Wl2b,
                                       al + 32, ar + 32, ln_g, ln_b,
                                       h1r0buf, ctx2buf, out);

  // 6) epilogue: Y = ctx2@Wfin2 (MFMA, M=8192 batched) ; ret2 = l2n(LN(h1r0+Y))
  mfma_gemm_kernel<false, true, false, float>
      <<<dim3(128, 4), 256, 0, stream>>>(ctx2buf, Wfin + 65536, nullptr,
                                         Yb, nullptr, nullptr);
  ln_l2n_kernel<<<NN, 256, 0, stream>>>(Yb, h1r0buf, ln_g + 256, ln_b + 256, out);
}